// Round 6
// baseline (463.987 us; speedup 1.0000x reference)
//
#include <hip/hip_runtime.h>
#include <hip/hip_bf16.h>

// Problem constants
#define Bz 8
#define Tn 64
#define Mn 500
#define KC 16
#define HA 64
#define HR 64
#define NHID 32
#define DF 160
#define FINALC 512
#define GSPLIT 8

typedef float in_t;   // reference dtypes are all float32
typedef __attribute__((ext_vector_type(8))) _Float16 half8;
typedef __attribute__((ext_vector_type(4))) float f32x4;
#define MFMAH __builtin_amdgcn_mfma_f32_16x16x32_f16

__device__ __forceinline__ float sigm(float x){ return 1.0f/(1.0f+__expf(-x)); }
__device__ __forceinline__ float tanhfast(float x){ float e=__expf(2.0f*x); return 1.0f-2.0f/(e+1.0f); }
__device__ __forceinline__ float eluf(float x){ return x>0.0f? x : (__expf(x)-1.0f); }
__device__ __forceinline__ unsigned short f2h(float f){
  _Float16 h = (_Float16)f;
  return *reinterpret_cast<unsigned short*>(&h);
}
__device__ __forceinline__ unsigned int pack2h(float a, float b){
  return (unsigned int)f2h(a) | ((unsigned int)f2h(b) << 16);
}

// ---------------------------------------------------------------------------
// K1: per-node convs -> h_SC (relu), writes f0[0:32] (f32) and f0T fp16
__global__ __launch_bounds__(128) void k_conv(
    const in_t* __restrict__ x, const in_t* __restrict__ wsw, const in_t* __restrict__ wsb,
    const in_t* __restrict__ wlw, const in_t* __restrict__ wlb,
    float* __restrict__ hSC, float* __restrict__ f0, unsigned short* __restrict__ f0T)
{
  __shared__ float sw[KC*Tn];
  __shared__ float lw[KC*Tn];
  __shared__ float sb[KC], lb[KC];
  int tid = threadIdx.x;
  for (int idx = tid; idx < KC*Tn; idx += blockDim.x) {
    sw[idx] = wsw[idx];
    int k = idx >> 6, t = idx & 63;
    lw[idx] = 0.5f * wlw[k*32 + (t>>1)];
  }
  if (tid < KC) { sb[tid] = wsb[tid]; lb[tid] = wlb[tid]; }
  __syncthreads();
  int m = blockIdx.x * blockDim.x + tid;
  int b = blockIdx.y;
  if (m >= Mn) return;
  float xv[Tn];
  const in_t* xp = x + (size_t)b*Tn*Mn + m;
  #pragma unroll
  for (int t = 0; t < Tn; ++t) xv[t] = xp[t*Mn];
  float* hp = hSC + ((size_t)b*Mn + m) * (2*KC);
  float* fp = f0  + ((size_t)b*Mn + m) * DF;
  for (int k = 0; k < KC; ++k) {
    float s = 0.f, l = 0.f;
    #pragma unroll
    for (int t = 0; t < Tn; ++t) { s += xv[t]*sw[k*Tn+t]; l += xv[t]*lw[k*Tn+t]; }
    float vs = fmaxf(s + sb[k], 0.f);
    float vl = fmaxf(l + lb[k], 0.f);
    hp[k] = vs; hp[KC+k] = vl;
    fp[k] = vs; fp[KC+k] = vl;
    f0T[((size_t)b*DF + k)*Mn + m]      = f2h(vs);
    f0T[((size_t)b*DF + KC + k)*Mn + m] = f2h(vl);
  }
}

// ---------------------------------------------------------------------------
// K2: Q/K projections
__global__ __launch_bounds__(256) void k_qk(
    const float* __restrict__ hSC, const in_t* __restrict__ WQw, const in_t* __restrict__ WQb,
    const in_t* __restrict__ WKw, const in_t* __restrict__ WKb,
    float* __restrict__ Q, float* __restrict__ Kt)
{
  __shared__ float wq[HA*32], wk[HA*32], bq[HA], bk[HA];
  int tid = threadIdx.x;
  for (int i = tid; i < HA*32; i += 256) { wq[i] = WQw[i]; wk[i] = WKw[i]; }
  for (int i = tid; i < HA; i += 256) { bq[i] = WQb[i]; bk[i] = WKb[i]; }
  __syncthreads();
  int gid = blockIdx.x*256 + tid;
  if (gid >= Bz*Mn) return;
  float h[32];
  const float* hp = hSC + (size_t)gid*32;
  #pragma unroll
  for (int c = 0; c < 32; ++c) h[c] = hp[c];
  float* qp = Q + (size_t)gid*HA;
  float* kp = Kt + (size_t)gid*HA;
  for (int a = 0; a < HA; ++a) {
    float aq = bq[a], ak = bk[a];
    #pragma unroll
    for (int c = 0; c < 32; ++c) { aq += h[c]*wq[a*32+c]; ak += h[c]*wk[a*32+c]; }
    qp[a] = aq; kp[a] = ak;
  }
}

// ---------------------------------------------------------------------------
// K3: split-K partial Gram: Gpart[(split*Bz+b)] = sum_{m in chunk} K_m K_m^T
__global__ __launch_bounds__(256) void k_gram(
    const float* __restrict__ Kt, float* __restrict__ Gpart, float* __restrict__ Kpart)
{
  int split = blockIdx.x, b = blockIdx.y;
  int tid = threadIdx.x;
  __shared__ float L[64][HA];
  int m0 = split*63;
  int mend = min(m0 + 63, Mn);
  int p = tid & 63;
  int q0 = (tid >> 6) * 16;
  float acc[16];
  #pragma unroll
  for (int e = 0; e < 16; ++e) acc[e] = 0.f;
  for (int idx = tid; idx < 64*HA; idx += 256) {
    int r = idx >> 6, c = idx & 63;
    int m = m0 + r;
    L[r][c] = (m < mend) ? Kt[((size_t)b*Mn + m)*HA + c] : 0.f;
  }
  __syncthreads();
  float ks = 0.f;
  #pragma unroll 4
  for (int r = 0; r < 63; ++r) {
    float lp = L[r][p];
    if (tid < 64) ks += lp;
    #pragma unroll
    for (int e = 0; e < 16; ++e) acc[e] += lp * L[r][q0+e];
  }
  float* gp = Gpart + ((size_t)split*Bz + b)*HA*HA;
  #pragma unroll
  for (int e = 0; e < 16; ++e) gp[p*HA + q0 + e] = acc[e];
  if (tid < 64) Kpart[((size_t)split*Bz + b)*HA + tid] = ks;
}

// ---------------------------------------------------------------------------
// K4: s-glob + h_L (sums the GSPLIT partials on load), writes f0[32:160]
__global__ __launch_bounds__(256) void k_sglob(
    const float* __restrict__ Q, const float* __restrict__ Gpart, const float* __restrict__ Kpart,
    const in_t* __restrict__ degree, const in_t* __restrict__ tencw, const in_t* __restrict__ tencb,
    const in_t* __restrict__ sencw, const in_t* __restrict__ sencb,
    float* __restrict__ f0, unsigned short* __restrict__ f0T)
{
  int b = blockIdx.y;
  __shared__ float Gs[HA*HA];
  __shared__ float Ks[HA], tw[HR], tb[HR], sw2[HR], sb2[HR];
  int tid = threadIdx.x;
  for (int i = tid; i < HA*HA; i += 256) {
    float s = 0.f;
    #pragma unroll
    for (int sp = 0; sp < GSPLIT; ++sp) s += Gpart[((size_t)sp*Bz + b)*HA*HA + i];
    Gs[i] = s;
  }
  for (int i = tid; i < HA; i += 256) {
    float s = 0.f;
    #pragma unroll
    for (int sp = 0; sp < GSPLIT; ++sp) s += Kpart[((size_t)sp*Bz + b)*HA + i];
    Ks[i] = s;
    tw[i] = tencw[i]; tb[i] = tencb[i];
    sw2[i] = sencw[i]; sb2[i] = sencb[i];
  }
  __syncthreads();
  int m = blockIdx.x*256 + tid;
  if (m >= Mn) return;
  const float* qp = Q + ((size_t)b*Mn + m)*HA;
  float q[HA];
  #pragma unroll
  for (int i = 0; i < HA; ++i) q[i] = qp[i];
  float rs = 0.f, qq = 0.f;
  for (int p = 0; p < HA; ++p) {
    float t = 0.f;
    #pragma unroll
    for (int c = 0; c < HA; ++c) t += Gs[p*HA + c] * q[c];
    float qpv = qp[p];
    qq += qpv * t;
    rs += qpv * Ks[p];
  }
  float nrm = fmaxf(sqrtf(fmaxf(qq, 0.f)), 1e-12f);
  float s = rs / nrm;
  float dg = degree[m];
  float* fp = f0 + ((size_t)b*Mn + m)*DF;
  for (int r = 0; r < HR; ++r) {
    float v1 = s*tw[r] + tb[r];
    float v2 = dg*sw2[r] + sb2[r];
    fp[32 + r] = v1;
    fp[96 + r] = v2;
    f0T[((size_t)b*DF + 32 + r)*Mn + m] = f2h(v1);
    f0T[((size_t)b*DF + 96 + r)*Mn + m] = f2h(v2);
  }
}

// ---------------------------------------------------------------------------
// K5: GRU — 12 partial accumulators (chain depth 8) + x prefetch/broadcast
__global__ __launch_bounds__(256) void k_gru(
    const in_t* __restrict__ x, const in_t* __restrict__ Wih, const in_t* __restrict__ Whh,
    const in_t* __restrict__ bih, const in_t* __restrict__ bhh, float* __restrict__ lh)
{
  int tid = threadIdx.x;
  int lane = tid & 31;
  int seq = blockIdx.x*8 + (tid >> 5);
  int b = seq / Mn, m = seq - b*Mn;
  float wr[32], wz[32], wn[32];
  #pragma unroll
  for (int j = 0; j < 32; ++j) {
    wr[j] = Whh[(0*32 + lane)*32 + j];
    wz[j] = Whh[(32 + lane)*32 + j];
    wn[j] = Whh[(64 + lane)*32 + j];
  }
  float wir = Wih[lane],   wiz = Wih[32+lane],   win = Wih[64+lane];
  float bir = bih[lane],   biz = bih[32+lane],   bin_ = bih[64+lane];
  float bhr = bhh[lane],   bhz = bhh[32+lane],   bhn = bhh[64+lane];
  const in_t* xp = x + (size_t)b*Tn*Mn + m;
  // prefetch all 64 timesteps: lane holds x[lane] and x[32+lane]
  float x0 = xp[lane*Mn];
  float x1 = xp[(32+lane)*Mn];
  float h = 0.f;
  for (int t = 0; t < Tn; ++t) {
    float xsrc = (t < 32) ? x0 : x1;
    float xt = __shfl(xsrc, t & 31, 32);
    float gr0=0.f, gr1=0.f, gr2=0.f, gr3=0.f;
    float gz0=0.f, gz1=0.f, gz2=0.f, gz3=0.f;
    float gn0=0.f, gn1=0.f, gn2=0.f, gn3=0.f;
    #pragma unroll
    for (int jj = 0; jj < 8; ++jj) {
      float h0 = __shfl(h, jj*4+0, 32);
      float h1 = __shfl(h, jj*4+1, 32);
      float h2 = __shfl(h, jj*4+2, 32);
      float h3 = __shfl(h, jj*4+3, 32);
      gr0 += wr[jj*4+0]*h0; gr1 += wr[jj*4+1]*h1; gr2 += wr[jj*4+2]*h2; gr3 += wr[jj*4+3]*h3;
      gz0 += wz[jj*4+0]*h0; gz1 += wz[jj*4+1]*h1; gz2 += wz[jj*4+2]*h2; gz3 += wz[jj*4+3]*h3;
      gn0 += wn[jj*4+0]*h0; gn1 += wn[jj*4+1]*h1; gn2 += wn[jj*4+2]*h2; gn3 += wn[jj*4+3]*h3;
    }
    float gr = ((gr0+gr1)+(gr2+gr3)) + bhr;
    float gz = ((gz0+gz1)+(gz2+gz3)) + bhz;
    float gn = ((gn0+gn1)+(gn2+gn3)) + bhn;
    float r = sigm(xt*wir + bir + gr);
    float z = sigm(xt*wiz + biz + gz);
    float n = tanhfast(xt*win + bin_ + r*gn);
    h = (1.f - z)*n + z*h;
  }
  lh[(size_t)seq*NHID + lane] = h;
}

// ---------------------------------------------------------------------------
// K6: A1/A2
__global__ __launch_bounds__(256) void k_a1a2(
    const float* __restrict__ lh, const in_t* __restrict__ W1, const in_t* __restrict__ W2,
    float* __restrict__ A1, float* __restrict__ A2)
{
  __shared__ float w1[32*32], w2[32*32];
  int tid = threadIdx.x;
  for (int i = tid; i < 1024; i += 256) { w1[i] = W1[i]; w2[i] = W2[i]; }
  __syncthreads();
  int gid = blockIdx.x*256 + tid;
  if (gid >= Bz*Mn) return;
  float h[32];
  #pragma unroll
  for (int c = 0; c < 32; ++c) h[c] = lh[(size_t)gid*32 + c];
  float* a1 = A1 + (size_t)gid*32;
  float* a2 = A2 + (size_t)gid*32;
  for (int a = 0; a < 32; ++a) {
    float s1 = 0.f, s2 = 0.f;
    #pragma unroll
    for (int c = 0; c < 32; ++c) { s1 += h[c]*w1[a*32+c]; s2 += h[c]*w2[a*32+c]; }
    a1[a] = s1; a2[a] = s2;
  }
}

// ---------------------------------------------------------------------------
// K7: dmat
__global__ __launch_bounds__(256) void k_dmat(
    const in_t* __restrict__ dgate, const in_t* __restrict__ degree, float* __restrict__ dmat)
{
  int idx = blockIdx.x*256 + threadIdx.x;
  if (idx >= Mn*Mn) return;
  int i = idx / Mn, j = idx - i*Mn;
  dmat[idx] = sigm(dgate[idx] * degree[i] * degree[j]);
}

// ---------------------------------------------------------------------------
// K8: a[b,i,j] = V . elu(A1_i + A2_j + b1) + bv   (f32 — sign feeds binarize)
__global__ __launch_bounds__(256) void k_pair(
    const float* __restrict__ A1, const float* __restrict__ A2, const in_t* __restrict__ Vv,
    const in_t* __restrict__ b1, const in_t* __restrict__ bv, float* __restrict__ aB)
{
  __shared__ float a1s[16][33], a2s[16][33], vs[32], b1s[32];
  int b = blockIdx.z;
  int i0 = blockIdx.y*16, j0 = blockIdx.x*16;
  int tid = threadIdx.x;
  if (tid < 32) { vs[tid] = Vv[tid]; b1s[tid] = b1[tid]; }
  {
    int r = tid >> 5, c = tid & 31;
    for (int rr = r; rr < 16; rr += 8) {
      int i = i0 + rr, j = j0 + rr;
      a1s[rr][c] = (i < Mn) ? A1[((size_t)b*Mn + i)*32 + c] : 0.f;
      a2s[rr][c] = (j < Mn) ? A2[((size_t)b*Mn + j)*32 + c] : 0.f;
    }
  }
  __syncthreads();
  int ti = tid >> 4, tj = tid & 15;
  int i = i0 + ti, j = j0 + tj;
  if (i >= Mn || j >= Mn) return;
  float acc = 0.f;
  #pragma unroll
  for (int c = 0; c < 32; ++c) {
    float u = a1s[ti][c] + a2s[tj][c] + b1s[c];
    acc += eluf(u) * vs[c];
  }
  aB[((size_t)b*Mn + i)*Mn + j] = acc + bv[0];
}

// ---------------------------------------------------------------------------
// K9a: partial column sum-squares over row chunks; grid (4 jblk, 8 isplit, Bz)
__global__ __launch_bounds__(128) void k_cnorm(const float* __restrict__ aB, float* __restrict__ ssp)
{
  int jb = blockIdx.x, isp = blockIdx.y, b = blockIdx.z;
  int j = jb*128 + threadIdx.x;
  if (j >= Mn) return;
  int i0 = isp*63, iend = min(i0 + 63, Mn);
  const float* ap = aB + (size_t)b*Mn*Mn + j;
  float ss = 0.f;
  for (int i = i0; i < iend; ++i) { float v = ap[(size_t)i*Mn]; ss += v*v; }
  ssp[((size_t)isp*Bz + b)*Mn + j] = ss;
}

// K9b: finalize cinv
__global__ __launch_bounds__(256) void k_cfin(const float* __restrict__ ssp, float* __restrict__ cinv)
{
  int idx = blockIdx.x*256 + threadIdx.x;
  if (idx >= Bz*Mn) return;
  int b = idx / Mn, j = idx - b*Mn;
  float ss = 0.f;
  #pragma unroll
  for (int sp = 0; sp < 8; ++sp) ss += ssp[((size_t)sp*Bz + b)*Mn + j];
  cinv[idx] = 1.f / fmaxf(sqrtf(ss), 1e-12f);
}

// ---------------------------------------------------------------------------
// K10: c_gate GEMM via plain fp16 MFMA + fused adj epilogue -> adj_bin (f32)
__global__ __launch_bounds__(256) void k_cgemm(
    const float* __restrict__ aB, const float* __restrict__ cinv, const in_t* __restrict__ Wb,
    const in_t* __restrict__ wb, const in_t* __restrict__ adj_geo, const float* __restrict__ dmat,
    float* __restrict__ adjb)
{
  __shared__ unsigned short As[64*72], Bs[64*72];
  int b = blockIdx.z, i0 = blockIdx.y*64, j0 = blockIdx.x*64;
  int tid = threadIdx.x;
  const float* aRow = aB + (size_t)b*Mn*Mn;
  const float* civ = cinv + b*Mn;
  int w = tid >> 6, lane = tid & 63, ln = lane & 15, lg = lane >> 4;
  int wm = (w >> 1)*32, wn = (w & 1)*32;
  f32x4 acc[2][2];
  #pragma unroll
  for (int p = 0; p < 2; ++p)
    #pragma unroll
    for (int q = 0; q < 2; ++q) acc[p][q] = (f32x4)(0.f);

  for (int k0 = 0; k0 < 512; k0 += 64) {
    for (int idx = tid; idx < 2048; idx += 256) {
      int r = idx >> 5, cp = idx & 31;
      int i = i0 + r, k = k0 + 2*cp;
      unsigned int v = 0;
      if (i < Mn && k < Mn)
        v = pack2h(aRow[(size_t)i*Mn + k]*civ[k], aRow[(size_t)i*Mn + k + 1]*civ[k+1]);
      *reinterpret_cast<unsigned int*>(&As[r*72 + 2*cp]) = v;
    }
    for (int idx = tid; idx < 2048; idx += 256) {
      int c = idx & 63, rp = idx >> 6;
      int j = j0 + c, k = k0 + 2*rp;
      unsigned int v = 0;
      if (j < Mn && k < Mn)
        v = pack2h(Wb[(size_t)k*Mn + j], Wb[(size_t)(k+1)*Mn + j]);
      *reinterpret_cast<unsigned int*>(&Bs[c*72 + 2*rp]) = v;
    }
    __syncthreads();
    #pragma unroll
    for (int kk = 0; kk < 2; ++kk) {
      half8 a0 = *reinterpret_cast<const half8*>(&As[(wm + 0  + ln)*72 + kk*32 + lg*8]);
      half8 a1 = *reinterpret_cast<const half8*>(&As[(wm + 16 + ln)*72 + kk*32 + lg*8]);
      half8 b0 = *reinterpret_cast<const half8*>(&Bs[(wn + 0  + ln)*72 + kk*32 + lg*8]);
      half8 b1 = *reinterpret_cast<const half8*>(&Bs[(wn + 16 + ln)*72 + kk*32 + lg*8]);
      acc[0][0] = MFMAH(a0, b0, acc[0][0], 0, 0, 0);
      acc[0][1] = MFMAH(a0, b1, acc[0][1], 0, 0, 0);
      acc[1][0] = MFMAH(a1, b0, acc[1][0], 0, 0, 0);
      acc[1][1] = MFMAH(a1, b1, acc[1][1], 0, 0, 0);
    }
    __syncthreads();
  }
  float wbv = wb[0];
  #pragma unroll
  for (int mt = 0; mt < 2; ++mt)
    #pragma unroll
    for (int nt = 0; nt < 2; ++nt)
      #pragma unroll
      for (int r = 0; r < 4; ++r) {
        int i = i0 + wm + mt*16 + lg*4 + r;
        int j = j0 + wn + nt*16 + ln;
        if (i < Mn && j < Mn) {
          float cg = sigm(acc[mt][nt][r] + wbv);
          float av = aRow[(size_t)i*Mn + j]*civ[j];
          float ag = adj_geo[(size_t)i*Mn + j];
          float adjf = ag*cg + av*(1.f - cg) + dmat[(size_t)i*Mn + j]*ag;
          adjb[((size_t)b*Mn + i)*Mn + j] = (adjf > 0.f) ? 1.f : adjf;
        }
      }
}

// ---------------------------------------------------------------------------
// K11: laplace row-normalize -> fp16 lapB
__global__ __launch_bounds__(256) void k_lap(const float* __restrict__ adjb, unsigned short* __restrict__ lapB)
{
  int b = blockIdx.y, i = blockIdx.x;
  const float* row = adjb + ((size_t)b*Mn + i)*Mn;
  int tid = threadIdx.x;
  float s = 0.f;
  for (int j = tid; j < Mn; j += 256) s += row[j];
  __shared__ float red[8];
  int lane = tid & 63, wv = tid >> 6;
  #pragma unroll
  for (int off = 32; off; off >>= 1) s += __shfl_down(s, off);
  if (lane == 0) red[wv] = s;
  __syncthreads();
  if (tid == 0) {
    float d = red[0] + red[1] + red[2] + red[3];
    red[4] = (d > 0.f) ? 1.f/d : 0.f;
  }
  __syncthreads();
  float inv = red[4];
  unsigned short* lrow = lapB + ((size_t)b*Mn + i)*Mn;
  for (int j = tid; j < Mn; j += 256) lrow[j] = f2h(row[j]*inv);
}

// ---------------------------------------------------------------------------
// K12: spmm via fp16 MFMA: tmpB[b][i][d] = lapB @ fT^T
__global__ __launch_bounds__(256) void k_spmm(
    const unsigned short* __restrict__ lapB, const unsigned short* __restrict__ fT,
    unsigned short* __restrict__ tmpB)
{
  __shared__ unsigned short As[64*72], Bs[64*72];
  int b = blockIdx.z, i0 = blockIdx.y*64, j0 = blockIdx.x*64;
  int tid = threadIdx.x;
  int w = tid >> 6, lane = tid & 63, ln = lane & 15, lg = lane >> 4;
  int wm = (w >> 1)*32, wn = (w & 1)*32;
  f32x4 acc[2][2];
  #pragma unroll
  for (int p = 0; p < 2; ++p)
    #pragma unroll
    for (int q = 0; q < 2; ++q) acc[p][q] = (f32x4)(0.f);

  for (int k0 = 0; k0 < 512; k0 += 64) {
    for (int idx = tid; idx < 2048; idx += 256) {
      int r = idx >> 5, cp = idx & 31;
      int i = i0 + r, k = k0 + 2*cp;
      unsigned int v = 0;
      if (i < Mn && k < Mn)
        v = *reinterpret_cast<const unsigned int*>(&lapB[((size_t)b*Mn + i)*Mn + k]);
      *reinterpret_cast<unsigned int*>(&As[r*72 + 2*cp]) = v;
    }
    for (int idx = tid; idx < 2048; idx += 256) {
      int r = idx >> 5, cp = idx & 31;
      int d = j0 + r, k = k0 + 2*cp;
      unsigned int v = 0;
      if (d < DF && k < Mn)
        v = *reinterpret_cast<const unsigned int*>(&fT[((size_t)b*DF + d)*Mn + k]);
      *reinterpret_cast<unsigned int*>(&Bs[r*72 + 2*cp]) = v;
    }
    __syncthreads();
    #pragma unroll
    for (int kk = 0; kk < 2; ++kk) {
      half8 a0 = *reinterpret_cast<const half8*>(&As[(wm + 0  + ln)*72 + kk*32 + lg*8]);
      half8 a1 = *reinterpret_cast<const half8*>(&As[(wm + 16 + ln)*72 + kk*32 + lg*8]);
      half8 b0 = *reinterpret_cast<const half8*>(&Bs[(wn + 0  + ln)*72 + kk*32 + lg*8]);
      half8 b1 = *reinterpret_cast<const half8*>(&Bs[(wn + 16 + ln)*72 + kk*32 + lg*8]);
      acc[0][0] = MFMAH(a0, b0, acc[0][0], 0, 0, 0);
      acc[0][1] = MFMAH(a0, b1, acc[0][1], 0, 0, 0);
      acc[1][0] = MFMAH(a1, b0, acc[1][0], 0, 0, 0);
      acc[1][1] = MFMAH(a1, b1, acc[1][1], 0, 0, 0);
    }
    __syncthreads();
  }
  #pragma unroll
  for (int mt = 0; mt < 2; ++mt)
    #pragma unroll
    for (int nt = 0; nt < 2; ++nt)
      #pragma unroll
      for (int r = 0; r < 4; ++r) {
        int i = i0 + wm + mt*16 + lg*4 + r;
        int j = j0 + wn + nt*16 + ln;
        if (i < Mn && j < DF)
          tmpB[((size_t)b*Mn + i)*DF + j] = f2h(acc[mt][nt][r]);
      }
}

// ---------------------------------------------------------------------------
// K13: dense: fout = elu(tmpB @ gnn_w + bias); optional fp16 transposed copy
__global__ __launch_bounds__(256) void k_dense(
    const unsigned short* __restrict__ tmpB, const in_t* __restrict__ W, const in_t* __restrict__ bias,
    float* __restrict__ fout, unsigned short* __restrict__ foutT)
{
  __shared__ unsigned short As[64*72], Bs[64*72];
  __shared__ float bs[64];
  int i0 = blockIdx.y*64, j0 = blockIdx.x*64;
  int tid = threadIdx.x;
  if (tid < 64) bs[tid] = (j0 + tid < DF) ? bias[j0 + tid] : 0.f;
  int w = tid >> 6, lane = tid & 63, ln = lane & 15, lg = lane >> 4;
  int wm = (w >> 1)*32, wn = (w & 1)*32;
  const int NR = Bz*Mn;
  f32x4 acc[2][2];
  #pragma unroll
  for (int p = 0; p < 2; ++p)
    #pragma unroll
    for (int q = 0; q < 2; ++q) acc[p][q] = (f32x4)(0.f);

  for (int k0 = 0; k0 < 192; k0 += 64) {
    for (int idx = tid; idx < 2048; idx += 256) {
      int r = idx >> 5, cp = idx & 31;
      int i = i0 + r, k = k0 + 2*cp;
      unsigned int v = 0;
      if (i < NR && k < DF)
        v = *reinterpret_cast<const unsigned int*>(&tmpB[(size_t)i*DF + k]);
      *reinterpret_cast<unsigned int*>(&As[r*72 + 2*cp]) = v;
    }
    for (int idx = tid; idx < 2048; idx += 256) {
      int c = idx & 63, rp = idx >> 6;
      int j = j0 + c, k = k0 + 2*rp;
      unsigned int v = 0;
      if (j < DF && k < DF)
        v = pack2h(W[(size_t)k*DF + j], W[(size_t)(k+1)*DF + j]);
      *reinterpret_cast<unsigned int*>(&Bs[c*72 + 2*rp]) = v;
    }
    __syncthreads();
    #pragma unroll
    for (int kk = 0; kk < 2; ++kk) {
      half8 a0 = *reinterpret_cast<const half8*>(&As[(wm + 0  + ln)*72 + kk*32 + lg*8]);
      half8 a1 = *reinterpret_cast<const half8*>(&As[(wm + 16 + ln)*72 + kk*32 + lg*8]);
      half8 b0 = *reinterpret_cast<const half8*>(&Bs[(wn + 0  + ln)*72 + kk*32 + lg*8]);
      half8 b1 = *reinterpret_cast<const half8*>(&Bs[(wn + 16 + ln)*72 + kk*32 + lg*8]);
      acc[0][0] = MFMAH(a0, b0, acc[0][0], 0, 0, 0);
      acc[0][1] = MFMAH(a0, b1, acc[0][1], 0, 0, 0);
      acc[1][0] = MFMAH(a1, b0, acc[1][0], 0, 0, 0);
      acc[1][1] = MFMAH(a1, b1, acc[1][1], 0, 0, 0);
    }
    __syncthreads();
  }
  #pragma unroll
  for (int mt = 0; mt < 2; ++mt)
    #pragma unroll
    for (int nt = 0; nt < 2; ++nt)
      #pragma unroll
      for (int r = 0; r < 4; ++r) {
        int i = i0 + wm + mt*16 + lg*4 + r;
        int jl = wn + nt*16 + ln;
        int j = j0 + jl;
        if (i < NR && j < DF) {
          float val = eluf(acc[mt][nt][r] + bs[jl]);
          fout[(size_t)i*DF + j] = val;
          if (foutT) {
            int bb = i / Mn, mm = i - bb*Mn;
            foutT[((size_t)bb*DF + j)*Mn + mm] = f2h(val);
          }
        }
      }
}

// ---------------------------------------------------------------------------
// K14: output projection
__global__ __launch_bounds__(256) void k_out(
    const float* __restrict__ f0, const float* __restrict__ f1, const float* __restrict__ f2,
    const float* __restrict__ lh, const in_t* __restrict__ ow, const in_t* __restrict__ ob,
    float* __restrict__ outp)
{
  __shared__ float w[FINALC];
  int tid = threadIdx.x;
  for (int i = tid; i < FINALC; i += 256) w[i] = ow[i];
  __syncthreads();
  int gid = blockIdx.x*256 + tid;
  if (gid >= Bz*Mn) return;
  float s = ob[0];
  const float* p0 = f0 + (size_t)gid*DF;
  const float* p1 = f1 + (size_t)gid*DF;
  const float* p2 = f2 + (size_t)gid*DF;
  const float* pl = lh + (size_t)gid*NHID;
  for (int c = 0; c < DF; ++c) s += p0[c]*w[c];
  for (int c = 0; c < DF; ++c) s += p1[c]*w[DF + c];
  for (int c = 0; c < DF; ++c) s += p2[c]*w[2*DF + c];
  for (int c = 0; c < NHID; ++c) s += pl[c]*w[3*DF + c];
  outp[gid] = s;
}

// ---------------------------------------------------------------------------
extern "C" void kernel_launch(void* const* d_in, const int* in_sizes, int n_in,
                              void* d_out, int out_size, void* d_ws, size_t ws_size,
                              hipStream_t stream)
{
  const in_t* x       = (const in_t*)d_in[0];
  const in_t* adj_geo = (const in_t*)d_in[1];
  const in_t* degree  = (const in_t*)d_in[2];
  const in_t* conv_s_w= (const in_t*)d_in[3];
  const in_t* conv_s_b= (const in_t*)d_in[4];
  const in_t* conv_l_w= (const in_t*)d_in[5];
  const in_t* conv_l_b= (const in_t*)d_in[6];
  const in_t* WQ_w    = (const in_t*)d_in[7];
  const in_t* WQ_b    = (const in_t*)d_in[8];
  const in_t* WK_w    = (const in_t*)d_in[9];
  const in_t* WK_b    = (const in_t*)d_in[10];
  const in_t* tenc_w  = (const in_t*)d_in[11];
  const in_t* tenc_b  = (const in_t*)d_in[12];
  const in_t* senc_w  = (const in_t*)d_in[13];
  const in_t* senc_b  = (const in_t*)d_in[14];
  const in_t* gru_Wih = (const in_t*)d_in[15];
  const in_t* gru_Whh = (const in_t*)d_in[16];
  const in_t* gru_bih = (const in_t*)d_in[17];
  const in_t* gru_bhh = (const in_t*)d_in[18];
  const in_t* Vv      = (const in_t*)d_in[19];
  const in_t* W1      = (const in_t*)d_in[20];
  const in_t* W2      = (const in_t*)d_in[21];
  const in_t* Wb      = (const in_t*)d_in[22];
  const in_t* bv      = (const in_t*)d_in[23];
  const in_t* b1      = (const in_t*)d_in[24];
  const in_t* wb      = (const in_t*)d_in[25];
  const in_t* d_gate  = (const in_t*)d_in[26];
  const in_t* gnn_w   = (const in_t*)d_in[27];
  const in_t* gnn_b   = (const in_t*)d_in[28];
  const in_t* out_w   = (const in_t*)d_in[29];
  const in_t* out_b   = (const in_t*)d_in[30];
  float* out = (float*)d_out;

  // workspace carve-up (float offsets)
  float* ws   = (float*)d_ws;
  float* hSC  = ws;                    // 128000
  float* Qb   = ws + 128000;           // 256000
  float* Ktb  = ws + 384000;           // 256000
  float* lh   = ws + 673280;           // 128000
  float* A1   = ws + 801280;           // 128000
  float* A2   = ws + 929280;           // 128000
  float* aB   = ws + 1057280;          // 2000000 (dead after k_cgemm; lapB overlays)
  float* cinv = ws + 3057280;          // 4000
  float* adjb = ws + 3061280;          // 2000000
  float* dmat = ws + 5061280;          // 250000
  float* f0   = ws + 5311280;          // 640000
  float* f1   = ws + 5951280;          // 640000
  float* f2   = ws + 6591280;          // 640000
  unsigned short* f0T  = (unsigned short*)(ws + 7231280);  // 640000 fp16
  unsigned short* tmpB = (unsigned short*)(ws + 7551280);  // 640000 fp16
  unsigned short* f1T  = (unsigned short*)(ws + 7871280);  // 640000 fp16
  unsigned short* lapB = (unsigned short*)aB;              // fp16 overlay (aB dead after cgemm)
  // transient partials in adjb region (adjb written only later by k_cgemm):
  float* Gpart = adjb;                 // 8*8*4096 = 262144
  float* Kpart = adjb + 262144;        // 8*8*64   = 4096
  float* ssp   = adjb + 266240;        // 8*8*500  = 32000

  k_conv<<<dim3(4, Bz), 128, 0, stream>>>(x, conv_s_w, conv_s_b, conv_l_w, conv_l_b, hSC, f0, f0T);
  k_qk<<<dim3(16), 256, 0, stream>>>(hSC, WQ_w, WQ_b, WK_w, WK_b, Qb, Ktb);
  k_gram<<<dim3(GSPLIT, Bz), 256, 0, stream>>>(Ktb, Gpart, Kpart);
  k_sglob<<<dim3(2, Bz), 256, 0, stream>>>(Qb, Gpart, Kpart, degree, tenc_w, tenc_b, senc_w, senc_b, f0, f0T);
  k_gru<<<dim3(500), 256, 0, stream>>>(x, gru_Wih, gru_Whh, gru_bih, gru_bhh, lh);
  k_a1a2<<<dim3(16), 256, 0, stream>>>(lh, W1, W2, A1, A2);
  k_dmat<<<dim3((Mn*Mn + 255)/256), 256, 0, stream>>>(d_gate, degree, dmat);
  k_pair<<<dim3(32, 32, Bz), 256, 0, stream>>>(A1, A2, Vv, b1, bv, aB);
  k_cnorm<<<dim3(4, 8, Bz), 128, 0, stream>>>(aB, ssp);
  k_cfin<<<dim3(16), 256, 0, stream>>>(ssp, cinv);
  k_cgemm<<<dim3(8, 8, Bz), 256, 0, stream>>>(aB, cinv, Wb, wb, adj_geo, dmat, adjb);
  k_lap<<<dim3(Mn, Bz), 256, 0, stream>>>(adjb, lapB);
  // GNN layer 0
  k_spmm<<<dim3(3, 8, Bz), 256, 0, stream>>>(lapB, f0T, tmpB);
  k_dense<<<dim3(3, 63), 256, 0, stream>>>(tmpB, gnn_w, gnn_b, f1, f1T);
  // GNN layer 1
  k_spmm<<<dim3(3, 8, Bz), 256, 0, stream>>>(lapB, f1T, tmpB);
  k_dense<<<dim3(3, 63), 256, 0, stream>>>(tmpB, gnn_w + DF*DF, gnn_b + DF, f2, (unsigned short*)nullptr);
  k_out<<<dim3(16), 256, 0, stream>>>(f0, f1, f2, lh, out_w, out_b, out);
}

// Round 7
// 462.570 us; speedup vs baseline: 1.0031x; 1.0031x over previous
//
#include <hip/hip_runtime.h>
#include <hip/hip_bf16.h>

// Problem constants
#define Bz 8
#define Tn 64
#define Mn 500
#define KC 16
#define HA 64
#define HR 64
#define NHID 32
#define DF 160
#define FINALC 512
#define GSPLIT 8

typedef float in_t;   // reference dtypes are all float32
typedef __attribute__((ext_vector_type(8))) _Float16 half8;
typedef __attribute__((ext_vector_type(4))) float f32x4;
#define MFMAH __builtin_amdgcn_mfma_f32_16x16x32_f16

__device__ __forceinline__ float sigm(float x){ return 1.0f/(1.0f+__expf(-x)); }
__device__ __forceinline__ float tanhfast(float x){ float e=__expf(2.0f*x); return 1.0f-2.0f/(e+1.0f); }
__device__ __forceinline__ float eluf(float x){ return x>0.0f? x : (__expf(x)-1.0f); }
__device__ __forceinline__ unsigned short f2h(float f){
  _Float16 h = (_Float16)f;
  return *reinterpret_cast<unsigned short*>(&h);
}
__device__ __forceinline__ unsigned int pack2h(float a, float b){
  return (unsigned int)f2h(a) | ((unsigned int)f2h(b) << 16);
}

// ---------------------------------------------------------------------------
// K1: per-node convs -> h_SC (relu), writes f0[0:32] (f32) and f0T fp16
__global__ __launch_bounds__(128) void k_conv(
    const in_t* __restrict__ x, const in_t* __restrict__ wsw, const in_t* __restrict__ wsb,
    const in_t* __restrict__ wlw, const in_t* __restrict__ wlb,
    float* __restrict__ hSC, float* __restrict__ f0, unsigned short* __restrict__ f0T)
{
  __shared__ float sw[KC*Tn];
  __shared__ float lw[KC*Tn];
  __shared__ float sb[KC], lb[KC];
  int tid = threadIdx.x;
  for (int idx = tid; idx < KC*Tn; idx += blockDim.x) {
    sw[idx] = wsw[idx];
    int k = idx >> 6, t = idx & 63;
    lw[idx] = 0.5f * wlw[k*32 + (t>>1)];
  }
  if (tid < KC) { sb[tid] = wsb[tid]; lb[tid] = wlb[tid]; }
  __syncthreads();
  int m = blockIdx.x * blockDim.x + tid;
  int b = blockIdx.y;
  if (m >= Mn) return;
  float xv[Tn];
  const in_t* xp = x + (size_t)b*Tn*Mn + m;
  #pragma unroll
  for (int t = 0; t < Tn; ++t) xv[t] = xp[t*Mn];
  float* hp = hSC + ((size_t)b*Mn + m) * (2*KC);
  float* fp = f0  + ((size_t)b*Mn + m) * DF;
  for (int k = 0; k < KC; ++k) {
    float s = 0.f, l = 0.f;
    #pragma unroll
    for (int t = 0; t < Tn; ++t) { s += xv[t]*sw[k*Tn+t]; l += xv[t]*lw[k*Tn+t]; }
    float vs = fmaxf(s + sb[k], 0.f);
    float vl = fmaxf(l + lb[k], 0.f);
    hp[k] = vs; hp[KC+k] = vl;
    fp[k] = vs; fp[KC+k] = vl;
    f0T[((size_t)b*DF + k)*Mn + m]      = f2h(vs);
    f0T[((size_t)b*DF + KC + k)*Mn + m] = f2h(vl);
  }
}

// ---------------------------------------------------------------------------
// K2: Q/K projections
__global__ __launch_bounds__(256) void k_qk(
    const float* __restrict__ hSC, const in_t* __restrict__ WQw, const in_t* __restrict__ WQb,
    const in_t* __restrict__ WKw, const in_t* __restrict__ WKb,
    float* __restrict__ Q, float* __restrict__ Kt)
{
  __shared__ float wq[HA*32], wk[HA*32], bq[HA], bk[HA];
  int tid = threadIdx.x;
  for (int i = tid; i < HA*32; i += 256) { wq[i] = WQw[i]; wk[i] = WKw[i]; }
  for (int i = tid; i < HA; i += 256) { bq[i] = WQb[i]; bk[i] = WKb[i]; }
  __syncthreads();
  int gid = blockIdx.x*256 + tid;
  if (gid >= Bz*Mn) return;
  float h[32];
  const float* hp = hSC + (size_t)gid*32;
  #pragma unroll
  for (int c = 0; c < 32; ++c) h[c] = hp[c];
  float* qp = Q + (size_t)gid*HA;
  float* kp = Kt + (size_t)gid*HA;
  for (int a = 0; a < HA; ++a) {
    float aq = bq[a], ak = bk[a];
    #pragma unroll
    for (int c = 0; c < 32; ++c) { aq += h[c]*wq[a*32+c]; ak += h[c]*wk[a*32+c]; }
    qp[a] = aq; kp[a] = ak;
  }
}

// ---------------------------------------------------------------------------
// K3: split-K partial Gram
__global__ __launch_bounds__(256) void k_gram(
    const float* __restrict__ Kt, float* __restrict__ Gpart, float* __restrict__ Kpart)
{
  int split = blockIdx.x, b = blockIdx.y;
  int tid = threadIdx.x;
  __shared__ float L[64][HA];
  int m0 = split*63;
  int mend = min(m0 + 63, Mn);
  int p = tid & 63;
  int q0 = (tid >> 6) * 16;
  float acc[16];
  #pragma unroll
  for (int e = 0; e < 16; ++e) acc[e] = 0.f;
  for (int idx = tid; idx < 64*HA; idx += 256) {
    int r = idx >> 6, c = idx & 63;
    int m = m0 + r;
    L[r][c] = (m < mend) ? Kt[((size_t)b*Mn + m)*HA + c] : 0.f;
  }
  __syncthreads();
  float ks = 0.f;
  #pragma unroll 4
  for (int r = 0; r < 63; ++r) {
    float lp = L[r][p];
    if (tid < 64) ks += lp;
    #pragma unroll
    for (int e = 0; e < 16; ++e) acc[e] += lp * L[r][q0+e];
  }
  float* gp = Gpart + ((size_t)split*Bz + b)*HA*HA;
  #pragma unroll
  for (int e = 0; e < 16; ++e) gp[p*HA + q0 + e] = acc[e];
  if (tid < 64) Kpart[((size_t)split*Bz + b)*HA + tid] = ks;
}

// ---------------------------------------------------------------------------
// K4: s-glob + h_L (sums the GSPLIT partials on load), writes f0[32:160]
__global__ __launch_bounds__(256) void k_sglob(
    const float* __restrict__ Q, const float* __restrict__ Gpart, const float* __restrict__ Kpart,
    const in_t* __restrict__ degree, const in_t* __restrict__ tencw, const in_t* __restrict__ tencb,
    const in_t* __restrict__ sencw, const in_t* __restrict__ sencb,
    float* __restrict__ f0, unsigned short* __restrict__ f0T)
{
  int b = blockIdx.y;
  __shared__ float Gs[HA*HA];
  __shared__ float Ks[HA], tw[HR], tb[HR], sw2[HR], sb2[HR];
  int tid = threadIdx.x;
  for (int i = tid; i < HA*HA; i += 256) {
    float s = 0.f;
    #pragma unroll
    for (int sp = 0; sp < GSPLIT; ++sp) s += Gpart[((size_t)sp*Bz + b)*HA*HA + i];
    Gs[i] = s;
  }
  for (int i = tid; i < HA; i += 256) {
    float s = 0.f;
    #pragma unroll
    for (int sp = 0; sp < GSPLIT; ++sp) s += Kpart[((size_t)sp*Bz + b)*HA + i];
    Ks[i] = s;
    tw[i] = tencw[i]; tb[i] = tencb[i];
    sw2[i] = sencw[i]; sb2[i] = sencb[i];
  }
  __syncthreads();
  int m = blockIdx.x*256 + tid;
  if (m >= Mn) return;
  const float* qp = Q + ((size_t)b*Mn + m)*HA;
  float q[HA];
  #pragma unroll
  for (int i = 0; i < HA; ++i) q[i] = qp[i];
  float rs = 0.f, qq = 0.f;
  for (int p = 0; p < HA; ++p) {
    float t = 0.f;
    #pragma unroll
    for (int c = 0; c < HA; ++c) t += Gs[p*HA + c] * q[c];
    float qpv = qp[p];
    qq += qpv * t;
    rs += qpv * Ks[p];
  }
  float nrm = fmaxf(sqrtf(fmaxf(qq, 0.f)), 1e-12f);
  float s = rs / nrm;
  float dg = degree[m];
  float* fp = f0 + ((size_t)b*Mn + m)*DF;
  for (int r = 0; r < HR; ++r) {
    float v1 = s*tw[r] + tb[r];
    float v2 = dg*sw2[r] + sb2[r];
    fp[32 + r] = v1;
    fp[96 + r] = v2;
    f0T[((size_t)b*DF + 32 + r)*Mn + m] = f2h(v1);
    f0T[((size_t)b*DF + 96 + r)*Mn + m] = f2h(v2);
  }
}

// ---------------------------------------------------------------------------
// K5: GRU via MFMA. 16 seqs/block, 1 wave (64 thr), 250 blocks (4000=250*16).
// Per step: [16,32]h @ [32,96]Whh^T as 6 mfma_16x16x32_f16; gate math lane-local
// (C layout: seq=(lane>>4)*4+r, hid=(jt*16)+(lane&15)); h LDS round-trip fp16.
__global__ __launch_bounds__(64) void k_gru(
    const in_t* __restrict__ x, const in_t* __restrict__ Wih, const in_t* __restrict__ Whh,
    const in_t* __restrict__ bih, const in_t* __restrict__ bhh, float* __restrict__ lh)
{
  __shared__ float xs[Tn*16];             // [t][s]
  __shared__ unsigned short hlds[16*40];  // [seq][hid], stride 40 (pad 8) fp16
  int tid = threadIdx.x;
  int ln = tid & 15, lg = tid >> 4;
  int blk = blockIdx.x;
  // stage x: 1024 elems
  for (int idx = tid; idx < Tn*16; idx += 64) {
    int t = idx >> 4, s = idx & 15;
    int gseq = blk*16 + s;
    int b = gseq / Mn, m = gseq - b*Mn;
    xs[idx] = x[(size_t)b*Tn*Mn + (size_t)t*Mn + m];
  }
  for (int idx = tid; idx < 16*40; idx += 64) hlds[idx] = 0;
  // B fragments for Whh (row = gate out j, col k): lane holds j=base+ln, k=lg*8..+7
  half8 wfrag[3][2];
  #pragma unroll
  for (int g = 0; g < 3; ++g)
    #pragma unroll
    for (int jt = 0; jt < 2; ++jt) {
      const float* wp = Whh + (size_t)(g*32 + jt*16 + ln)*32 + lg*8;
      half8 v;
      #pragma unroll
      for (int e = 0; e < 8; ++e) v[e] = (_Float16)wp[e];
      wfrag[g][jt] = v;
    }
  // per-lane gate constants for hid = jt*16 + ln
  float wir[2], wiz[2], win_[2], brc[2], bzc[2], binc[2], bhnc[2];
  #pragma unroll
  for (int jt = 0; jt < 2; ++jt) {
    int hid = jt*16 + ln;
    wir[jt]  = Wih[hid];       wiz[jt] = Wih[32+hid];     win_[jt] = Wih[64+hid];
    brc[jt]  = bih[hid]    + bhh[hid];
    bzc[jt]  = bih[32+hid] + bhh[32+hid];
    binc[jt] = bih[64+hid];
    bhnc[jt] = bhh[64+hid];
  }
  float hprev[2][4];
  #pragma unroll
  for (int jt = 0; jt < 2; ++jt)
    #pragma unroll
    for (int r = 0; r < 4; ++r) hprev[jt][r] = 0.f;
  __syncthreads();

  for (int t = 0; t < Tn; ++t) {
    // A fragment: row(seq)=ln, k=lg*8..+7
    half8 a = *reinterpret_cast<const half8*>(&hlds[ln*40 + lg*8]);
    f32x4 accs[3][2];
    #pragma unroll
    for (int g = 0; g < 3; ++g)
      #pragma unroll
      for (int jt = 0; jt < 2; ++jt)
        accs[g][jt] = MFMAH(a, wfrag[g][jt], (f32x4)(0.f), 0, 0, 0);
    #pragma unroll
    for (int jt = 0; jt < 2; ++jt)
      #pragma unroll
      for (int r = 0; r < 4; ++r) {
        float xt = xs[t*16 + lg*4 + r];
        float rg = sigm(xt*wir[jt]  + brc[jt] + accs[0][jt][r]);
        float zg = sigm(xt*wiz[jt]  + bzc[jt] + accs[1][jt][r]);
        float ng = tanhfast(xt*win_[jt] + binc[jt] + rg*(accs[2][jt][r] + bhnc[jt]));
        float hn = (1.f - zg)*ng + zg*hprev[jt][r];
        hprev[jt][r] = hn;
        hlds[(lg*4 + r)*40 + jt*16 + ln] = f2h(hn);
      }
    __syncthreads();
  }
  #pragma unroll
  for (int jt = 0; jt < 2; ++jt)
    #pragma unroll
    for (int r = 0; r < 4; ++r)
      lh[(size_t)(blk*16 + lg*4 + r)*NHID + jt*16 + ln] = hprev[jt][r];
}

// ---------------------------------------------------------------------------
// K6: A1/A2
__global__ __launch_bounds__(256) void k_a1a2(
    const float* __restrict__ lh, const in_t* __restrict__ W1, const in_t* __restrict__ W2,
    float* __restrict__ A1, float* __restrict__ A2)
{
  __shared__ float w1[32*32], w2[32*32];
  int tid = threadIdx.x;
  for (int i = tid; i < 1024; i += 256) { w1[i] = W1[i]; w2[i] = W2[i]; }
  __syncthreads();
  int gid = blockIdx.x*256 + tid;
  if (gid >= Bz*Mn) return;
  float h[32];
  #pragma unroll
  for (int c = 0; c < 32; ++c) h[c] = lh[(size_t)gid*32 + c];
  float* a1 = A1 + (size_t)gid*32;
  float* a2 = A2 + (size_t)gid*32;
  for (int a = 0; a < 32; ++a) {
    float s1 = 0.f, s2 = 0.f;
    #pragma unroll
    for (int c = 0; c < 32; ++c) { s1 += h[c]*w1[a*32+c]; s2 += h[c]*w2[a*32+c]; }
    a1[a] = s1; a2[a] = s2;
  }
}

// ---------------------------------------------------------------------------
// K7: dmat
__global__ __launch_bounds__(256) void k_dmat(
    const in_t* __restrict__ dgate, const in_t* __restrict__ degree, float* __restrict__ dmat)
{
  int idx = blockIdx.x*256 + threadIdx.x;
  if (idx >= Mn*Mn) return;
  int i = idx / Mn, j = idx - i*Mn;
  dmat[idx] = sigm(dgate[idx] * degree[i] * degree[j]);
}

// ---------------------------------------------------------------------------
// K8: a[b,i,j] = V . elu(A1_i + A2_j + b1) + bv   (f32 — sign feeds binarize)
__global__ __launch_bounds__(256) void k_pair(
    const float* __restrict__ A1, const float* __restrict__ A2, const in_t* __restrict__ Vv,
    const in_t* __restrict__ b1, const in_t* __restrict__ bv, float* __restrict__ aB)
{
  __shared__ float a1s[16][33], a2s[16][33], vs[32], b1s[32];
  int b = blockIdx.z;
  int i0 = blockIdx.y*16, j0 = blockIdx.x*16;
  int tid = threadIdx.x;
  if (tid < 32) { vs[tid] = Vv[tid]; b1s[tid] = b1[tid]; }
  {
    int r = tid >> 5, c = tid & 31;
    for (int rr = r; rr < 16; rr += 8) {
      int i = i0 + rr, j = j0 + rr;
      a1s[rr][c] = (i < Mn) ? A1[((size_t)b*Mn + i)*32 + c] : 0.f;
      a2s[rr][c] = (j < Mn) ? A2[((size_t)b*Mn + j)*32 + c] : 0.f;
    }
  }
  __syncthreads();
  int ti = tid >> 4, tj = tid & 15;
  int i = i0 + ti, j = j0 + tj;
  if (i >= Mn || j >= Mn) return;
  float acc = 0.f;
  #pragma unroll
  for (int c = 0; c < 32; ++c) {
    float u = a1s[ti][c] + a2s[tj][c] + b1s[c];
    acc += eluf(u) * vs[c];
  }
  aB[((size_t)b*Mn + i)*Mn + j] = acc + bv[0];
}

// ---------------------------------------------------------------------------
// K9a: partial column sum-squares over row chunks; grid (4 jblk, 8 isplit, Bz)
__global__ __launch_bounds__(128) void k_cnorm(const float* __restrict__ aB, float* __restrict__ ssp)
{
  int jb = blockIdx.x, isp = blockIdx.y, b = blockIdx.z;
  int j = jb*128 + threadIdx.x;
  if (j >= Mn) return;
  int i0 = isp*63, iend = min(i0 + 63, Mn);
  const float* ap = aB + (size_t)b*Mn*Mn + j;
  float ss = 0.f;
  for (int i = i0; i < iend; ++i) { float v = ap[(size_t)i*Mn]; ss += v*v; }
  ssp[((size_t)isp*Bz + b)*Mn + j] = ss;
}

// K9b: finalize cinv
__global__ __launch_bounds__(256) void k_cfin(const float* __restrict__ ssp, float* __restrict__ cinv)
{
  int idx = blockIdx.x*256 + threadIdx.x;
  if (idx >= Bz*Mn) return;
  int b = idx / Mn, j = idx - b*Mn;
  float ss = 0.f;
  #pragma unroll
  for (int sp = 0; sp < 8; ++sp) ss += ssp[((size_t)sp*Bz + b)*Mn + j];
  cinv[idx] = 1.f / fmaxf(sqrtf(ss), 1e-12f);
}

// ---------------------------------------------------------------------------
// K10: c_gate GEMM via plain fp16 MFMA + fused adj epilogue -> adj_bin (f32)
__global__ __launch_bounds__(256) void k_cgemm(
    const float* __restrict__ aB, const float* __restrict__ cinv, const in_t* __restrict__ Wb,
    const in_t* __restrict__ wb, const in_t* __restrict__ adj_geo, const float* __restrict__ dmat,
    float* __restrict__ adjb)
{
  __shared__ unsigned short As[64*72], Bs[64*72];
  int b = blockIdx.z, i0 = blockIdx.y*64, j0 = blockIdx.x*64;
  int tid = threadIdx.x;
  const float* aRow = aB + (size_t)b*Mn*Mn;
  const float* civ = cinv + b*Mn;
  int w = tid >> 6, lane = tid & 63, ln = lane & 15, lg = lane >> 4;
  int wm = (w >> 1)*32, wn = (w & 1)*32;
  f32x4 acc[2][2];
  #pragma unroll
  for (int p = 0; p < 2; ++p)
    #pragma unroll
    for (int q = 0; q < 2; ++q) acc[p][q] = (f32x4)(0.f);

  for (int k0 = 0; k0 < 512; k0 += 64) {
    for (int idx = tid; idx < 2048; idx += 256) {
      int r = idx >> 5, cp = idx & 31;
      int i = i0 + r, k = k0 + 2*cp;
      unsigned int v = 0;
      if (i < Mn && k < Mn)
        v = pack2h(aRow[(size_t)i*Mn + k]*civ[k], aRow[(size_t)i*Mn + k + 1]*civ[k+1]);
      *reinterpret_cast<unsigned int*>(&As[r*72 + 2*cp]) = v;
    }
    for (int idx = tid; idx < 2048; idx += 256) {
      int c = idx & 63, rp = idx >> 6;
      int j = j0 + c, k = k0 + 2*rp;
      unsigned int v = 0;
      if (j < Mn && k < Mn)
        v = pack2h(Wb[(size_t)k*Mn + j], Wb[(size_t)(k+1)*Mn + j]);
      *reinterpret_cast<unsigned int*>(&Bs[c*72 + 2*rp]) = v;
    }
    __syncthreads();
    #pragma unroll
    for (int kk = 0; kk < 2; ++kk) {
      half8 a0 = *reinterpret_cast<const half8*>(&As[(wm + 0  + ln)*72 + kk*32 + lg*8]);
      half8 a1 = *reinterpret_cast<const half8*>(&As[(wm + 16 + ln)*72 + kk*32 + lg*8]);
      half8 b0 = *reinterpret_cast<const half8*>(&Bs[(wn + 0  + ln)*72 + kk*32 + lg*8]);
      half8 b1 = *reinterpret_cast<const half8*>(&Bs[(wn + 16 + ln)*72 + kk*32 + lg*8]);
      acc[0][0] = MFMAH(a0, b0, acc[0][0], 0, 0, 0);
      acc[0][1] = MFMAH(a0, b1, acc[0][1], 0, 0, 0);
      acc[1][0] = MFMAH(a1, b0, acc[1][0], 0, 0, 0);
      acc[1][1] = MFMAH(a1, b1, acc[1][1], 0, 0, 0);
    }
    __syncthreads();
  }
  float wbv = wb[0];
  #pragma unroll
  for (int mt = 0; mt < 2; ++mt)
    #pragma unroll
    for (int nt = 0; nt < 2; ++nt)
      #pragma unroll
      for (int r = 0; r < 4; ++r) {
        int i = i0 + wm + mt*16 + lg*4 + r;
        int j = j0 + wn + nt*16 + ln;
        if (i < Mn && j < Mn) {
          float cg = sigm(acc[mt][nt][r] + wbv);
          float av = aRow[(size_t)i*Mn + j]*civ[j];
          float ag = adj_geo[(size_t)i*Mn + j];
          float adjf = ag*cg + av*(1.f - cg) + dmat[(size_t)i*Mn + j]*ag;
          adjb[((size_t)b*Mn + i)*Mn + j] = (adjf > 0.f) ? 1.f : adjf;
        }
      }
}

// ---------------------------------------------------------------------------
// K11: laplace row-normalize -> fp16 lapB
__global__ __launch_bounds__(256) void k_lap(const float* __restrict__ adjb, unsigned short* __restrict__ lapB)
{
  int b = blockIdx.y, i = blockIdx.x;
  const float* row = adjb + ((size_t)b*Mn + i)*Mn;
  int tid = threadIdx.x;
  float s = 0.f;
  for (int j = tid; j < Mn; j += 256) s += row[j];
  __shared__ float red[8];
  int lane = tid & 63, wv = tid >> 6;
  #pragma unroll
  for (int off = 32; off; off >>= 1) s += __shfl_down(s, off);
  if (lane == 0) red[wv] = s;
  __syncthreads();
  if (tid == 0) {
    float d = red[0] + red[1] + red[2] + red[3];
    red[4] = (d > 0.f) ? 1.f/d : 0.f;
  }
  __syncthreads();
  float inv = red[4];
  unsigned short* lrow = lapB + ((size_t)b*Mn + i)*Mn;
  for (int j = tid; j < Mn; j += 256) lrow[j] = f2h(row[j]*inv);
}

// ---------------------------------------------------------------------------
// K12: spmm via fp16 MFMA: tmpB[b][i][d] = lapB @ fT^T
__global__ __launch_bounds__(256) void k_spmm(
    const unsigned short* __restrict__ lapB, const unsigned short* __restrict__ fT,
    unsigned short* __restrict__ tmpB)
{
  __shared__ unsigned short As[64*72], Bs[64*72];
  int b = blockIdx.z, i0 = blockIdx.y*64, j0 = blockIdx.x*64;
  int tid = threadIdx.x;
  int w = tid >> 6, lane = tid & 63, ln = lane & 15, lg = lane >> 4;
  int wm = (w >> 1)*32, wn = (w & 1)*32;
  f32x4 acc[2][2];
  #pragma unroll
  for (int p = 0; p < 2; ++p)
    #pragma unroll
    for (int q = 0; q < 2; ++q) acc[p][q] = (f32x4)(0.f);

  for (int k0 = 0; k0 < 512; k0 += 64) {
    for (int idx = tid; idx < 2048; idx += 256) {
      int r = idx >> 5, cp = idx & 31;
      int i = i0 + r, k = k0 + 2*cp;
      unsigned int v = 0;
      if (i < Mn && k < Mn)
        v = *reinterpret_cast<const unsigned int*>(&lapB[((size_t)b*Mn + i)*Mn + k]);
      *reinterpret_cast<unsigned int*>(&As[r*72 + 2*cp]) = v;
    }
    for (int idx = tid; idx < 2048; idx += 256) {
      int r = idx >> 5, cp = idx & 31;
      int d = j0 + r, k = k0 + 2*cp;
      unsigned int v = 0;
      if (d < DF && k < Mn)
        v = *reinterpret_cast<const unsigned int*>(&fT[((size_t)b*DF + d)*Mn + k]);
      *reinterpret_cast<unsigned int*>(&Bs[r*72 + 2*cp]) = v;
    }
    __syncthreads();
    #pragma unroll
    for (int kk = 0; kk < 2; ++kk) {
      half8 a0 = *reinterpret_cast<const half8*>(&As[(wm + 0  + ln)*72 + kk*32 + lg*8]);
      half8 a1 = *reinterpret_cast<const half8*>(&As[(wm + 16 + ln)*72 + kk*32 + lg*8]);
      half8 b0 = *reinterpret_cast<const half8*>(&Bs[(wn + 0  + ln)*72 + kk*32 + lg*8]);
      half8 b1 = *reinterpret_cast<const half8*>(&Bs[(wn + 16 + ln)*72 + kk*32 + lg*8]);
      acc[0][0] = MFMAH(a0, b0, acc[0][0], 0, 0, 0);
      acc[0][1] = MFMAH(a0, b1, acc[0][1], 0, 0, 0);
      acc[1][0] = MFMAH(a1, b0, acc[1][0], 0, 0, 0);
      acc[1][1] = MFMAH(a1, b1, acc[1][1], 0, 0, 0);
    }
    __syncthreads();
  }
  #pragma unroll
  for (int mt = 0; mt < 2; ++mt)
    #pragma unroll
    for (int nt = 0; nt < 2; ++nt)
      #pragma unroll
      for (int r = 0; r < 4; ++r) {
        int i = i0 + wm + mt*16 + lg*4 + r;
        int j = j0 + wn + nt*16 + ln;
        if (i < Mn && j < DF)
          tmpB[((size_t)b*Mn + i)*DF + j] = f2h(acc[mt][nt][r]);
      }
}

// ---------------------------------------------------------------------------
// K13: dense: fout = elu(tmpB @ gnn_w + bias); optional fp16 transposed copy
__global__ __launch_bounds__(256) void k_dense(
    const unsigned short* __restrict__ tmpB, const in_t* __restrict__ W, const in_t* __restrict__ bias,
    float* __restrict__ fout, unsigned short* __restrict__ foutT)
{
  __shared__ unsigned short As[64*72], Bs[64*72];
  __shared__ float bs[64];
  int i0 = blockIdx.y*64, j0 = blockIdx.x*64;
  int tid = threadIdx.x;
  if (tid < 64) bs[tid] = (j0 + tid < DF) ? bias[j0 + tid] : 0.f;
  int w = tid >> 6, lane = tid & 63, ln = lane & 15, lg = lane >> 4;
  int wm = (w >> 1)*32, wn = (w & 1)*32;
  const int NR = Bz*Mn;
  f32x4 acc[2][2];
  #pragma unroll
  for (int p = 0; p < 2; ++p)
    #pragma unroll
    for (int q = 0; q < 2; ++q) acc[p][q] = (f32x4)(0.f);

  for (int k0 = 0; k0 < 192; k0 += 64) {
    for (int idx = tid; idx < 2048; idx += 256) {
      int r = idx >> 5, cp = idx & 31;
      int i = i0 + r, k = k0 + 2*cp;
      unsigned int v = 0;
      if (i < NR && k < DF)
        v = *reinterpret_cast<const unsigned int*>(&tmpB[(size_t)i*DF + k]);
      *reinterpret_cast<unsigned int*>(&As[r*72 + 2*cp]) = v;
    }
    for (int idx = tid; idx < 2048; idx += 256) {
      int c = idx & 63, rp = idx >> 6;
      int j = j0 + c, k = k0 + 2*rp;
      unsigned int v = 0;
      if (j < DF && k < DF)
        v = pack2h(W[(size_t)k*DF + j], W[(size_t)(k+1)*DF + j]);
      *reinterpret_cast<unsigned int*>(&Bs[c*72 + 2*rp]) = v;
    }
    __syncthreads();
    #pragma unroll
    for (int kk = 0; kk < 2; ++kk) {
      half8 a0 = *reinterpret_cast<const half8*>(&As[(wm + 0  + ln)*72 + kk*32 + lg*8]);
      half8 a1 = *reinterpret_cast<const half8*>(&As[(wm + 16 + ln)*72 + kk*32 + lg*8]);
      half8 b0 = *reinterpret_cast<const half8*>(&Bs[(wn + 0  + ln)*72 + kk*32 + lg*8]);
      half8 b1 = *reinterpret_cast<const half8*>(&Bs[(wn + 16 + ln)*72 + kk*32 + lg*8]);
      acc[0][0] = MFMAH(a0, b0, acc[0][0], 0, 0, 0);
      acc[0][1] = MFMAH(a0, b1, acc[0][1], 0, 0, 0);
      acc[1][0] = MFMAH(a1, b0, acc[1][0], 0, 0, 0);
      acc[1][1] = MFMAH(a1, b1, acc[1][1], 0, 0, 0);
    }
    __syncthreads();
  }
  #pragma unroll
  for (int mt = 0; mt < 2; ++mt)
    #pragma unroll
    for (int nt = 0; nt < 2; ++nt)
      #pragma unroll
      for (int r = 0; r < 4; ++r) {
        int i = i0 + wm + mt*16 + lg*4 + r;
        int jl = wn + nt*16 + ln;
        int j = j0 + jl;
        if (i < NR && j < DF) {
          float val = eluf(acc[mt][nt][r] + bs[jl]);
          fout[(size_t)i*DF + j] = val;
          if (foutT) {
            int bb = i / Mn, mm = i - bb*Mn;
            foutT[((size_t)bb*DF + j)*Mn + mm] = f2h(val);
          }
        }
      }
}

// ---------------------------------------------------------------------------
// K14: output projection
__global__ __launch_bounds__(256) void k_out(
    const float* __restrict__ f0, const float* __restrict__ f1, const float* __restrict__ f2,
    const float* __restrict__ lh, const in_t* __restrict__ ow, const in_t* __restrict__ ob,
    float* __restrict__ outp)
{
  __shared__ float w[FINALC];
  int tid = threadIdx.x;
  for (int i = tid; i < FINALC; i += 256) w[i] = ow[i];
  __syncthreads();
  int gid = blockIdx.x*256 + tid;
  if (gid >= Bz*Mn) return;
  float s = ob[0];
  const float* p0 = f0 + (size_t)gid*DF;
  const float* p1 = f1 + (size_t)gid*DF;
  const float* p2 = f2 + (size_t)gid*DF;
  const float* pl = lh + (size_t)gid*NHID;
  for (int c = 0; c < DF; ++c) s += p0[c]*w[c];
  for (int c = 0; c < DF; ++c) s += p1[c]*w[DF + c];
  for (int c = 0; c < DF; ++c) s += p2[c]*w[2*DF + c];
  for (int c = 0; c < NHID; ++c) s += pl[c]*w[3*DF + c];
  outp[gid] = s;
}

// ---------------------------------------------------------------------------
extern "C" void kernel_launch(void* const* d_in, const int* in_sizes, int n_in,
                              void* d_out, int out_size, void* d_ws, size_t ws_size,
                              hipStream_t stream)
{
  const in_t* x       = (const in_t*)d_in[0];
  const in_t* adj_geo = (const in_t*)d_in[1];
  const in_t* degree  = (const in_t*)d_in[2];
  const in_t* conv_s_w= (const in_t*)d_in[3];
  const in_t* conv_s_b= (const in_t*)d_in[4];
  const in_t* conv_l_w= (const in_t*)d_in[5];
  const in_t* conv_l_b= (const in_t*)d_in[6];
  const in_t* WQ_w    = (const in_t*)d_in[7];
  const in_t* WQ_b    = (const in_t*)d_in[8];
  const in_t* WK_w    = (const in_t*)d_in[9];
  const in_t* WK_b    = (const in_t*)d_in[10];
  const in_t* tenc_w  = (const in_t*)d_in[11];
  const in_t* tenc_b  = (const in_t*)d_in[12];
  const in_t* senc_w  = (const in_t*)d_in[13];
  const in_t* senc_b  = (const in_t*)d_in[14];
  const in_t* gru_Wih = (const in_t*)d_in[15];
  const in_t* gru_Whh = (const in_t*)d_in[16];
  const in_t* gru_bih = (const in_t*)d_in[17];
  const in_t* gru_bhh = (const in_t*)d_in[18];
  const in_t* Vv      = (const in_t*)d_in[19];
  const in_t* W1      = (const in_t*)d_in[20];
  const in_t* W2      = (const in_t*)d_in[21];
  const in_t* Wb      = (const in_t*)d_in[22];
  const in_t* bv      = (const in_t*)d_in[23];
  const in_t* b1      = (const in_t*)d_in[24];
  const in_t* wb      = (const in_t*)d_in[25];
  const in_t* d_gate  = (const in_t*)d_in[26];
  const in_t* gnn_w   = (const in_t*)d_in[27];
  const in_t* gnn_b   = (const in_t*)d_in[28];
  const in_t* out_w   = (const in_t*)d_in[29];
  const in_t* out_b   = (const in_t*)d_in[30];
  float* out = (float*)d_out;

  // workspace carve-up (float offsets)
  float* ws   = (float*)d_ws;
  float* hSC  = ws;                    // 128000
  float* Qb   = ws + 128000;           // 256000
  float* Ktb  = ws + 384000;           // 256000
  float* lh   = ws + 673280;           // 128000
  float* A1   = ws + 801280;           // 128000
  float* A2   = ws + 929280;           // 128000
  float* aB   = ws + 1057280;          // 2000000 (dead after k_cgemm; lapB overlays)
  float* cinv = ws + 3057280;          // 4000
  float* adjb = ws + 3061280;          // 2000000
  float* dmat = ws + 5061280;          // 250000
  float* f0   = ws + 5311280;          // 640000
  float* f1   = ws + 5951280;          // 640000
  float* f2   = ws + 6591280;          // 640000
  unsigned short* f0T  = (unsigned short*)(ws + 7231280);  // 640000 fp16
  unsigned short* tmpB = (unsigned short*)(ws + 7551280);  // 640000 fp16
  unsigned short* f1T  = (unsigned short*)(ws + 7871280);  // 640000 fp16
  unsigned short* lapB = (unsigned short*)aB;              // fp16 overlay (aB dead after cgemm)
  // transient partials in adjb region (adjb written only later by k_cgemm):
  float* Gpart = adjb;                 // 8*8*4096 = 262144
  float* Kpart = adjb + 262144;        // 8*8*64   = 4096
  float* ssp   = adjb + 266240;        // 8*8*500  = 32000

  k_conv<<<dim3(4, Bz), 128, 0, stream>>>(x, conv_s_w, conv_s_b, conv_l_w, conv_l_b, hSC, f0, f0T);
  k_qk<<<dim3(16), 256, 0, stream>>>(hSC, WQ_w, WQ_b, WK_w, WK_b, Qb, Ktb);
  k_gram<<<dim3(GSPLIT, Bz), 256, 0, stream>>>(Ktb, Gpart, Kpart);
  k_sglob<<<dim3(2, Bz), 256, 0, stream>>>(Qb, Gpart, Kpart, degree, tenc_w, tenc_b, senc_w, senc_b, f0, f0T);
  k_gru<<<dim3(250), 64, 0, stream>>>(x, gru_Wih, gru_Whh, gru_bih, gru_bhh, lh);
  k_a1a2<<<dim3(16), 256, 0, stream>>>(lh, W1, W2, A1, A2);
  k_dmat<<<dim3((Mn*Mn + 255)/256), 256, 0, stream>>>(d_gate, degree, dmat);
  k_pair<<<dim3(32, 32, Bz), 256, 0, stream>>>(A1, A2, Vv, b1, bv, aB);
  k_cnorm<<<dim3(4, 8, Bz), 128, 0, stream>>>(aB, ssp);
  k_cfin<<<dim3(16), 256, 0, stream>>>(ssp, cinv);
  k_cgemm<<<dim3(8, 8, Bz), 256, 0, stream>>>(aB, cinv, Wb, wb, adj_geo, dmat, adjb);
  k_lap<<<dim3(Mn, Bz), 256, 0, stream>>>(adjb, lapB);
  // GNN layer 0
  k_spmm<<<dim3(3, 8, Bz), 256, 0, stream>>>(lapB, f0T, tmpB);
  k_dense<<<dim3(3, 63), 256, 0, stream>>>(tmpB, gnn_w, gnn_b, f1, f1T);
  // GNN layer 1
  k_spmm<<<dim3(3, 8, Bz), 256, 0, stream>>>(lapB, f1T, tmpB);
  k_dense<<<dim3(3, 63), 256, 0, stream>>>(tmpB, gnn_w + DF*DF, gnn_b + DF, f2, (unsigned short*)nullptr);
  k_out<<<dim3(16), 256, 0, stream>>>(f0, f1, f2, lh, out_w, out_b, out);
}

// Round 8
// 459.818 us; speedup vs baseline: 1.0091x; 1.0060x over previous
//
#include <hip/hip_runtime.h>
#include <hip/hip_bf16.h>

// Problem constants
#define Bz 8
#define Tn 64
#define Mn 500
#define KC 16
#define HA 64
#define HR 64
#define NHID 32
#define DF 160
#define FINALC 512
#define GSPLIT 8

typedef float in_t;   // reference dtypes are all float32
typedef __attribute__((ext_vector_type(8))) _Float16 half8;
typedef __attribute__((ext_vector_type(4))) float f32x4;
#define MFMAH __builtin_amdgcn_mfma_f32_16x16x32_f16

__device__ __forceinline__ float sigm(float x){ return 1.0f/(1.0f+__expf(-x)); }
__device__ __forceinline__ float tanhfast(float x){ float e=__expf(2.0f*x); return 1.0f-2.0f/(e+1.0f); }
__device__ __forceinline__ float eluf(float x){ return x>0.0f? x : (__expf(x)-1.0f); }
__device__ __forceinline__ unsigned short f2h(float f){
  _Float16 h = (_Float16)f;
  return *reinterpret_cast<unsigned short*>(&h);
}
__device__ __forceinline__ unsigned int pack2h(float a, float b){
  return (unsigned int)f2h(a) | ((unsigned int)f2h(b) << 16);
}

// ---------------------------------------------------------------------------
// K1: per-node convs -> h_SC (relu), writes f0[0:32] (f32) and f0T fp16
__global__ __launch_bounds__(128) void k_conv(
    const in_t* __restrict__ x, const in_t* __restrict__ wsw, const in_t* __restrict__ wsb,
    const in_t* __restrict__ wlw, const in_t* __restrict__ wlb,
    float* __restrict__ hSC, float* __restrict__ f0, unsigned short* __restrict__ f0T)
{
  __shared__ float sw[KC*Tn];
  __shared__ float lw[KC*Tn];
  __shared__ float sb[KC], lb[KC];
  int tid = threadIdx.x;
  for (int idx = tid; idx < KC*Tn; idx += blockDim.x) {
    sw[idx] = wsw[idx];
    int k = idx >> 6, t = idx & 63;
    lw[idx] = 0.5f * wlw[k*32 + (t>>1)];
  }
  if (tid < KC) { sb[tid] = wsb[tid]; lb[tid] = wlb[tid]; }
  __syncthreads();
  int m = blockIdx.x * blockDim.x + tid;
  int b = blockIdx.y;
  if (m >= Mn) return;
  float xv[Tn];
  const in_t* xp = x + (size_t)b*Tn*Mn + m;
  #pragma unroll
  for (int t = 0; t < Tn; ++t) xv[t] = xp[t*Mn];
  float* hp = hSC + ((size_t)b*Mn + m) * (2*KC);
  float* fp = f0  + ((size_t)b*Mn + m) * DF;
  for (int k = 0; k < KC; ++k) {
    float s = 0.f, l = 0.f;
    #pragma unroll
    for (int t = 0; t < Tn; ++t) { s += xv[t]*sw[k*Tn+t]; l += xv[t]*lw[k*Tn+t]; }
    float vs = fmaxf(s + sb[k], 0.f);
    float vl = fmaxf(l + lb[k], 0.f);
    hp[k] = vs; hp[KC+k] = vl;
    fp[k] = vs; fp[KC+k] = vl;
    f0T[((size_t)b*DF + k)*Mn + m]      = f2h(vs);
    f0T[((size_t)b*DF + KC + k)*Mn + m] = f2h(vl);
  }
}

// ---------------------------------------------------------------------------
// K2: Q/K projections
__global__ __launch_bounds__(256) void k_qk(
    const float* __restrict__ hSC, const in_t* __restrict__ WQw, const in_t* __restrict__ WQb,
    const in_t* __restrict__ WKw, const in_t* __restrict__ WKb,
    float* __restrict__ Q, float* __restrict__ Kt)
{
  __shared__ float wq[HA*32], wk[HA*32], bq[HA], bk[HA];
  int tid = threadIdx.x;
  for (int i = tid; i < HA*32; i += 256) { wq[i] = WQw[i]; wk[i] = WKw[i]; }
  for (int i = tid; i < HA; i += 256) { bq[i] = WQb[i]; bk[i] = WKb[i]; }
  __syncthreads();
  int gid = blockIdx.x*256 + tid;
  if (gid >= Bz*Mn) return;
  float h[32];
  const float* hp = hSC + (size_t)gid*32;
  #pragma unroll
  for (int c = 0; c < 32; ++c) h[c] = hp[c];
  float* qp = Q + (size_t)gid*HA;
  float* kp = Kt + (size_t)gid*HA;
  for (int a = 0; a < HA; ++a) {
    float aq = bq[a], ak = bk[a];
    #pragma unroll
    for (int c = 0; c < 32; ++c) { aq += h[c]*wq[a*32+c]; ak += h[c]*wk[a*32+c]; }
    qp[a] = aq; kp[a] = ak;
  }
}

// ---------------------------------------------------------------------------
// K3: split-K partial Gram
__global__ __launch_bounds__(256) void k_gram(
    const float* __restrict__ Kt, float* __restrict__ Gpart, float* __restrict__ Kpart)
{
  int split = blockIdx.x, b = blockIdx.y;
  int tid = threadIdx.x;
  __shared__ float L[64][HA];
  int m0 = split*63;
  int mend = min(m0 + 63, Mn);
  int p = tid & 63;
  int q0 = (tid >> 6) * 16;
  float acc[16];
  #pragma unroll
  for (int e = 0; e < 16; ++e) acc[e] = 0.f;
  for (int idx = tid; idx < 64*HA; idx += 256) {
    int r = idx >> 6, c = idx & 63;
    int m = m0 + r;
    L[r][c] = (m < mend) ? Kt[((size_t)b*Mn + m)*HA + c] : 0.f;
  }
  __syncthreads();
  float ks = 0.f;
  #pragma unroll 4
  for (int r = 0; r < 63; ++r) {
    float lp = L[r][p];
    if (tid < 64) ks += lp;
    #pragma unroll
    for (int e = 0; e < 16; ++e) acc[e] += lp * L[r][q0+e];
  }
  float* gp = Gpart + ((size_t)split*Bz + b)*HA*HA;
  #pragma unroll
  for (int e = 0; e < 16; ++e) gp[p*HA + q0 + e] = acc[e];
  if (tid < 64) Kpart[((size_t)split*Bz + b)*HA + tid] = ks;
}

// ---------------------------------------------------------------------------
// K4: s-glob + h_L (sums the GSPLIT partials on load), writes f0[32:160]
__global__ __launch_bounds__(256) void k_sglob(
    const float* __restrict__ Q, const float* __restrict__ Gpart, const float* __restrict__ Kpart,
    const in_t* __restrict__ degree, const in_t* __restrict__ tencw, const in_t* __restrict__ tencb,
    const in_t* __restrict__ sencw, const in_t* __restrict__ sencb,
    float* __restrict__ f0, unsigned short* __restrict__ f0T)
{
  int b = blockIdx.y;
  __shared__ float Gs[HA*HA];
  __shared__ float Ks[HA], tw[HR], tb[HR], sw2[HR], sb2[HR];
  int tid = threadIdx.x;
  for (int i = tid; i < HA*HA; i += 256) {
    float s = 0.f;
    #pragma unroll
    for (int sp = 0; sp < GSPLIT; ++sp) s += Gpart[((size_t)sp*Bz + b)*HA*HA + i];
    Gs[i] = s;
  }
  for (int i = tid; i < HA; i += 256) {
    float s = 0.f;
    #pragma unroll
    for (int sp = 0; sp < GSPLIT; ++sp) s += Kpart[((size_t)sp*Bz + b)*HA + i];
    Ks[i] = s;
    tw[i] = tencw[i]; tb[i] = tencb[i];
    sw2[i] = sencw[i]; sb2[i] = sencb[i];
  }
  __syncthreads();
  int m = blockIdx.x*256 + tid;
  if (m >= Mn) return;
  const float* qp = Q + ((size_t)b*Mn + m)*HA;
  float q[HA];
  #pragma unroll
  for (int i = 0; i < HA; ++i) q[i] = qp[i];
  float rs = 0.f, qq = 0.f;
  for (int p = 0; p < HA; ++p) {
    float t = 0.f;
    #pragma unroll
    for (int c = 0; c < HA; ++c) t += Gs[p*HA + c] * q[c];
    float qpv = qp[p];
    qq += qpv * t;
    rs += qpv * Ks[p];
  }
  float nrm = fmaxf(sqrtf(fmaxf(qq, 0.f)), 1e-12f);
  float s = rs / nrm;
  float dg = degree[m];
  float* fp = f0 + ((size_t)b*Mn + m)*DF;
  for (int r = 0; r < HR; ++r) {
    float v1 = s*tw[r] + tb[r];
    float v2 = dg*sw2[r] + sb2[r];
    fp[32 + r] = v1;
    fp[96 + r] = v2;
    f0T[((size_t)b*DF + 32 + r)*Mn + m] = f2h(v1);
    f0T[((size_t)b*DF + 96 + r)*Mn + m] = f2h(v2);
  }
}

// ---------------------------------------------------------------------------
// K5: GRU — 64 lanes per sequence (2 lanes per hidden unit, split-j halves),
// 4 seqs per 256-thr block, 1000 blocks -> 4000 waves (~49% occupancy).
__global__ __launch_bounds__(256) void k_gru(
    const in_t* __restrict__ x, const in_t* __restrict__ Wih, const in_t* __restrict__ Whh,
    const in_t* __restrict__ bih, const in_t* __restrict__ bhh, float* __restrict__ lh)
{
  int tid = threadIdx.x;
  int lane = tid & 63;
  int hid = lane & 31;
  int half = lane >> 5;
  int seq = blockIdx.x*4 + (tid >> 6);
  int b = seq / Mn, m = seq - b*Mn;
  float wr[16], wz[16], wn[16];
  #pragma unroll
  for (int jj = 0; jj < 16; ++jj) {
    int j = half*16 + jj;
    wr[jj] = Whh[(size_t)hid*32 + j];
    wz[jj] = Whh[(size_t)(32+hid)*32 + j];
    wn[jj] = Whh[(size_t)(64+hid)*32 + j];
  }
  float wir = Wih[hid], wiz = Wih[32+hid], win = Wih[64+hid];
  float bir = bih[hid], biz = bih[32+hid], bin_ = bih[64+hid];
  float bhr = bhh[hid], bhz = bhh[32+hid], bhn = bhh[64+hid];
  float h = 0.f;     // lane 'hid' holds h[hid]; dup in half=1
  const in_t* xp = x + (size_t)b*Tn*Mn + m;
  for (int t = 0; t < Tn; ++t) {
    float xt = xp[(size_t)t*Mn];
    float gr = 0.f, gz = 0.f, gn = 0.f;
    #pragma unroll
    for (int jj = 0; jj < 16; ++jj) {
      float hj = __shfl(h, half*16 + jj, 64);
      gr += wr[jj]*hj; gz += wz[jj]*hj; gn += wn[jj]*hj;
    }
    gr += __shfl_xor(gr, 32, 64);
    gz += __shfl_xor(gz, 32, 64);
    gn += __shfl_xor(gn, 32, 64);
    float r = sigm(xt*wir + bir + gr + bhr);
    float z = sigm(xt*wiz + biz + gz + bhz);
    float n = tanhfast(xt*win + bin_ + r*(gn + bhn));
    h = (1.f - z)*n + z*h;
  }
  if (half == 0) lh[(size_t)seq*NHID + hid] = h;
}

// ---------------------------------------------------------------------------
// K6: A1/A2
__global__ __launch_bounds__(256) void k_a1a2(
    const float* __restrict__ lh, const in_t* __restrict__ W1, const in_t* __restrict__ W2,
    float* __restrict__ A1, float* __restrict__ A2)
{
  __shared__ float w1[32*32], w2[32*32];
  int tid = threadIdx.x;
  for (int i = tid; i < 1024; i += 256) { w1[i] = W1[i]; w2[i] = W2[i]; }
  __syncthreads();
  int gid = blockIdx.x*256 + tid;
  if (gid >= Bz*Mn) return;
  float h[32];
  #pragma unroll
  for (int c = 0; c < 32; ++c) h[c] = lh[(size_t)gid*32 + c];
  float* a1 = A1 + (size_t)gid*32;
  float* a2 = A2 + (size_t)gid*32;
  for (int a = 0; a < 32; ++a) {
    float s1 = 0.f, s2 = 0.f;
    #pragma unroll
    for (int c = 0; c < 32; ++c) { s1 += h[c]*w1[a*32+c]; s2 += h[c]*w2[a*32+c]; }
    a1[a] = s1; a2[a] = s2;
  }
}

// ---------------------------------------------------------------------------
// K7: dmat
__global__ __launch_bounds__(256) void k_dmat(
    const in_t* __restrict__ dgate, const in_t* __restrict__ degree, float* __restrict__ dmat)
{
  int idx = blockIdx.x*256 + threadIdx.x;
  if (idx >= Mn*Mn) return;
  int i = idx / Mn, j = idx - i*Mn;
  dmat[idx] = sigm(dgate[idx] * degree[i] * degree[j]);
}

// ---------------------------------------------------------------------------
// K8: a[b,i,j] = V . elu(A1_i + A2_j + b1) + bv   (f32 — sign feeds binarize)
__global__ __launch_bounds__(256) void k_pair(
    const float* __restrict__ A1, const float* __restrict__ A2, const in_t* __restrict__ Vv,
    const in_t* __restrict__ b1, const in_t* __restrict__ bv, float* __restrict__ aB)
{
  __shared__ float a1s[16][33], a2s[16][33], vs[32], b1s[32];
  int b = blockIdx.z;
  int i0 = blockIdx.y*16, j0 = blockIdx.x*16;
  int tid = threadIdx.x;
  if (tid < 32) { vs[tid] = Vv[tid]; b1s[tid] = b1[tid]; }
  {
    int r = tid >> 5, c = tid & 31;
    for (int rr = r; rr < 16; rr += 8) {
      int i = i0 + rr, j = j0 + rr;
      a1s[rr][c] = (i < Mn) ? A1[((size_t)b*Mn + i)*32 + c] : 0.f;
      a2s[rr][c] = (j < Mn) ? A2[((size_t)b*Mn + j)*32 + c] : 0.f;
    }
  }
  __syncthreads();
  int ti = tid >> 4, tj = tid & 15;
  int i = i0 + ti, j = j0 + tj;
  if (i >= Mn || j >= Mn) return;
  float acc = 0.f;
  #pragma unroll
  for (int c = 0; c < 32; ++c) {
    float u = a1s[ti][c] + a2s[tj][c] + b1s[c];
    acc += eluf(u) * vs[c];
  }
  aB[((size_t)b*Mn + i)*Mn + j] = acc + bv[0];
}

// ---------------------------------------------------------------------------
// K9a: partial column sum-squares over row chunks; grid (4 jblk, 8 isplit, Bz)
__global__ __launch_bounds__(128) void k_cnorm(const float* __restrict__ aB, float* __restrict__ ssp)
{
  int jb = blockIdx.x, isp = blockIdx.y, b = blockIdx.z;
  int j = jb*128 + threadIdx.x;
  if (j >= Mn) return;
  int i0 = isp*63, iend = min(i0 + 63, Mn);
  const float* ap = aB + (size_t)b*Mn*Mn + j;
  float ss = 0.f;
  for (int i = i0; i < iend; ++i) { float v = ap[(size_t)i*Mn]; ss += v*v; }
  ssp[((size_t)isp*Bz + b)*Mn + j] = ss;
}

// K9b: finalize cinv
__global__ __launch_bounds__(256) void k_cfin(const float* __restrict__ ssp, float* __restrict__ cinv)
{
  int idx = blockIdx.x*256 + threadIdx.x;
  if (idx >= Bz*Mn) return;
  int b = idx / Mn, j = idx - b*Mn;
  float ss = 0.f;
  #pragma unroll
  for (int sp = 0; sp < 8; ++sp) ss += ssp[((size_t)sp*Bz + b)*Mn + j];
  cinv[idx] = 1.f / fmaxf(sqrtf(ss), 1e-12f);
}

// ---------------------------------------------------------------------------
// K10: c_gate GEMM via plain fp16 MFMA + fused adj epilogue -> adj_bin (f32)
__global__ __launch_bounds__(256) void k_cgemm(
    const float* __restrict__ aB, const float* __restrict__ cinv, const in_t* __restrict__ Wb,
    const in_t* __restrict__ wb, const in_t* __restrict__ adj_geo, const float* __restrict__ dmat,
    float* __restrict__ adjb)
{
  __shared__ unsigned short As[64*72], Bs[64*72];
  int b = blockIdx.z, i0 = blockIdx.y*64, j0 = blockIdx.x*64;
  int tid = threadIdx.x;
  const float* aRow = aB + (size_t)b*Mn*Mn;
  const float* civ = cinv + b*Mn;
  int w = tid >> 6, lane = tid & 63, ln = lane & 15, lg = lane >> 4;
  int wm = (w >> 1)*32, wn = (w & 1)*32;
  f32x4 acc[2][2];
  #pragma unroll
  for (int p = 0; p < 2; ++p)
    #pragma unroll
    for (int q = 0; q < 2; ++q) acc[p][q] = (f32x4)(0.f);

  for (int k0 = 0; k0 < 512; k0 += 64) {
    for (int idx = tid; idx < 2048; idx += 256) {
      int r = idx >> 5, cp = idx & 31;
      int i = i0 + r, k = k0 + 2*cp;
      unsigned int v = 0;
      if (i < Mn && k < Mn)
        v = pack2h(aRow[(size_t)i*Mn + k]*civ[k], aRow[(size_t)i*Mn + k + 1]*civ[k+1]);
      *reinterpret_cast<unsigned int*>(&As[r*72 + 2*cp]) = v;
    }
    for (int idx = tid; idx < 2048; idx += 256) {
      int c = idx & 63, rp = idx >> 6;
      int j = j0 + c, k = k0 + 2*rp;
      unsigned int v = 0;
      if (j < Mn && k < Mn)
        v = pack2h(Wb[(size_t)k*Mn + j], Wb[(size_t)(k+1)*Mn + j]);
      *reinterpret_cast<unsigned int*>(&Bs[c*72 + 2*rp]) = v;
    }
    __syncthreads();
    #pragma unroll
    for (int kk = 0; kk < 2; ++kk) {
      half8 a0 = *reinterpret_cast<const half8*>(&As[(wm + 0  + ln)*72 + kk*32 + lg*8]);
      half8 a1 = *reinterpret_cast<const half8*>(&As[(wm + 16 + ln)*72 + kk*32 + lg*8]);
      half8 b0 = *reinterpret_cast<const half8*>(&Bs[(wn + 0  + ln)*72 + kk*32 + lg*8]);
      half8 b1 = *reinterpret_cast<const half8*>(&Bs[(wn + 16 + ln)*72 + kk*32 + lg*8]);
      acc[0][0] = MFMAH(a0, b0, acc[0][0], 0, 0, 0);
      acc[0][1] = MFMAH(a0, b1, acc[0][1], 0, 0, 0);
      acc[1][0] = MFMAH(a1, b0, acc[1][0], 0, 0, 0);
      acc[1][1] = MFMAH(a1, b1, acc[1][1], 0, 0, 0);
    }
    __syncthreads();
  }
  float wbv = wb[0];
  #pragma unroll
  for (int mt = 0; mt < 2; ++mt)
    #pragma unroll
    for (int nt = 0; nt < 2; ++nt)
      #pragma unroll
      for (int r = 0; r < 4; ++r) {
        int i = i0 + wm + mt*16 + lg*4 + r;
        int j = j0 + wn + nt*16 + ln;
        if (i < Mn && j < Mn) {
          float cg = sigm(acc[mt][nt][r] + wbv);
          float av = aRow[(size_t)i*Mn + j]*civ[j];
          float ag = adj_geo[(size_t)i*Mn + j];
          float adjf = ag*cg + av*(1.f - cg) + dmat[(size_t)i*Mn + j]*ag;
          adjb[((size_t)b*Mn + i)*Mn + j] = (adjf > 0.f) ? 1.f : adjf;
        }
      }
}

// ---------------------------------------------------------------------------
// K11: laplace row-normalize -> fp16 lapB
__global__ __launch_bounds__(256) void k_lap(const float* __restrict__ adjb, unsigned short* __restrict__ lapB)
{
  int b = blockIdx.y, i = blockIdx.x;
  const float* row = adjb + ((size_t)b*Mn + i)*Mn;
  int tid = threadIdx.x;
  float s = 0.f;
  for (int j = tid; j < Mn; j += 256) s += row[j];
  __shared__ float red[8];
  int lane = tid & 63, wv = tid >> 6;
  #pragma unroll
  for (int off = 32; off; off >>= 1) s += __shfl_down(s, off);
  if (lane == 0) red[wv] = s;
  __syncthreads();
  if (tid == 0) {
    float d = red[0] + red[1] + red[2] + red[3];
    red[4] = (d > 0.f) ? 1.f/d : 0.f;
  }
  __syncthreads();
  float inv = red[4];
  unsigned short* lrow = lapB + ((size_t)b*Mn + i)*Mn;
  for (int j = tid; j < Mn; j += 256) lrow[j] = f2h(row[j]*inv);
}

// ---------------------------------------------------------------------------
// K12: spmm via fp16 MFMA: tmpB[b][i][d] = lapB @ fT^T
__global__ __launch_bounds__(256) void k_spmm(
    const unsigned short* __restrict__ lapB, const unsigned short* __restrict__ fT,
    unsigned short* __restrict__ tmpB)
{
  __shared__ unsigned short As[64*72], Bs[64*72];
  int b = blockIdx.z, i0 = blockIdx.y*64, j0 = blockIdx.x*64;
  int tid = threadIdx.x;
  int w = tid >> 6, lane = tid & 63, ln = lane & 15, lg = lane >> 4;
  int wm = (w >> 1)*32, wn = (w & 1)*32;
  f32x4 acc[2][2];
  #pragma unroll
  for (int p = 0; p < 2; ++p)
    #pragma unroll
    for (int q = 0; q < 2; ++q) acc[p][q] = (f32x4)(0.f);

  for (int k0 = 0; k0 < 512; k0 += 64) {
    for (int idx = tid; idx < 2048; idx += 256) {
      int r = idx >> 5, cp = idx & 31;
      int i = i0 + r, k = k0 + 2*cp;
      unsigned int v = 0;
      if (i < Mn && k < Mn)
        v = *reinterpret_cast<const unsigned int*>(&lapB[((size_t)b*Mn + i)*Mn + k]);
      *reinterpret_cast<unsigned int*>(&As[r*72 + 2*cp]) = v;
    }
    for (int idx = tid; idx < 2048; idx += 256) {
      int r = idx >> 5, cp = idx & 31;
      int d = j0 + r, k = k0 + 2*cp;
      unsigned int v = 0;
      if (d < DF && k < Mn)
        v = *reinterpret_cast<const unsigned int*>(&fT[((size_t)b*DF + d)*Mn + k]);
      *reinterpret_cast<unsigned int*>(&Bs[r*72 + 2*cp]) = v;
    }
    __syncthreads();
    #pragma unroll
    for (int kk = 0; kk < 2; ++kk) {
      half8 a0 = *reinterpret_cast<const half8*>(&As[(wm + 0  + ln)*72 + kk*32 + lg*8]);
      half8 a1 = *reinterpret_cast<const half8*>(&As[(wm + 16 + ln)*72 + kk*32 + lg*8]);
      half8 b0 = *reinterpret_cast<const half8*>(&Bs[(wn + 0  + ln)*72 + kk*32 + lg*8]);
      half8 b1 = *reinterpret_cast<const half8*>(&Bs[(wn + 16 + ln)*72 + kk*32 + lg*8]);
      acc[0][0] = MFMAH(a0, b0, acc[0][0], 0, 0, 0);
      acc[0][1] = MFMAH(a0, b1, acc[0][1], 0, 0, 0);
      acc[1][0] = MFMAH(a1, b0, acc[1][0], 0, 0, 0);
      acc[1][1] = MFMAH(a1, b1, acc[1][1], 0, 0, 0);
    }
    __syncthreads();
  }
  #pragma unroll
  for (int mt = 0; mt < 2; ++mt)
    #pragma unroll
    for (int nt = 0; nt < 2; ++nt)
      #pragma unroll
      for (int r = 0; r < 4; ++r) {
        int i = i0 + wm + mt*16 + lg*4 + r;
        int j = j0 + wn + nt*16 + ln;
        if (i < Mn && j < DF)
          tmpB[((size_t)b*Mn + i)*DF + j] = f2h(acc[mt][nt][r]);
      }
}

// ---------------------------------------------------------------------------
// K13: dense: fout = elu(tmpB @ gnn_w + bias); optional fp16 transposed copy
__global__ __launch_bounds__(256) void k_dense(
    const unsigned short* __restrict__ tmpB, const in_t* __restrict__ W, const in_t* __restrict__ bias,
    float* __restrict__ fout, unsigned short* __restrict__ foutT)
{
  __shared__ unsigned short As[64*72], Bs[64*72];
  __shared__ float bs[64];
  int i0 = blockIdx.y*64, j0 = blockIdx.x*64;
  int tid = threadIdx.x;
  if (tid < 64) bs[tid] = (j0 + tid < DF) ? bias[j0 + tid] : 0.f;
  int w = tid >> 6, lane = tid & 63, ln = lane & 15, lg = lane >> 4;
  int wm = (w >> 1)*32, wn = (w & 1)*32;
  const int NR = Bz*Mn;
  f32x4 acc[2][2];
  #pragma unroll
  for (int p = 0; p < 2; ++p)
    #pragma unroll
    for (int q = 0; q < 2; ++q) acc[p][q] = (f32x4)(0.f);

  for (int k0 = 0; k0 < 192; k0 += 64) {
    for (int idx = tid; idx < 2048; idx += 256) {
      int r = idx >> 5, cp = idx & 31;
      int i = i0 + r, k = k0 + 2*cp;
      unsigned int v = 0;
      if (i < NR && k < DF)
        v = *reinterpret_cast<const unsigned int*>(&tmpB[(size_t)i*DF + k]);
      *reinterpret_cast<unsigned int*>(&As[r*72 + 2*cp]) = v;
    }
    for (int idx = tid; idx < 2048; idx += 256) {
      int c = idx & 63, rp = idx >> 6;
      int j = j0 + c, k = k0 + 2*rp;
      unsigned int v = 0;
      if (j < DF && k < DF)
        v = pack2h(W[(size_t)k*DF + j], W[(size_t)(k+1)*DF + j]);
      *reinterpret_cast<unsigned int*>(&Bs[c*72 + 2*rp]) = v;
    }
    __syncthreads();
    #pragma unroll
    for (int kk = 0; kk < 2; ++kk) {
      half8 a0 = *reinterpret_cast<const half8*>(&As[(wm + 0  + ln)*72 + kk*32 + lg*8]);
      half8 a1 = *reinterpret_cast<const half8*>(&As[(wm + 16 + ln)*72 + kk*32 + lg*8]);
      half8 b0 = *reinterpret_cast<const half8*>(&Bs[(wn + 0  + ln)*72 + kk*32 + lg*8]);
      half8 b1 = *reinterpret_cast<const half8*>(&Bs[(wn + 16 + ln)*72 + kk*32 + lg*8]);
      acc[0][0] = MFMAH(a0, b0, acc[0][0], 0, 0, 0);
      acc[0][1] = MFMAH(a0, b1, acc[0][1], 0, 0, 0);
      acc[1][0] = MFMAH(a1, b0, acc[1][0], 0, 0, 0);
      acc[1][1] = MFMAH(a1, b1, acc[1][1], 0, 0, 0);
    }
    __syncthreads();
  }
  #pragma unroll
  for (int mt = 0; mt < 2; ++mt)
    #pragma unroll
    for (int nt = 0; nt < 2; ++nt)
      #pragma unroll
      for (int r = 0; r < 4; ++r) {
        int i = i0 + wm + mt*16 + lg*4 + r;
        int jl = wn + nt*16 + ln;
        int j = j0 + jl;
        if (i < NR && j < DF) {
          float val = eluf(acc[mt][nt][r] + bs[jl]);
          fout[(size_t)i*DF + j] = val;
          if (foutT) {
            int bb = i / Mn, mm = i - bb*Mn;
            foutT[((size_t)bb*DF + j)*Mn + mm] = f2h(val);
          }
        }
      }
}

// ---------------------------------------------------------------------------
// K14: output projection
__global__ __launch_bounds__(256) void k_out(
    const float* __restrict__ f0, const float* __restrict__ f1, const float* __restrict__ f2,
    const float* __restrict__ lh, const in_t* __restrict__ ow, const in_t* __restrict__ ob,
    float* __restrict__ outp)
{
  __shared__ float w[FINALC];
  int tid = threadIdx.x;
  for (int i = tid; i < FINALC; i += 256) w[i] = ow[i];
  __syncthreads();
  int gid = blockIdx.x*256 + tid;
  if (gid >= Bz*Mn) return;
  float s = ob[0];
  const float* p0 = f0 + (size_t)gid*DF;
  const float* p1 = f1 + (size_t)gid*DF;
  const float* p2 = f2 + (size_t)gid*DF;
  const float* pl = lh + (size_t)gid*NHID;
  for (int c = 0; c < DF; ++c) s += p0[c]*w[c];
  for (int c = 0; c < DF; ++c) s += p1[c]*w[DF + c];
  for (int c = 0; c < DF; ++c) s += p2[c]*w[2*DF + c];
  for (int c = 0; c < NHID; ++c) s += pl[c]*w[3*DF + c];
  outp[gid] = s;
}

// ---------------------------------------------------------------------------
extern "C" void kernel_launch(void* const* d_in, const int* in_sizes, int n_in,
                              void* d_out, int out_size, void* d_ws, size_t ws_size,
                              hipStream_t stream)
{
  const in_t* x       = (const in_t*)d_in[0];
  const in_t* adj_geo = (const in_t*)d_in[1];
  const in_t* degree  = (const in_t*)d_in[2];
  const in_t* conv_s_w= (const in_t*)d_in[3];
  const in_t* conv_s_b= (const in_t*)d_in[4];
  const in_t* conv_l_w= (const in_t*)d_in[5];
  const in_t* conv_l_b= (const in_t*)d_in[6];
  const in_t* WQ_w    = (const in_t*)d_in[7];
  const in_t* WQ_b    = (const in_t*)d_in[8];
  const in_t* WK_w    = (const in_t*)d_in[9];
  const in_t* WK_b    = (const in_t*)d_in[10];
  const in_t* tenc_w  = (const in_t*)d_in[11];
  const in_t* tenc_b  = (const in_t*)d_in[12];
  const in_t* senc_w  = (const in_t*)d_in[13];
  const in_t* senc_b  = (const in_t*)d_in[14];
  const in_t* gru_Wih = (const in_t*)d_in[15];
  const in_t* gru_Whh = (const in_t*)d_in[16];
  const in_t* gru_bih = (const in_t*)d_in[17];
  const in_t* gru_bhh = (const in_t*)d_in[18];
  const in_t* Vv      = (const in_t*)d_in[19];
  const in_t* W1      = (const in_t*)d_in[20];
  const in_t* W2      = (const in_t*)d_in[21];
  const in_t* Wb      = (const in_t*)d_in[22];
  const in_t* bv      = (const in_t*)d_in[23];
  const in_t* b1      = (const in_t*)d_in[24];
  const in_t* wb      = (const in_t*)d_in[25];
  const in_t* d_gate  = (const in_t*)d_in[26];
  const in_t* gnn_w   = (const in_t*)d_in[27];
  const in_t* gnn_b   = (const in_t*)d_in[28];
  const in_t* out_w   = (const in_t*)d_in[29];
  const in_t* out_b   = (const in_t*)d_in[30];
  float* out = (float*)d_out;

  // workspace carve-up (float offsets)
  float* ws   = (float*)d_ws;
  float* hSC  = ws;                    // 128000
  float* Qb   = ws + 128000;           // 256000
  float* Ktb  = ws + 384000;           // 256000
  float* lh   = ws + 673280;           // 128000
  float* A1   = ws + 801280;           // 128000
  float* A2   = ws + 929280;           // 128000
  float* aB   = ws + 1057280;          // 2000000 (dead after k_cgemm; lapB overlays)
  float* cinv = ws + 3057280;          // 4000
  float* adjb = ws + 3061280;          // 2000000
  float* dmat = ws + 5061280;          // 250000
  float* f0   = ws + 5311280;          // 640000
  float* f1   = ws + 5951280;          // 640000
  float* f2   = ws + 6591280;          // 640000
  unsigned short* f0T  = (unsigned short*)(ws + 7231280);  // 640000 fp16
  unsigned short* tmpB = (unsigned short*)(ws + 7551280);  // 640000 fp16
  unsigned short* f1T  = (unsigned short*)(ws + 7871280);  // 640000 fp16
  unsigned short* lapB = (unsigned short*)aB;              // fp16 overlay (aB dead after cgemm)
  // transient partials in adjb region (adjb written only later by k_cgemm):
  float* Gpart = adjb;                 // 8*8*4096 = 262144
  float* Kpart = adjb + 262144;        // 8*8*64   = 4096
  float* ssp   = adjb + 266240;        // 8*8*500  = 32000

  k_conv<<<dim3(4, Bz), 128, 0, stream>>>(x, conv_s_w, conv_s_b, conv_l_w, conv_l_b, hSC, f0, f0T);
  k_qk<<<dim3(16), 256, 0, stream>>>(hSC, WQ_w, WQ_b, WK_w, WK_b, Qb, Ktb);
  k_gram<<<dim3(GSPLIT, Bz), 256, 0, stream>>>(Ktb, Gpart, Kpart);
  k_sglob<<<dim3(2, Bz), 256, 0, stream>>>(Qb, Gpart, Kpart, degree, tenc_w, tenc_b, senc_w, senc_b, f0, f0T);
  k_gru<<<dim3(1000), 256, 0, stream>>>(x, gru_Wih, gru_Whh, gru_bih, gru_bhh, lh);
  k_a1a2<<<dim3(16), 256, 0, stream>>>(lh, W1, W2, A1, A2);
  k_dmat<<<dim3((Mn*Mn + 255)/256), 256, 0, stream>>>(d_gate, degree, dmat);
  k_pair<<<dim3(32, 32, Bz), 256, 0, stream>>>(A1, A2, Vv, b1, bv, aB);
  k_cnorm<<<dim3(4, 8, Bz), 128, 0, stream>>>(aB, ssp);
  k_cfin<<<dim3(16), 256, 0, stream>>>(ssp, cinv);
  k_cgemm<<<dim3(8, 8, Bz), 256, 0, stream>>>(aB, cinv, Wb, wb, adj_geo, dmat, adjb);
  k_lap<<<dim3(Mn, Bz), 256, 0, stream>>>(adjb, lapB);
  // GNN layer 0
  k_spmm<<<dim3(3, 8, Bz), 256, 0, stream>>>(lapB, f0T, tmpB);
  k_dense<<<dim3(3, 63), 256, 0, stream>>>(tmpB, gnn_w, gnn_b, f1, f1T);
  // GNN layer 1
  k_spmm<<<dim3(3, 8, Bz), 256, 0, stream>>>(lapB, f1T, tmpB);
  k_dense<<<dim3(3, 63), 256, 0, stream>>>(tmpB, gnn_w + DF*DF, gnn_b + DF, f2, (unsigned short*)nullptr);
  k_out<<<dim3(16), 256, 0, stream>>>(f0, f1, f2, lh, out_w, out_b, out);
}

// Round 9
// 415.044 us; speedup vs baseline: 1.1179x; 1.1079x over previous
//
#include <hip/hip_runtime.h>
#include <hip/hip_bf16.h>

// Problem constants
#define Bz 8
#define Tn 64
#define Mn 500
#define KC 16
#define HA 64
#define HR 64
#define NHID 32
#define DF 160
#define FINALC 512
#define GSPLIT 8

typedef float in_t;   // reference dtypes are all float32
typedef __attribute__((ext_vector_type(8))) _Float16 half8;
typedef __attribute__((ext_vector_type(2))) _Float16 h2v;
typedef __attribute__((ext_vector_type(4))) float f32x4;
#define MFMAH __builtin_amdgcn_mfma_f32_16x16x32_f16

__device__ __forceinline__ float sigm(float x){ return 1.0f/(1.0f+__expf(-x)); }
__device__ __forceinline__ float tanhfast(float x){ float e=__expf(2.0f*x); return 1.0f-2.0f/(e+1.0f); }
__device__ __forceinline__ float eluf(float x){ return x>0.0f? x : (__expf(x)-1.0f); }
__device__ __forceinline__ unsigned short f2h(float f){
  _Float16 h = (_Float16)f;
  return *reinterpret_cast<unsigned short*>(&h);
}
__device__ __forceinline__ unsigned int pack2h(float a, float b){
  return (unsigned int)f2h(a) | ((unsigned int)f2h(b) << 16);
}

// ---------------------------------------------------------------------------
// K1: per-node convs -> h_SC (relu), writes f0[0:32] (f32) and f0T fp16
__global__ __launch_bounds__(128) void k_conv(
    const in_t* __restrict__ x, const in_t* __restrict__ wsw, const in_t* __restrict__ wsb,
    const in_t* __restrict__ wlw, const in_t* __restrict__ wlb,
    float* __restrict__ hSC, float* __restrict__ f0, unsigned short* __restrict__ f0T)
{
  __shared__ float sw[KC*Tn];
  __shared__ float lw[KC*Tn];
  __shared__ float sb[KC], lb[KC];
  int tid = threadIdx.x;
  for (int idx = tid; idx < KC*Tn; idx += blockDim.x) {
    sw[idx] = wsw[idx];
    int k = idx >> 6, t = idx & 63;
    lw[idx] = 0.5f * wlw[k*32 + (t>>1)];
  }
  if (tid < KC) { sb[tid] = wsb[tid]; lb[tid] = wlb[tid]; }
  __syncthreads();
  int m = blockIdx.x * blockDim.x + tid;
  int b = blockIdx.y;
  if (m >= Mn) return;
  float xv[Tn];
  const in_t* xp = x + (size_t)b*Tn*Mn + m;
  #pragma unroll
  for (int t = 0; t < Tn; ++t) xv[t] = xp[t*Mn];
  float* hp = hSC + ((size_t)b*Mn + m) * (2*KC);
  float* fp = f0  + ((size_t)b*Mn + m) * DF;
  for (int k = 0; k < KC; ++k) {
    float s = 0.f, l = 0.f;
    #pragma unroll
    for (int t = 0; t < Tn; ++t) { s += xv[t]*sw[k*Tn+t]; l += xv[t]*lw[k*Tn+t]; }
    float vs = fmaxf(s + sb[k], 0.f);
    float vl = fmaxf(l + lb[k], 0.f);
    hp[k] = vs; hp[KC+k] = vl;
    fp[k] = vs; fp[KC+k] = vl;
    f0T[((size_t)b*DF + k)*Mn + m]      = f2h(vs);
    f0T[((size_t)b*DF + KC + k)*Mn + m] = f2h(vl);
  }
}

// ---------------------------------------------------------------------------
// K2: Q/K projections
__global__ __launch_bounds__(256) void k_qk(
    const float* __restrict__ hSC, const in_t* __restrict__ WQw, const in_t* __restrict__ WQb,
    const in_t* __restrict__ WKw, const in_t* __restrict__ WKb,
    float* __restrict__ Q, float* __restrict__ Kt)
{
  __shared__ float wq[HA*32], wk[HA*32], bq[HA], bk[HA];
  int tid = threadIdx.x;
  for (int i = tid; i < HA*32; i += 256) { wq[i] = WQw[i]; wk[i] = WKw[i]; }
  for (int i = tid; i < HA; i += 256) { bq[i] = WQb[i]; bk[i] = WKb[i]; }
  __syncthreads();
  int gid = blockIdx.x*256 + tid;
  if (gid >= Bz*Mn) return;
  float h[32];
  const float* hp = hSC + (size_t)gid*32;
  #pragma unroll
  for (int c = 0; c < 32; ++c) h[c] = hp[c];
  float* qp = Q + (size_t)gid*HA;
  float* kp = Kt + (size_t)gid*HA;
  for (int a = 0; a < HA; ++a) {
    float aq = bq[a], ak = bk[a];
    #pragma unroll
    for (int c = 0; c < 32; ++c) { aq += h[c]*wq[a*32+c]; ak += h[c]*wk[a*32+c]; }
    qp[a] = aq; kp[a] = ak;
  }
}

// ---------------------------------------------------------------------------
// K3: split-K partial Gram
__global__ __launch_bounds__(256) void k_gram(
    const float* __restrict__ Kt, float* __restrict__ Gpart, float* __restrict__ Kpart)
{
  int split = blockIdx.x, b = blockIdx.y;
  int tid = threadIdx.x;
  __shared__ float L[64][HA];
  int m0 = split*63;
  int mend = min(m0 + 63, Mn);
  int p = tid & 63;
  int q0 = (tid >> 6) * 16;
  float acc[16];
  #pragma unroll
  for (int e = 0; e < 16; ++e) acc[e] = 0.f;
  for (int idx = tid; idx < 64*HA; idx += 256) {
    int r = idx >> 6, c = idx & 63;
    int m = m0 + r;
    L[r][c] = (m < mend) ? Kt[((size_t)b*Mn + m)*HA + c] : 0.f;
  }
  __syncthreads();
  float ks = 0.f;
  #pragma unroll 4
  for (int r = 0; r < 63; ++r) {
    float lp = L[r][p];
    if (tid < 64) ks += lp;
    #pragma unroll
    for (int e = 0; e < 16; ++e) acc[e] += lp * L[r][q0+e];
  }
  float* gp = Gpart + ((size_t)split*Bz + b)*HA*HA;
  #pragma unroll
  for (int e = 0; e < 16; ++e) gp[p*HA + q0 + e] = acc[e];
  if (tid < 64) Kpart[((size_t)split*Bz + b)*HA + tid] = ks;
}

// ---------------------------------------------------------------------------
// K4: s-glob + h_L (sums the GSPLIT partials on load), writes f0[32:160]
__global__ __launch_bounds__(256) void k_sglob(
    const float* __restrict__ Q, const float* __restrict__ Gpart, const float* __restrict__ Kpart,
    const in_t* __restrict__ degree, const in_t* __restrict__ tencw, const in_t* __restrict__ tencb,
    const in_t* __restrict__ sencw, const in_t* __restrict__ sencb,
    float* __restrict__ f0, unsigned short* __restrict__ f0T)
{
  int b = blockIdx.y;
  __shared__ float Gs[HA*HA];
  __shared__ float Ks[HA], tw[HR], tb[HR], sw2[HR], sb2[HR];
  int tid = threadIdx.x;
  for (int i = tid; i < HA*HA; i += 256) {
    float s = 0.f;
    #pragma unroll
    for (int sp = 0; sp < GSPLIT; ++sp) s += Gpart[((size_t)sp*Bz + b)*HA*HA + i];
    Gs[i] = s;
  }
  for (int i = tid; i < HA; i += 256) {
    float s = 0.f;
    #pragma unroll
    for (int sp = 0; sp < GSPLIT; ++sp) s += Kpart[((size_t)sp*Bz + b)*HA + i];
    Ks[i] = s;
    tw[i] = tencw[i]; tb[i] = tencb[i];
    sw2[i] = sencw[i]; sb2[i] = sencb[i];
  }
  __syncthreads();
  int m = blockIdx.x*256 + tid;
  if (m >= Mn) return;
  const float* qp = Q + ((size_t)b*Mn + m)*HA;
  float q[HA];
  #pragma unroll
  for (int i = 0; i < HA; ++i) q[i] = qp[i];
  float rs = 0.f, qq = 0.f;
  for (int p = 0; p < HA; ++p) {
    float t = 0.f;
    #pragma unroll
    for (int c = 0; c < HA; ++c) t += Gs[p*HA + c] * q[c];
    float qpv = qp[p];
    qq += qpv * t;
    rs += qpv * Ks[p];
  }
  float nrm = fmaxf(sqrtf(fmaxf(qq, 0.f)), 1e-12f);
  float s = rs / nrm;
  float dg = degree[m];
  float* fp = f0 + ((size_t)b*Mn + m)*DF;
  for (int r = 0; r < HR; ++r) {
    float v1 = s*tw[r] + tb[r];
    float v2 = dg*sw2[r] + sb2[r];
    fp[32 + r] = v1;
    fp[96 + r] = v2;
    f0T[((size_t)b*DF + 32 + r)*Mn + m] = f2h(v1);
    f0T[((size_t)b*DF + 96 + r)*Mn + m] = f2h(v2);
  }
}

// ---------------------------------------------------------------------------
// K5: GRU — fdot2 (2 MAC/inst, f32 accum) with packed-fp16 h pairs in LDS.
// 32 lanes per seq (lane=hid), 8 seqs per 256-thr block, 500 blocks = 2000 waves.
// All LDS accesses through declared uint type (no aliasing UB, order preserved);
// no barriers (each 32-lane group owns its own h2 row); x pipelined 1 ahead.
__global__ __launch_bounds__(256) void k_gru(
    const in_t* __restrict__ x, const in_t* __restrict__ Wih, const in_t* __restrict__ Whh,
    const in_t* __restrict__ bih, const in_t* __restrict__ bhh, float* __restrict__ lh)
{
  __shared__ unsigned int h2[8][20];   // [local seq][16 pairs + 4 pad]
  int tid = threadIdx.x;
  int hid = tid & 31;
  int ls  = tid >> 5;
  int seq = blockIdx.x*8 + ls;
  int b = seq / Mn, m = seq - b*Mn;
  unsigned int wr2[16], wz2[16], wn2[16];
  #pragma unroll
  for (int p = 0; p < 16; ++p) {
    wr2[p] = pack2h(Whh[(size_t)hid*32 + 2*p],      Whh[(size_t)hid*32 + 2*p + 1]);
    wz2[p] = pack2h(Whh[(size_t)(32+hid)*32 + 2*p], Whh[(size_t)(32+hid)*32 + 2*p + 1]);
    wn2[p] = pack2h(Whh[(size_t)(64+hid)*32 + 2*p], Whh[(size_t)(64+hid)*32 + 2*p + 1]);
  }
  float wir = Wih[hid], wiz = Wih[32+hid], win = Wih[64+hid];
  float brc  = bih[hid]    + bhh[hid];
  float bzc  = bih[32+hid] + bhh[32+hid];
  float binc = bih[64+hid];
  float bhnc = bhh[64+hid];
  if (!(hid & 1)) h2[ls][hid>>1] = 0u;
  float h = 0.f;
  const in_t* xp = x + (size_t)b*Tn*Mn + m;
  float xcur = xp[0];
  for (int t = 0; t < Tn; ++t) {
    float xnext = (t < Tn-1) ? xp[(size_t)(t+1)*Mn] : 0.f;
    float rg = 0.f, zg = 0.f, ng = 0.f;
    #pragma unroll
    for (int p = 0; p < 16; ++p) {
      h2v hp = __builtin_bit_cast(h2v, h2[ls][p]);
      rg = __builtin_amdgcn_fdot2(__builtin_bit_cast(h2v, wr2[p]), hp, rg, false);
      zg = __builtin_amdgcn_fdot2(__builtin_bit_cast(h2v, wz2[p]), hp, zg, false);
      ng = __builtin_amdgcn_fdot2(__builtin_bit_cast(h2v, wn2[p]), hp, ng, false);
    }
    float r = sigm(xcur*wir + brc + rg);
    float z = sigm(xcur*wiz + bzc + zg);
    float n = tanhfast(xcur*win + binc + r*(ng + bhnc));
    h = (1.f - z)*n + z*h;
    float hpart = __shfl_xor(h, 1, 64);
    unsigned int pk = (hid & 1) ? pack2h(hpart, h) : pack2h(h, hpart);
    if (!(hid & 1)) h2[ls][hid>>1] = pk;
    xcur = xnext;
  }
  lh[(size_t)seq*NHID + hid] = h;
}

// ---------------------------------------------------------------------------
// K6: A1/A2
__global__ __launch_bounds__(256) void k_a1a2(
    const float* __restrict__ lh, const in_t* __restrict__ W1, const in_t* __restrict__ W2,
    float* __restrict__ A1, float* __restrict__ A2)
{
  __shared__ float w1[32*32], w2[32*32];
  int tid = threadIdx.x;
  for (int i = tid; i < 1024; i += 256) { w1[i] = W1[i]; w2[i] = W2[i]; }
  __syncthreads();
  int gid = blockIdx.x*256 + tid;
  if (gid >= Bz*Mn) return;
  float h[32];
  #pragma unroll
  for (int c = 0; c < 32; ++c) h[c] = lh[(size_t)gid*32 + c];
  float* a1 = A1 + (size_t)gid*32;
  float* a2 = A2 + (size_t)gid*32;
  for (int a = 0; a < 32; ++a) {
    float s1 = 0.f, s2 = 0.f;
    #pragma unroll
    for (int c = 0; c < 32; ++c) { s1 += h[c]*w1[a*32+c]; s2 += h[c]*w2[a*32+c]; }
    a1[a] = s1; a2[a] = s2;
  }
}

// ---------------------------------------------------------------------------
// K7: dmat
__global__ __launch_bounds__(256) void k_dmat(
    const in_t* __restrict__ dgate, const in_t* __restrict__ degree, float* __restrict__ dmat)
{
  int idx = blockIdx.x*256 + threadIdx.x;
  if (idx >= Mn*Mn) return;
  int i = idx / Mn, j = idx - i*Mn;
  dmat[idx] = sigm(dgate[idx] * degree[i] * degree[j]);
}

// ---------------------------------------------------------------------------
// K8: a[b,i,j] = V . elu(A1_i + A2_j + b1) + bv   (f32 — sign feeds binarize)
__global__ __launch_bounds__(256) void k_pair(
    const float* __restrict__ A1, const float* __restrict__ A2, const in_t* __restrict__ Vv,
    const in_t* __restrict__ b1, const in_t* __restrict__ bv, float* __restrict__ aB)
{
  __shared__ float a1s[16][33], a2s[16][33], vs[32], b1s[32];
  int b = blockIdx.z;
  int i0 = blockIdx.y*16, j0 = blockIdx.x*16;
  int tid = threadIdx.x;
  if (tid < 32) { vs[tid] = Vv[tid]; b1s[tid] = b1[tid]; }
  {
    int r = tid >> 5, c = tid & 31;
    for (int rr = r; rr < 16; rr += 8) {
      int i = i0 + rr, j = j0 + rr;
      a1s[rr][c] = (i < Mn) ? A1[((size_t)b*Mn + i)*32 + c] : 0.f;
      a2s[rr][c] = (j < Mn) ? A2[((size_t)b*Mn + j)*32 + c] : 0.f;
    }
  }
  __syncthreads();
  int ti = tid >> 4, tj = tid & 15;
  int i = i0 + ti, j = j0 + tj;
  if (i >= Mn || j >= Mn) return;
  float acc = 0.f;
  #pragma unroll
  for (int c = 0; c < 32; ++c) {
    float u = a1s[ti][c] + a2s[tj][c] + b1s[c];
    acc += eluf(u) * vs[c];
  }
  aB[((size_t)b*Mn + i)*Mn + j] = acc + bv[0];
}

// ---------------------------------------------------------------------------
// K9a: partial column sum-squares over row chunks; grid (4 jblk, 8 isplit, Bz)
__global__ __launch_bounds__(128) void k_cnorm(const float* __restrict__ aB, float* __restrict__ ssp)
{
  int jb = blockIdx.x, isp = blockIdx.y, b = blockIdx.z;
  int j = jb*128 + threadIdx.x;
  if (j >= Mn) return;
  int i0 = isp*63, iend = min(i0 + 63, Mn);
  const float* ap = aB + (size_t)b*Mn*Mn + j;
  float ss = 0.f;
  for (int i = i0; i < iend; ++i) { float v = ap[(size_t)i*Mn]; ss += v*v; }
  ssp[((size_t)isp*Bz + b)*Mn + j] = ss;
}

// K9b: finalize cinv
__global__ __launch_bounds__(256) void k_cfin(const float* __restrict__ ssp, float* __restrict__ cinv)
{
  int idx = blockIdx.x*256 + threadIdx.x;
  if (idx >= Bz*Mn) return;
  int b = idx / Mn, j = idx - b*Mn;
  float ss = 0.f;
  #pragma unroll
  for (int sp = 0; sp < 8; ++sp) ss += ssp[((size_t)sp*Bz + b)*Mn + j];
  cinv[idx] = 1.f / fmaxf(sqrtf(ss), 1e-12f);
}

// ---------------------------------------------------------------------------
// K10: c_gate GEMM via plain fp16 MFMA + fused adj epilogue -> adj_bin (f32)
__global__ __launch_bounds__(256) void k_cgemm(
    const float* __restrict__ aB, const float* __restrict__ cinv, const in_t* __restrict__ Wb,
    const in_t* __restrict__ wb, const in_t* __restrict__ adj_geo, const float* __restrict__ dmat,
    float* __restrict__ adjb)
{
  __shared__ unsigned short As[64*72], Bs[64*72];
  int b = blockIdx.z, i0 = blockIdx.y*64, j0 = blockIdx.x*64;
  int tid = threadIdx.x;
  const float* aRow = aB + (size_t)b*Mn*Mn;
  const float* civ = cinv + b*Mn;
  int w = tid >> 6, lane = tid & 63, ln = lane & 15, lg = lane >> 4;
  int wm = (w >> 1)*32, wn = (w & 1)*32;
  f32x4 acc[2][2];
  #pragma unroll
  for (int p = 0; p < 2; ++p)
    #pragma unroll
    for (int q = 0; q < 2; ++q) acc[p][q] = (f32x4)(0.f);

  for (int k0 = 0; k0 < 512; k0 += 64) {
    for (int idx = tid; idx < 2048; idx += 256) {
      int r = idx >> 5, cp = idx & 31;
      int i = i0 + r, k = k0 + 2*cp;
      unsigned int v = 0;
      if (i < Mn && k < Mn)
        v = pack2h(aRow[(size_t)i*Mn + k]*civ[k], aRow[(size_t)i*Mn + k + 1]*civ[k+1]);
      *reinterpret_cast<unsigned int*>(&As[r*72 + 2*cp]) = v;
    }
    for (int idx = tid; idx < 2048; idx += 256) {
      int c = idx & 63, rp = idx >> 6;
      int j = j0 + c, k = k0 + 2*rp;
      unsigned int v = 0;
      if (j < Mn && k < Mn)
        v = pack2h(Wb[(size_t)k*Mn + j], Wb[(size_t)(k+1)*Mn + j]);
      *reinterpret_cast<unsigned int*>(&Bs[c*72 + 2*rp]) = v;
    }
    __syncthreads();
    #pragma unroll
    for (int kk = 0; kk < 2; ++kk) {
      half8 a0 = *reinterpret_cast<const half8*>(&As[(wm + 0  + ln)*72 + kk*32 + lg*8]);
      half8 a1 = *reinterpret_cast<const half8*>(&As[(wm + 16 + ln)*72 + kk*32 + lg*8]);
      half8 b0 = *reinterpret_cast<const half8*>(&Bs[(wn + 0  + ln)*72 + kk*32 + lg*8]);
      half8 b1 = *reinterpret_cast<const half8*>(&Bs[(wn + 16 + ln)*72 + kk*32 + lg*8]);
      acc[0][0] = MFMAH(a0, b0, acc[0][0], 0, 0, 0);
      acc[0][1] = MFMAH(a0, b1, acc[0][1], 0, 0, 0);
      acc[1][0] = MFMAH(a1, b0, acc[1][0], 0, 0, 0);
      acc[1][1] = MFMAH(a1, b1, acc[1][1], 0, 0, 0);
    }
    __syncthreads();
  }
  float wbv = wb[0];
  #pragma unroll
  for (int mt = 0; mt < 2; ++mt)
    #pragma unroll
    for (int nt = 0; nt < 2; ++nt)
      #pragma unroll
      for (int r = 0; r < 4; ++r) {
        int i = i0 + wm + mt*16 + lg*4 + r;
        int j = j0 + wn + nt*16 + ln;
        if (i < Mn && j < Mn) {
          float cg = sigm(acc[mt][nt][r] + wbv);
          float av = aRow[(size_t)i*Mn + j]*civ[j];
          float ag = adj_geo[(size_t)i*Mn + j];
          float adjf = ag*cg + av*(1.f - cg) + dmat[(size_t)i*Mn + j]*ag;
          adjb[((size_t)b*Mn + i)*Mn + j] = (adjf > 0.f) ? 1.f : adjf;
        }
      }
}

// ---------------------------------------------------------------------------
// K11: laplace row-normalize -> fp16 lapB
__global__ __launch_bounds__(256) void k_lap(const float* __restrict__ adjb, unsigned short* __restrict__ lapB)
{
  int b = blockIdx.y, i = blockIdx.x;
  const float* row = adjb + ((size_t)b*Mn + i)*Mn;
  int tid = threadIdx.x;
  float s = 0.f;
  for (int j = tid; j < Mn; j += 256) s += row[j];
  __shared__ float red[8];
  int lane = tid & 63, wv = tid >> 6;
  #pragma unroll
  for (int off = 32; off; off >>= 1) s += __shfl_down(s, off);
  if (lane == 0) red[wv] = s;
  __syncthreads();
  if (tid == 0) {
    float d = red[0] + red[1] + red[2] + red[3];
    red[4] = (d > 0.f) ? 1.f/d : 0.f;
  }
  __syncthreads();
  float inv = red[4];
  unsigned short* lrow = lapB + ((size_t)b*Mn + i)*Mn;
  for (int j = tid; j < Mn; j += 256) lrow[j] = f2h(row[j]*inv);
}

// ---------------------------------------------------------------------------
// K12: spmm via fp16 MFMA: tmpB[b][i][d] = lapB @ fT^T
__global__ __launch_bounds__(256) void k_spmm(
    const unsigned short* __restrict__ lapB, const unsigned short* __restrict__ fT,
    unsigned short* __restrict__ tmpB)
{
  __shared__ unsigned short As[64*72], Bs[64*72];
  int b = blockIdx.z, i0 = blockIdx.y*64, j0 = blockIdx.x*64;
  int tid = threadIdx.x;
  int w = tid >> 6, lane = tid & 63, ln = lane & 15, lg = lane >> 4;
  int wm = (w >> 1)*32, wn = (w & 1)*32;
  f32x4 acc[2][2];
  #pragma unroll
  for (int p = 0; p < 2; ++p)
    #pragma unroll
    for (int q = 0; q < 2; ++q) acc[p][q] = (f32x4)(0.f);

  for (int k0 = 0; k0 < 512; k0 += 64) {
    for (int idx = tid; idx < 2048; idx += 256) {
      int r = idx >> 5, cp = idx & 31;
      int i = i0 + r, k = k0 + 2*cp;
      unsigned int v = 0;
      if (i < Mn && k < Mn)
        v = *reinterpret_cast<const unsigned int*>(&lapB[((size_t)b*Mn + i)*Mn + k]);
      *reinterpret_cast<unsigned int*>(&As[r*72 + 2*cp]) = v;
    }
    for (int idx = tid; idx < 2048; idx += 256) {
      int r = idx >> 5, cp = idx & 31;
      int d = j0 + r, k = k0 + 2*cp;
      unsigned int v = 0;
      if (d < DF && k < Mn)
        v = *reinterpret_cast<const unsigned int*>(&fT[((size_t)b*DF + d)*Mn + k]);
      *reinterpret_cast<unsigned int*>(&Bs[r*72 + 2*cp]) = v;
    }
    __syncthreads();
    #pragma unroll
    for (int kk = 0; kk < 2; ++kk) {
      half8 a0 = *reinterpret_cast<const half8*>(&As[(wm + 0  + ln)*72 + kk*32 + lg*8]);
      half8 a1 = *reinterpret_cast<const half8*>(&As[(wm + 16 + ln)*72 + kk*32 + lg*8]);
      half8 b0 = *reinterpret_cast<const half8*>(&Bs[(wn + 0  + ln)*72 + kk*32 + lg*8]);
      half8 b1 = *reinterpret_cast<const half8*>(&Bs[(wn + 16 + ln)*72 + kk*32 + lg*8]);
      acc[0][0] = MFMAH(a0, b0, acc[0][0], 0, 0, 0);
      acc[0][1] = MFMAH(a0, b1, acc[0][1], 0, 0, 0);
      acc[1][0] = MFMAH(a1, b0, acc[1][0], 0, 0, 0);
      acc[1][1] = MFMAH(a1, b1, acc[1][1], 0, 0, 0);
    }
    __syncthreads();
  }
  #pragma unroll
  for (int mt = 0; mt < 2; ++mt)
    #pragma unroll
    for (int nt = 0; nt < 2; ++nt)
      #pragma unroll
      for (int r = 0; r < 4; ++r) {
        int i = i0 + wm + mt*16 + lg*4 + r;
        int j = j0 + wn + nt*16 + ln;
        if (i < Mn && j < DF)
          tmpB[((size_t)b*Mn + i)*DF + j] = f2h(acc[mt][nt][r]);
      }
}

// ---------------------------------------------------------------------------
// K13: dense: fout = elu(tmpB @ gnn_w + bias); optional fp16 transposed copy
__global__ __launch_bounds__(256) void k_dense(
    const unsigned short* __restrict__ tmpB, const in_t* __restrict__ W, const in_t* __restrict__ bias,
    float* __restrict__ fout, unsigned short* __restrict__ foutT)
{
  __shared__ unsigned short As[64*72], Bs[64*72];
  __shared__ float bs[64];
  int i0 = blockIdx.y*64, j0 = blockIdx.x*64;
  int tid = threadIdx.x;
  if (tid < 64) bs[tid] = (j0 + tid < DF) ? bias[j0 + tid] : 0.f;
  int w = tid >> 6, lane = tid & 63, ln = lane & 15, lg = lane >> 4;
  int wm = (w >> 1)*32, wn = (w & 1)*32;
  const int NR = Bz*Mn;
  f32x4 acc[2][2];
  #pragma unroll
  for (int p = 0; p < 2; ++p)
    #pragma unroll
    for (int q = 0; q < 2; ++q) acc[p][q] = (f32x4)(0.f);

  for (int k0 = 0; k0 < 192; k0 += 64) {
    for (int idx = tid; idx < 2048; idx += 256) {
      int r = idx >> 5, cp = idx & 31;
      int i = i0 + r, k = k0 + 2*cp;
      unsigned int v = 0;
      if (i < NR && k < DF)
        v = *reinterpret_cast<const unsigned int*>(&tmpB[(size_t)i*DF + k]);
      *reinterpret_cast<unsigned int*>(&As[r*72 + 2*cp]) = v;
    }
    for (int idx = tid; idx < 2048; idx += 256) {
      int c = idx & 63, rp = idx >> 6;
      int j = j0 + c, k = k0 + 2*rp;
      unsigned int v = 0;
      if (j < DF && k < DF)
        v = pack2h(W[(size_t)k*DF + j], W[(size_t)(k+1)*DF + j]);
      *reinterpret_cast<unsigned int*>(&Bs[c*72 + 2*rp]) = v;
    }
    __syncthreads();
    #pragma unroll
    for (int kk = 0; kk < 2; ++kk) {
      half8 a0 = *reinterpret_cast<const half8*>(&As[(wm + 0  + ln)*72 + kk*32 + lg*8]);
      half8 a1 = *reinterpret_cast<const half8*>(&As[(wm + 16 + ln)*72 + kk*32 + lg*8]);
      half8 b0 = *reinterpret_cast<const half8*>(&Bs[(wn + 0  + ln)*72 + kk*32 + lg*8]);
      half8 b1 = *reinterpret_cast<const half8*>(&Bs[(wn + 16 + ln)*72 + kk*32 + lg*8]);
      acc[0][0] = MFMAH(a0, b0, acc[0][0], 0, 0, 0);
      acc[0][1] = MFMAH(a0, b1, acc[0][1], 0, 0, 0);
      acc[1][0] = MFMAH(a1, b0, acc[1][0], 0, 0, 0);
      acc[1][1] = MFMAH(a1, b1, acc[1][1], 0, 0, 0);
    }
    __syncthreads();
  }
  #pragma unroll
  for (int mt = 0; mt < 2; ++mt)
    #pragma unroll
    for (int nt = 0; nt < 2; ++nt)
      #pragma unroll
      for (int r = 0; r < 4; ++r) {
        int i = i0 + wm + mt*16 + lg*4 + r;
        int jl = wn + nt*16 + ln;
        int j = j0 + jl;
        if (i < NR && j < DF) {
          float val = eluf(acc[mt][nt][r] + bs[jl]);
          fout[(size_t)i*DF + j] = val;
          if (foutT) {
            int bb = i / Mn, mm = i - bb*Mn;
            foutT[((size_t)bb*DF + j)*Mn + mm] = f2h(val);
          }
        }
      }
}

// ---------------------------------------------------------------------------
// K14: output projection — one wave per output row, lanes over channels
__global__ __launch_bounds__(256) void k_out(
    const float* __restrict__ f0, const float* __restrict__ f1, const float* __restrict__ f2,
    const float* __restrict__ lh, const in_t* __restrict__ ow, const in_t* __restrict__ ob,
    float* __restrict__ outp)
{
  __shared__ float w[FINALC];
  int tid = threadIdx.x;
  for (int i = tid; i < FINALC; i += 256) w[i] = ow[i];
  __syncthreads();
  int lane = tid & 63;
  int gid = blockIdx.x*4 + (tid >> 6);
  const float* p0 = f0 + (size_t)gid*DF;
  const float* p1 = f1 + (size_t)gid*DF;
  const float* p2 = f2 + (size_t)gid*DF;
  const float* pl = lh + (size_t)gid*NHID;
  float s = 0.f;
  #pragma unroll
  for (int ch = 0; ch < 8; ++ch) {
    int ci = ch*64 + lane;
    float v;
    if (ci < DF)          v = p0[ci];
    else if (ci < 2*DF)   v = p1[ci - DF];
    else if (ci < 3*DF)   v = p2[ci - 2*DF];
    else                  v = pl[ci - 3*DF];
    s += v * w[ci];
  }
  #pragma unroll
  for (int off = 32; off; off >>= 1) s += __shfl_down(s, off, 64);
  if (lane == 0) outp[gid] = s + ob[0];
}

// ---------------------------------------------------------------------------
extern "C" void kernel_launch(void* const* d_in, const int* in_sizes, int n_in,
                              void* d_out, int out_size, void* d_ws, size_t ws_size,
                              hipStream_t stream)
{
  const in_t* x       = (const in_t*)d_in[0];
  const in_t* adj_geo = (const in_t*)d_in[1];
  const in_t* degree  = (const in_t*)d_in[2];
  const in_t* conv_s_w= (const in_t*)d_in[3];
  const in_t* conv_s_b= (const in_t*)d_in[4];
  const in_t* conv_l_w= (const in_t*)d_in[5];
  const in_t* conv_l_b= (const in_t*)d_in[6];
  const in_t* WQ_w    = (const in_t*)d_in[7];
  const in_t* WQ_b    = (const in_t*)d_in[8];
  const in_t* WK_w    = (const in_t*)d_in[9];
  const in_t* WK_b    = (const in_t*)d_in[10];
  const in_t* tenc_w  = (const in_t*)d_in[11];
  const in_t* tenc_b  = (const in_t*)d_in[12];
  const in_t* senc_w  = (const in_t*)d_in[13];
  const in_t* senc_b  = (const in_t*)d_in[14];
  const in_t* gru_Wih = (const in_t*)d_in[15];
  const in_t* gru_Whh = (const in_t*)d_in[16];
  const in_t* gru_bih = (const in_t*)d_in[17];
  const in_t* gru_bhh = (const in_t*)d_in[18];
  const in_t* Vv      = (const in_t*)d_in[19];
  const in_t* W1      = (const in_t*)d_in[20];
  const in_t* W2      = (const in_t*)d_in[21];
  const in_t* Wb      = (const in_t*)d_in[22];
  const in_t* bv      = (const in_t*)d_in[23];
  const in_t* b1      = (const in_t*)d_in[24];
  const in_t* wb      = (const in_t*)d_in[25];
  const in_t* d_gate  = (const in_t*)d_in[26];
  const in_t* gnn_w   = (const in_t*)d_in[27];
  const in_t* gnn_b   = (const in_t*)d_in[28];
  const in_t* out_w   = (const in_t*)d_in[29];
  const in_t* out_b   = (const in_t*)d_in[30];
  float* out = (float*)d_out;

  // workspace carve-up (float offsets)
  float* ws   = (float*)d_ws;
  float* hSC  = ws;                    // 128000
  float* Qb   = ws + 128000;           // 256000
  float* Ktb  = ws + 384000;           // 256000
  float* lh   = ws + 673280;           // 128000
  float* A1   = ws + 801280;           // 128000
  float* A2   = ws + 929280;           // 128000
  float* aB   = ws + 1057280;          // 2000000 (dead after k_cgemm; lapB overlays)
  float* cinv = ws + 3057280;          // 4000
  float* adjb = ws + 3061280;          // 2000000
  float* dmat = ws + 5061280;          // 250000
  float* f0   = ws + 5311280;          // 640000
  float* f1   = ws + 5951280;          // 640000
  float* f2   = ws + 6591280;          // 640000
  unsigned short* f0T  = (unsigned short*)(ws + 7231280);  // 640000 fp16
  unsigned short* tmpB = (unsigned short*)(ws + 7551280);  // 640000 fp16
  unsigned short* f1T  = (unsigned short*)(ws + 7871280);  // 640000 fp16
  unsigned short* lapB = (unsigned short*)aB;              // fp16 overlay (aB dead after cgemm)
  // transient partials in adjb region (adjb written only later by k_cgemm):
  float* Gpart = adjb;                 // 8*8*4096 = 262144
  float* Kpart = adjb + 262144;        // 8*8*64   = 4096
  float* ssp   = adjb + 266240;        // 8*8*500  = 32000

  k_conv<<<dim3(4, Bz), 128, 0, stream>>>(x, conv_s_w, conv_s_b, conv_l_w, conv_l_b, hSC, f0, f0T);
  k_qk<<<dim3(16), 256, 0, stream>>>(hSC, WQ_w, WQ_b, WK_w, WK_b, Qb, Ktb);
  k_gram<<<dim3(GSPLIT, Bz), 256, 0, stream>>>(Ktb, Gpart, Kpart);
  k_sglob<<<dim3(2, Bz), 256, 0, stream>>>(Qb, Gpart, Kpart, degree, tenc_w, tenc_b, senc_w, senc_b, f0, f0T);
  k_gru<<<dim3(500), 256, 0, stream>>>(x, gru_Wih, gru_Whh, gru_bih, gru_bhh, lh);
  k_a1a2<<<dim3(16), 256, 0, stream>>>(lh, W1, W2, A1, A2);
  k_dmat<<<dim3((Mn*Mn + 255)/256), 256, 0, stream>>>(d_gate, degree, dmat);
  k_pair<<<dim3(32, 32, Bz), 256, 0, stream>>>(A1, A2, Vv, b1, bv, aB);
  k_cnorm<<<dim3(4, 8, Bz), 128, 0, stream>>>(aB, ssp);
  k_cfin<<<dim3(16), 256, 0, stream>>>(ssp, cinv);
  k_cgemm<<<dim3(8, 8, Bz), 256, 0, stream>>>(aB, cinv, Wb, wb, adj_geo, dmat, adjb);
  k_lap<<<dim3(Mn, Bz), 256, 0, stream>>>(adjb, lapB);
  // GNN layer 0
  k_spmm<<<dim3(3, 8, Bz), 256, 0, stream>>>(lapB, f0T, tmpB);
  k_dense<<<dim3(3, 63), 256, 0, stream>>>(tmpB, gnn_w, gnn_b, f1, f1T);
  // GNN layer 1
  k_spmm<<<dim3(3, 8, Bz), 256, 0, stream>>>(lapB, f1T, tmpB);
  k_dense<<<dim3(3, 63), 256, 0, stream>>>(tmpB, gnn_w + DF*DF, gnn_b + DF, f2, (unsigned short*)nullptr);
  k_out<<<dim3(1000), 256, 0, stream>>>(f0, f1, f2, lh, out_w, out_b, out);
}

// Round 10
// 343.179 us; speedup vs baseline: 1.3520x; 1.2094x over previous
//
#include <hip/hip_runtime.h>
#include <hip/hip_bf16.h>

// Problem constants
#define Bz 8
#define Tn 64
#define Mn 500
#define KC 16
#define HA 64
#define HR 64
#define NHID 32
#define DF 160
#define FINALC 512
#define GSPLIT 8

typedef float in_t;   // reference dtypes are all float32
typedef __attribute__((ext_vector_type(8))) _Float16 half8;
typedef __attribute__((ext_vector_type(2))) _Float16 h2v;
typedef __attribute__((ext_vector_type(4))) float f32x4;
#define MFMAH __builtin_amdgcn_mfma_f32_16x16x32_f16

__device__ __forceinline__ float sigm(float x){ return 1.0f/(1.0f+__expf(-x)); }
__device__ __forceinline__ float tanhfast(float x){ float e=__expf(2.0f*x); return 1.0f-2.0f/(e+1.0f); }
__device__ __forceinline__ float eluf(float x){ return x>0.0f? x : (__expf(x)-1.0f); }
__device__ __forceinline__ unsigned short f2h(float f){
  _Float16 h = (_Float16)f;
  return *reinterpret_cast<unsigned short*>(&h);
}
__device__ __forceinline__ unsigned int pack2h(float a, float b){
  return (unsigned int)f2h(a) | ((unsigned int)f2h(b) << 16);
}

// ---------------------------------------------------------------------------
// K1: per-node convs -> h_SC (relu), writes f0[0:32] (f32) and f0T fp16
__global__ __launch_bounds__(128) void k_conv(
    const in_t* __restrict__ x, const in_t* __restrict__ wsw, const in_t* __restrict__ wsb,
    const in_t* __restrict__ wlw, const in_t* __restrict__ wlb,
    float* __restrict__ hSC, float* __restrict__ f0, unsigned short* __restrict__ f0T)
{
  __shared__ float sw[KC*Tn];
  __shared__ float lw[KC*Tn];
  __shared__ float sb[KC], lb[KC];
  int tid = threadIdx.x;
  for (int idx = tid; idx < KC*Tn; idx += blockDim.x) {
    sw[idx] = wsw[idx];
    int k = idx >> 6, t = idx & 63;
    lw[idx] = 0.5f * wlw[k*32 + (t>>1)];
  }
  if (tid < KC) { sb[tid] = wsb[tid]; lb[tid] = wlb[tid]; }
  __syncthreads();
  int m = blockIdx.x * blockDim.x + tid;
  int b = blockIdx.y;
  if (m >= Mn) return;
  float xv[Tn];
  const in_t* xp = x + (size_t)b*Tn*Mn + m;
  #pragma unroll
  for (int t = 0; t < Tn; ++t) xv[t] = xp[t*Mn];
  float* hp = hSC + ((size_t)b*Mn + m) * (2*KC);
  float* fp = f0  + ((size_t)b*Mn + m) * DF;
  for (int k = 0; k < KC; ++k) {
    float s = 0.f, l = 0.f;
    #pragma unroll
    for (int t = 0; t < Tn; ++t) { s += xv[t]*sw[k*Tn+t]; l += xv[t]*lw[k*Tn+t]; }
    float vs = fmaxf(s + sb[k], 0.f);
    float vl = fmaxf(l + lb[k], 0.f);
    hp[k] = vs; hp[KC+k] = vl;
    fp[k] = vs; fp[KC+k] = vl;
    f0T[((size_t)b*DF + k)*Mn + m]      = f2h(vs);
    f0T[((size_t)b*DF + KC + k)*Mn + m] = f2h(vl);
  }
}

// ---------------------------------------------------------------------------
// K2: Q/K projections
__global__ __launch_bounds__(256) void k_qk(
    const float* __restrict__ hSC, const in_t* __restrict__ WQw, const in_t* __restrict__ WQb,
    const in_t* __restrict__ WKw, const in_t* __restrict__ WKb,
    float* __restrict__ Q, float* __restrict__ Kt)
{
  __shared__ float wq[HA*32], wk[HA*32], bq[HA], bk[HA];
  int tid = threadIdx.x;
  for (int i = tid; i < HA*32; i += 256) { wq[i] = WQw[i]; wk[i] = WKw[i]; }
  for (int i = tid; i < HA; i += 256) { bq[i] = WQb[i]; bk[i] = WKb[i]; }
  __syncthreads();
  int gid = blockIdx.x*256 + tid;
  if (gid >= Bz*Mn) return;
  float h[32];
  const float* hp = hSC + (size_t)gid*32;
  #pragma unroll
  for (int c = 0; c < 32; ++c) h[c] = hp[c];
  float* qp = Q + (size_t)gid*HA;
  float* kp = Kt + (size_t)gid*HA;
  for (int a = 0; a < HA; ++a) {
    float aq = bq[a], ak = bk[a];
    #pragma unroll
    for (int c = 0; c < 32; ++c) { aq += h[c]*wq[a*32+c]; ak += h[c]*wk[a*32+c]; }
    qp[a] = aq; kp[a] = ak;
  }
}

// ---------------------------------------------------------------------------
// K3: split-K partial Gram
__global__ __launch_bounds__(256) void k_gram(
    const float* __restrict__ Kt, float* __restrict__ Gpart, float* __restrict__ Kpart)
{
  int split = blockIdx.x, b = blockIdx.y;
  int tid = threadIdx.x;
  __shared__ float L[64][HA];
  int m0 = split*63;
  int mend = min(m0 + 63, Mn);
  int p = tid & 63;
  int q0 = (tid >> 6) * 16;
  float acc[16];
  #pragma unroll
  for (int e = 0; e < 16; ++e) acc[e] = 0.f;
  for (int idx = tid; idx < 64*HA; idx += 256) {
    int r = idx >> 6, c = idx & 63;
    int m = m0 + r;
    L[r][c] = (m < mend) ? Kt[((size_t)b*Mn + m)*HA + c] : 0.f;
  }
  __syncthreads();
  float ks = 0.f;
  #pragma unroll 4
  for (int r = 0; r < 63; ++r) {
    float lp = L[r][p];
    if (tid < 64) ks += lp;
    #pragma unroll
    for (int e = 0; e < 16; ++e) acc[e] += lp * L[r][q0+e];
  }
  float* gp = Gpart + ((size_t)split*Bz + b)*HA*HA;
  #pragma unroll
  for (int e = 0; e < 16; ++e) gp[p*HA + q0 + e] = acc[e];
  if (tid < 64) Kpart[((size_t)split*Bz + b)*HA + tid] = ks;
}

// ---------------------------------------------------------------------------
// K4: s-glob + h_L (sums the GSPLIT partials on load), writes f0[32:160]
__global__ __launch_bounds__(256) void k_sglob(
    const float* __restrict__ Q, const float* __restrict__ Gpart, const float* __restrict__ Kpart,
    const in_t* __restrict__ degree, const in_t* __restrict__ tencw, const in_t* __restrict__ tencb,
    const in_t* __restrict__ sencw, const in_t* __restrict__ sencb,
    float* __restrict__ f0, unsigned short* __restrict__ f0T)
{
  int b = blockIdx.y;
  __shared__ float Gs[HA*HA];
  __shared__ float Ks[HA], tw[HR], tb[HR], sw2[HR], sb2[HR];
  int tid = threadIdx.x;
  for (int i = tid; i < HA*HA; i += 256) {
    float s = 0.f;
    #pragma unroll
    for (int sp = 0; sp < GSPLIT; ++sp) s += Gpart[((size_t)sp*Bz + b)*HA*HA + i];
    Gs[i] = s;
  }
  for (int i = tid; i < HA; i += 256) {
    float s = 0.f;
    #pragma unroll
    for (int sp = 0; sp < GSPLIT; ++sp) s += Kpart[((size_t)sp*Bz + b)*HA + i];
    Ks[i] = s;
    tw[i] = tencw[i]; tb[i] = tencb[i];
    sw2[i] = sencw[i]; sb2[i] = sencb[i];
  }
  __syncthreads();
  int m = blockIdx.x*256 + tid;
  if (m >= Mn) return;
  const float* qp = Q + ((size_t)b*Mn + m)*HA;
  float q[HA];
  #pragma unroll
  for (int i = 0; i < HA; ++i) q[i] = qp[i];
  float rs = 0.f, qq = 0.f;
  for (int p = 0; p < HA; ++p) {
    float t = 0.f;
    #pragma unroll
    for (int c = 0; c < HA; ++c) t += Gs[p*HA + c] * q[c];
    float qpv = qp[p];
    qq += qpv * t;
    rs += qpv * Ks[p];
  }
  float nrm = fmaxf(sqrtf(fmaxf(qq, 0.f)), 1e-12f);
  float s = rs / nrm;
  float dg = degree[m];
  float* fp = f0 + ((size_t)b*Mn + m)*DF;
  for (int r = 0; r < HR; ++r) {
    float v1 = s*tw[r] + tb[r];
    float v2 = dg*sw2[r] + sb2[r];
    fp[32 + r] = v1;
    fp[96 + r] = v2;
    f0T[((size_t)b*DF + 32 + r)*Mn + m] = f2h(v1);
    f0T[((size_t)b*DF + 96 + r)*Mn + m] = f2h(v2);
  }
}

// ---------------------------------------------------------------------------
// K5: GRU — fdot2 with packed-fp16 h pairs in LDS (round-9 version, kept)
__global__ __launch_bounds__(256) void k_gru(
    const in_t* __restrict__ x, const in_t* __restrict__ Wih, const in_t* __restrict__ Whh,
    const in_t* __restrict__ bih, const in_t* __restrict__ bhh, float* __restrict__ lh)
{
  __shared__ unsigned int h2[8][20];
  int tid = threadIdx.x;
  int hid = tid & 31;
  int ls  = tid >> 5;
  int seq = blockIdx.x*8 + ls;
  int b = seq / Mn, m = seq - b*Mn;
  unsigned int wr2[16], wz2[16], wn2[16];
  #pragma unroll
  for (int p = 0; p < 16; ++p) {
    wr2[p] = pack2h(Whh[(size_t)hid*32 + 2*p],      Whh[(size_t)hid*32 + 2*p + 1]);
    wz2[p] = pack2h(Whh[(size_t)(32+hid)*32 + 2*p], Whh[(size_t)(32+hid)*32 + 2*p + 1]);
    wn2[p] = pack2h(Whh[(size_t)(64+hid)*32 + 2*p], Whh[(size_t)(64+hid)*32 + 2*p + 1]);
  }
  float wir = Wih[hid], wiz = Wih[32+hid], win = Wih[64+hid];
  float brc  = bih[hid]    + bhh[hid];
  float bzc  = bih[32+hid] + bhh[32+hid];
  float binc = bih[64+hid];
  float bhnc = bhh[64+hid];
  if (!(hid & 1)) h2[ls][hid>>1] = 0u;
  float h = 0.f;
  const in_t* xp = x + (size_t)b*Tn*Mn + m;
  float xcur = xp[0];
  for (int t = 0; t < Tn; ++t) {
    float xnext = (t < Tn-1) ? xp[(size_t)(t+1)*Mn] : 0.f;
    float rg = 0.f, zg = 0.f, ng = 0.f;
    #pragma unroll
    for (int p = 0; p < 16; ++p) {
      h2v hp = __builtin_bit_cast(h2v, h2[ls][p]);
      rg = __builtin_amdgcn_fdot2(__builtin_bit_cast(h2v, wr2[p]), hp, rg, false);
      zg = __builtin_amdgcn_fdot2(__builtin_bit_cast(h2v, wz2[p]), hp, zg, false);
      ng = __builtin_amdgcn_fdot2(__builtin_bit_cast(h2v, wn2[p]), hp, ng, false);
    }
    float r = sigm(xcur*wir + brc + rg);
    float z = sigm(xcur*wiz + bzc + zg);
    float n = tanhfast(xcur*win + binc + r*(ng + bhnc));
    h = (1.f - z)*n + z*h;
    float hpart = __shfl_xor(h, 1, 64);
    unsigned int pk = (hid & 1) ? pack2h(hpart, h) : pack2h(h, hpart);
    if (!(hid & 1)) h2[ls][hid>>1] = pk;
    xcur = xnext;
  }
  lh[(size_t)seq*NHID + hid] = h;
}

// ---------------------------------------------------------------------------
// K6: A1/A2
__global__ __launch_bounds__(256) void k_a1a2(
    const float* __restrict__ lh, const in_t* __restrict__ W1, const in_t* __restrict__ W2,
    float* __restrict__ A1, float* __restrict__ A2)
{
  __shared__ float w1[32*32], w2[32*32];
  int tid = threadIdx.x;
  for (int i = tid; i < 1024; i += 256) { w1[i] = W1[i]; w2[i] = W2[i]; }
  __syncthreads();
  int gid = blockIdx.x*256 + tid;
  if (gid >= Bz*Mn) return;
  float h[32];
  #pragma unroll
  for (int c = 0; c < 32; ++c) h[c] = lh[(size_t)gid*32 + c];
  float* a1 = A1 + (size_t)gid*32;
  float* a2 = A2 + (size_t)gid*32;
  for (int a = 0; a < 32; ++a) {
    float s1 = 0.f, s2 = 0.f;
    #pragma unroll
    for (int c = 0; c < 32; ++c) { s1 += h[c]*w1[a*32+c]; s2 += h[c]*w2[a*32+c]; }
    a1[a] = s1; a2[a] = s2;
  }
}

// ---------------------------------------------------------------------------
// K7: dmat
__global__ __launch_bounds__(256) void k_dmat(
    const in_t* __restrict__ dgate, const in_t* __restrict__ degree, float* __restrict__ dmat)
{
  int idx = blockIdx.x*256 + threadIdx.x;
  if (idx >= Mn*Mn) return;
  int i = idx / Mn, j = idx - i*Mn;
  dmat[idx] = sigm(dgate[idx] * degree[i] * degree[j]);
}

// ---------------------------------------------------------------------------
// K8: a[b,i,j] = V . elu(A1_i + A2_j + b1) + bv   (f32 — sign feeds binarize)
__global__ __launch_bounds__(256) void k_pair(
    const float* __restrict__ A1, const float* __restrict__ A2, const in_t* __restrict__ Vv,
    const in_t* __restrict__ b1, const in_t* __restrict__ bv, float* __restrict__ aB)
{
  __shared__ float a1s[16][33], a2s[16][33], vs[32], b1s[32];
  int b = blockIdx.z;
  int i0 = blockIdx.y*16, j0 = blockIdx.x*16;
  int tid = threadIdx.x;
  if (tid < 32) { vs[tid] = Vv[tid]; b1s[tid] = b1[tid]; }
  {
    int r = tid >> 5, c = tid & 31;
    for (int rr = r; rr < 16; rr += 8) {
      int i = i0 + rr, j = j0 + rr;
      a1s[rr][c] = (i < Mn) ? A1[((size_t)b*Mn + i)*32 + c] : 0.f;
      a2s[rr][c] = (j < Mn) ? A2[((size_t)b*Mn + j)*32 + c] : 0.f;
    }
  }
  __syncthreads();
  int ti = tid >> 4, tj = tid & 15;
  int i = i0 + ti, j = j0 + tj;
  if (i >= Mn || j >= Mn) return;
  float acc = 0.f;
  #pragma unroll
  for (int c = 0; c < 32; ++c) {
    float u = a1s[ti][c] + a2s[tj][c] + b1s[c];
    acc += eluf(u) * vs[c];
  }
  aB[((size_t)b*Mn + i)*Mn + j] = acc + bv[0];
}

// ---------------------------------------------------------------------------
// K9a: partial column sum-squares over row chunks; grid (4 jblk, 8 isplit, Bz)
__global__ __launch_bounds__(128) void k_cnorm(const float* __restrict__ aB, float* __restrict__ ssp)
{
  int jb = blockIdx.x, isp = blockIdx.y, b = blockIdx.z;
  int j = jb*128 + threadIdx.x;
  if (j >= Mn) return;
  int i0 = isp*63, iend = min(i0 + 63, Mn);
  const float* ap = aB + (size_t)b*Mn*Mn + j;
  float ss = 0.f;
  for (int i = i0; i < iend; ++i) { float v = ap[(size_t)i*Mn]; ss += v*v; }
  ssp[((size_t)isp*Bz + b)*Mn + j] = ss;
}

// K9b: finalize cinv
__global__ __launch_bounds__(256) void k_cfin(const float* __restrict__ ssp, float* __restrict__ cinv)
{
  int idx = blockIdx.x*256 + threadIdx.x;
  if (idx >= Bz*Mn) return;
  int b = idx / Mn, j = idx - b*Mn;
  float ss = 0.f;
  #pragma unroll
  for (int sp = 0; sp < 8; ++sp) ss += ssp[((size_t)sp*Bz + b)*Mn + j];
  cinv[idx] = 1.f / fmaxf(sqrtf(ss), 1e-12f);
}

// ---------------------------------------------------------------------------
// K10: c_gate GEMM fp16 MFMA, 512 threads (8 waves, 2x4 wave grid) for occupancy
__global__ __launch_bounds__(512) void k_cgemm(
    const float* __restrict__ aB, const float* __restrict__ cinv, const in_t* __restrict__ Wb,
    const in_t* __restrict__ wb, const in_t* __restrict__ adj_geo, const float* __restrict__ dmat,
    float* __restrict__ adjb)
{
  __shared__ unsigned short As[64*72], Bs[64*72];
  int b = blockIdx.z, i0 = blockIdx.y*64, j0 = blockIdx.x*64;
  int tid = threadIdx.x;
  const float* aRow = aB + (size_t)b*Mn*Mn;
  const float* civ = cinv + b*Mn;
  int w = tid >> 6, lane = tid & 63, ln = lane & 15, lg = lane >> 4;
  int wm = (w >> 2)*32, wn = (w & 3)*16;   // 2x4 wave grid: each wave 32x16
  f32x4 acc[2];
  acc[0] = (f32x4)(0.f); acc[1] = (f32x4)(0.f);

  for (int k0 = 0; k0 < 512; k0 += 64) {
    for (int idx = tid; idx < 2048; idx += 512) {
      int r = idx >> 5, cp = idx & 31;
      int i = i0 + r, k = k0 + 2*cp;
      unsigned int v = 0;
      if (i < Mn && k < Mn)
        v = pack2h(aRow[(size_t)i*Mn + k]*civ[k], aRow[(size_t)i*Mn + k + 1]*civ[k+1]);
      *reinterpret_cast<unsigned int*>(&As[r*72 + 2*cp]) = v;
    }
    for (int idx = tid; idx < 2048; idx += 512) {
      int c = idx & 63, rp = idx >> 6;
      int j = j0 + c, k = k0 + 2*rp;
      unsigned int v = 0;
      if (j < Mn && k < Mn)
        v = pack2h(Wb[(size_t)k*Mn + j], Wb[(size_t)(k+1)*Mn + j]);
      *reinterpret_cast<unsigned int*>(&Bs[c*72 + 2*rp]) = v;
    }
    __syncthreads();
    #pragma unroll
    for (int kk = 0; kk < 2; ++kk) {
      half8 a0 = *reinterpret_cast<const half8*>(&As[(wm + 0  + ln)*72 + kk*32 + lg*8]);
      half8 a1 = *reinterpret_cast<const half8*>(&As[(wm + 16 + ln)*72 + kk*32 + lg*8]);
      half8 b0 = *reinterpret_cast<const half8*>(&Bs[(wn + ln)*72 + kk*32 + lg*8]);
      acc[0] = MFMAH(a0, b0, acc[0], 0, 0, 0);
      acc[1] = MFMAH(a1, b0, acc[1], 0, 0, 0);
    }
    __syncthreads();
  }
  float wbv = wb[0];
  #pragma unroll
  for (int mt = 0; mt < 2; ++mt)
    #pragma unroll
    for (int r = 0; r < 4; ++r) {
      int i = i0 + wm + mt*16 + lg*4 + r;
      int j = j0 + wn + ln;
      if (i < Mn && j < Mn) {
        float cg = sigm(acc[mt][r] + wbv);
        float av = aRow[(size_t)i*Mn + j]*civ[j];
        float ag = adj_geo[(size_t)i*Mn + j];
        float adjf = ag*cg + av*(1.f - cg) + dmat[(size_t)i*Mn + j]*ag;
        adjb[((size_t)b*Mn + i)*Mn + j] = (adjf > 0.f) ? 1.f : adjf;
      }
    }
}

// ---------------------------------------------------------------------------
// K11: laplace row-normalize -> fp16 lapB
__global__ __launch_bounds__(256) void k_lap(const float* __restrict__ adjb, unsigned short* __restrict__ lapB)
{
  int b = blockIdx.y, i = blockIdx.x;
  const float* row = adjb + ((size_t)b*Mn + i)*Mn;
  int tid = threadIdx.x;
  float s = 0.f;
  for (int j = tid; j < Mn; j += 256) s += row[j];
  __shared__ float red[8];
  int lane = tid & 63, wv = tid >> 6;
  #pragma unroll
  for (int off = 32; off; off >>= 1) s += __shfl_down(s, off);
  if (lane == 0) red[wv] = s;
  __syncthreads();
  if (tid == 0) {
    float d = red[0] + red[1] + red[2] + red[3];
    red[4] = (d > 0.f) ? 1.f/d : 0.f;
  }
  __syncthreads();
  float inv = red[4];
  unsigned short* lrow = lapB + ((size_t)b*Mn + i)*Mn;
  for (int j = tid; j < Mn; j += 256) lrow[j] = f2h(row[j]*inv);
}

// ---------------------------------------------------------------------------
// K12: spmm via fp16 MFMA, 32x32 tiles for occupancy: grid (5, 16, Bz)
__global__ __launch_bounds__(256) void k_spmm(
    const unsigned short* __restrict__ lapB, const unsigned short* __restrict__ fT,
    unsigned short* __restrict__ tmpB)
{
  __shared__ unsigned short As[32*72], Bs[32*72];
  int b = blockIdx.z, i0 = blockIdx.y*32, j0 = blockIdx.x*32;
  int tid = threadIdx.x;
  int w = tid >> 6, lane = tid & 63, ln = lane & 15, lg = lane >> 4;
  int wm = (w >> 1)*16, wn = (w & 1)*16;    // 2x2 wave grid: each wave 16x16
  f32x4 acc = (f32x4)(0.f);

  for (int k0 = 0; k0 < 512; k0 += 64) {
    for (int idx = tid; idx < 1024; idx += 256) {
      int r = idx >> 5, cp = idx & 31;
      int i = i0 + r, k = k0 + 2*cp;
      unsigned int v = 0;
      if (i < Mn && k < Mn)
        v = *reinterpret_cast<const unsigned int*>(&lapB[((size_t)b*Mn + i)*Mn + k]);
      *reinterpret_cast<unsigned int*>(&As[r*72 + 2*cp]) = v;
    }
    for (int idx = tid; idx < 1024; idx += 256) {
      int r = idx >> 5, cp = idx & 31;
      int d = j0 + r, k = k0 + 2*cp;
      unsigned int v = 0;
      if (k < Mn)
        v = *reinterpret_cast<const unsigned int*>(&fT[((size_t)b*DF + d)*Mn + k]);
      *reinterpret_cast<unsigned int*>(&Bs[r*72 + 2*cp]) = v;
    }
    __syncthreads();
    #pragma unroll
    for (int kk = 0; kk < 2; ++kk) {
      half8 a0 = *reinterpret_cast<const half8*>(&As[(wm + ln)*72 + kk*32 + lg*8]);
      half8 b0 = *reinterpret_cast<const half8*>(&Bs[(wn + ln)*72 + kk*32 + lg*8]);
      acc = MFMAH(a0, b0, acc, 0, 0, 0);
    }
    __syncthreads();
  }
  #pragma unroll
  for (int r = 0; r < 4; ++r) {
    int i = i0 + wm + lg*4 + r;
    int j = j0 + wn + ln;
    if (i < Mn)
      tmpB[((size_t)b*Mn + i)*DF + j] = f2h(acc[r]);
  }
}

// ---------------------------------------------------------------------------
// K13: dense 32x32 tiles: grid (5, 125); NR=4000=125*32, DF=160=5*32 exact
__global__ __launch_bounds__(256) void k_dense(
    const unsigned short* __restrict__ tmpB, const in_t* __restrict__ W, const in_t* __restrict__ bias,
    float* __restrict__ fout, unsigned short* __restrict__ foutT)
{
  __shared__ unsigned short As[32*72], Bs[32*72];
  __shared__ float bs[32];
  int i0 = blockIdx.y*32, j0 = blockIdx.x*32;
  int tid = threadIdx.x;
  if (tid < 32) bs[tid] = bias[j0 + tid];
  int w = tid >> 6, lane = tid & 63, ln = lane & 15, lg = lane >> 4;
  int wm = (w >> 1)*16, wn = (w & 1)*16;
  f32x4 acc = (f32x4)(0.f);

  for (int k0 = 0; k0 < 192; k0 += 64) {
    for (int idx = tid; idx < 1024; idx += 256) {
      int r = idx >> 5, cp = idx & 31;
      int i = i0 + r, k = k0 + 2*cp;
      unsigned int v = 0;
      if (k < DF)
        v = *reinterpret_cast<const unsigned int*>(&tmpB[(size_t)i*DF + k]);
      *reinterpret_cast<unsigned int*>(&As[r*72 + 2*cp]) = v;
    }
    for (int idx = tid; idx < 1024; idx += 256) {
      int c = idx & 31, rp = idx >> 5;
      int j = j0 + c, k = k0 + 2*rp;
      unsigned int v = 0;
      if (k < DF)
        v = pack2h(W[(size_t)k*DF + j], W[(size_t)(k+1)*DF + j]);
      *reinterpret_cast<unsigned int*>(&Bs[c*72 + 2*rp]) = v;
    }
    __syncthreads();
    #pragma unroll
    for (int kk = 0; kk < 2; ++kk) {
      half8 a0 = *reinterpret_cast<const half8*>(&As[(wm + ln)*72 + kk*32 + lg*8]);
      half8 b0 = *reinterpret_cast<const half8*>(&Bs[(wn + ln)*72 + kk*32 + lg*8]);
      acc = MFMAH(a0, b0, acc, 0, 0, 0);
    }
    __syncthreads();
  }
  #pragma unroll
  for (int r = 0; r < 4; ++r) {
    int i = i0 + wm + lg*4 + r;
    int jl = wn + ln;
    int j = j0 + jl;
    float val = eluf(acc[r] + bs[jl]);
    fout[(size_t)i*DF + j] = val;
    if (foutT) {
      int bb = i / Mn, mm = i - bb*Mn;
      foutT[((size_t)bb*DF + j)*Mn + mm] = f2h(val);
    }
  }
}

// ---------------------------------------------------------------------------
// K14: output projection — one wave per output row, lanes over channels
__global__ __launch_bounds__(256) void k_out(
    const float* __restrict__ f0, const float* __restrict__ f1, const float* __restrict__ f2,
    const float* __restrict__ lh, const in_t* __restrict__ ow, const in_t* __restrict__ ob,
    float* __restrict__ outp)
{
  __shared__ float w[FINALC];
  int tid = threadIdx.x;
  for (int i = tid; i < FINALC; i += 256) w[i] = ow[i];
  __syncthreads();
  int lane = tid & 63;
  int gid = blockIdx.x*4 + (tid >> 6);
  const float* p0 = f0 + (size_t)gid*DF;
  const float* p1 = f1 + (size_t)gid*DF;
  const float* p2 = f2 + (size_t)gid*DF;
  const float* pl = lh + (size_t)gid*NHID;
  float s = 0.f;
  #pragma unroll
  for (int ch = 0; ch < 8; ++ch) {
    int ci = ch*64 + lane;
    float v;
    if (ci < DF)          v = p0[ci];
    else if (ci < 2*DF)   v = p1[ci - DF];
    else if (ci < 3*DF)   v = p2[ci - 2*DF];
    else                  v = pl[ci - 3*DF];
    s += v * w[ci];
  }
  #pragma unroll
  for (int off = 32; off; off >>= 1) s += __shfl_down(s, off, 64);
  if (lane == 0) outp[gid] = s + ob[0];
}

// ---------------------------------------------------------------------------
extern "C" void kernel_launch(void* const* d_in, const int* in_sizes, int n_in,
                              void* d_out, int out_size, void* d_ws, size_t ws_size,
                              hipStream_t stream)
{
  const in_t* x       = (const in_t*)d_in[0];
  const in_t* adj_geo = (const in_t*)d_in[1];
  const in_t* degree  = (const in_t*)d_in[2];
  const in_t* conv_s_w= (const in_t*)d_in[3];
  const in_t* conv_s_b= (const in_t*)d_in[4];
  const in_t* conv_l_w= (const in_t*)d_in[5];
  const in_t* conv_l_b= (const in_t*)d_in[6];
  const in_t* WQ_w    = (const in_t*)d_in[7];
  const in_t* WQ_b    = (const in_t*)d_in[8];
  const in_t* WK_w    = (const in_t*)d_in[9];
  const in_t* WK_b    = (const in_t*)d_in[10];
  const in_t* tenc_w  = (const in_t*)d_in[11];
  const in_t* tenc_b  = (const in_t*)d_in[12];
  const in_t* senc_w  = (const in_t*)d_in[13];
  const in_t* senc_b  = (const in_t*)d_in[14];
  const in_t* gru_Wih = (const in_t*)d_in[15];
  const in_t* gru_Whh = (const in_t*)d_in[16];
  const in_t* gru_bih = (const in_t*)d_in[17];
  const in_t* gru_bhh = (const in_t*)d_in[18];
  const in_t* Vv      = (const in_t*)d_in[19];
  const in_t* W1      = (const in_t*)d_in[20];
  const in_t* W2      = (const in_t*)d_in[21];
  const in_t* Wb      = (const in_t*)d_in[22];
  const in_t* bv      = (const in_t*)d_in[23];
  const in_t* b1      = (const in_t*)d_in[24];
  const in_t* wb      = (const in_t*)d_in[25];
  const in_t* d_gate  = (const in_t*)d_in[26];
  const in_t* gnn_w   = (const in_t*)d_in[27];
  const in_t* gnn_b   = (const in_t*)d_in[28];
  const in_t* out_w   = (const in_t*)d_in[29];
  const in_t* out_b   = (const in_t*)d_in[30];
  float* out = (float*)d_out;

  // workspace carve-up (float offsets)
  float* ws   = (float*)d_ws;
  float* hSC  = ws;                    // 128000
  float* Qb   = ws + 128000;           // 256000
  float* Ktb  = ws + 384000;           // 256000
  float* lh   = ws + 673280;           // 128000
  float* A1   = ws + 801280;           // 128000
  float* A2   = ws + 929280;           // 128000
  float* aB   = ws + 1057280;          // 2000000 (dead after k_cgemm; lapB overlays)
  float* cinv = ws + 3057280;          // 4000
  float* adjb = ws + 3061280;          // 2000000
  float* dmat = ws + 5061280;          // 250000
  float* f0   = ws + 5311280;          // 640000
  float* f1   = ws + 5951280;          // 640000
  float* f2   = ws + 6591280;          // 640000
  unsigned short* f0T  = (unsigned short*)(ws + 7231280);  // 640000 fp16
  unsigned short* tmpB = (unsigned short*)(ws + 7551280);  // 640000 fp16
  unsigned short* f1T  = (unsigned short*)(ws + 7871280);  // 640000 fp16
  unsigned short* lapB = (unsigned short*)aB;              // fp16 overlay (aB dead after cgemm)
  // transient partials in adjb region (adjb written only later by k_cgemm):
  float* Gpart = adjb;                 // 8*8*4096 = 262144
  float* Kpart = adjb + 262144;        // 8*8*64   = 4096
  float* ssp   = adjb + 266240;        // 8*8*500  = 32000

  k_conv<<<dim3(4, Bz), 128, 0, stream>>>(x, conv_s_w, conv_s_b, conv_l_w, conv_l_b, hSC, f0, f0T);
  k_qk<<<dim3(16), 256, 0, stream>>>(hSC, WQ_w, WQ_b, WK_w, WK_b, Qb, Ktb);
  k_gram<<<dim3(GSPLIT, Bz), 256, 0, stream>>>(Ktb, Gpart, Kpart);
  k_sglob<<<dim3(2, Bz), 256, 0, stream>>>(Qb, Gpart, Kpart, degree, tenc_w, tenc_b, senc_w, senc_b, f0, f0T);
  k_gru<<<dim3(500), 256, 0, stream>>>(x, gru_Wih, gru_Whh, gru_bih, gru_bhh, lh);
  k_a1a2<<<dim3(16), 256, 0, stream>>>(lh, W1, W2, A1, A2);
  k_dmat<<<dim3((Mn*Mn + 255)/256), 256, 0, stream>>>(d_gate, degree, dmat);
  k_pair<<<dim3(32, 32, Bz), 256, 0, stream>>>(A1, A2, Vv, b1, bv, aB);
  k_cnorm<<<dim3(4, 8, Bz), 128, 0, stream>>>(aB, ssp);
  k_cfin<<<dim3(16), 256, 0, stream>>>(ssp, cinv);
  k_cgemm<<<dim3(8, 8, Bz), 512, 0, stream>>>(aB, cinv, Wb, wb, adj_geo, dmat, adjb);
  k_lap<<<dim3(Mn, Bz), 256, 0, stream>>>(adjb, lapB);
  // GNN layer 0
  k_spmm<<<dim3(5, 16, Bz), 256, 0, stream>>>(lapB, f0T, tmpB);
  k_dense<<<dim3(5, 125), 256, 0, stream>>>(tmpB, gnn_w, gnn_b, f1, f1T);
  // GNN layer 1
  k_spmm<<<dim3(5, 16, Bz), 256, 0, stream>>>(lapB, f1T, tmpB);
  k_dense<<<dim3(5, 125), 256, 0, stream>>>(tmpB, gnn_w + DF*DF, gnn_b + DF, f2, (unsigned short*)nullptr);
  k_out<<<dim3(1000), 256, 0, stream>>>(f0, f1, f2, lh, out_w, out_b, out);
}

// Round 11
// 254.296 us; speedup vs baseline: 1.8246x; 1.3495x over previous
//
#include <hip/hip_runtime.h>
#include <hip/hip_bf16.h>

// Problem constants
#define Bz 8
#define Tn 64
#define Mn 500
#define KC 16
#define HA 64
#define HR 64
#define NHID 32
#define DF 160
#define FINALC 512
#define GSPLIT 8

typedef float in_t;   // reference dtypes are all float32
typedef __attribute__((ext_vector_type(8))) _Float16 half8;
typedef __attribute__((ext_vector_type(2))) _Float16 h2v;
typedef __attribute__((ext_vector_type(4))) float f32x4;
#define MFMAH __builtin_amdgcn_mfma_f32_16x16x32_f16

__device__ __forceinline__ float sigm(float x){ return 1.0f/(1.0f+__expf(-x)); }
__device__ __forceinline__ float tanhfast(float x){ float e=__expf(2.0f*x); return 1.0f-2.0f/(e+1.0f); }
__device__ __forceinline__ float eluf(float x){ return x>0.0f? x : (__expf(x)-1.0f); }
__device__ __forceinline__ unsigned short f2h(float f){
  _Float16 h = (_Float16)f;
  return *reinterpret_cast<unsigned short*>(&h);
}
__device__ __forceinline__ unsigned int pack2h(float a, float b){
  return (unsigned int)f2h(a) | ((unsigned int)f2h(b) << 16);
}

// ---------------------------------------------------------------------------
// K1: convs; 16 nodes x 16 features per 256-block, 250 blocks
__global__ __launch_bounds__(256) void k_conv(
    const in_t* __restrict__ x, const in_t* __restrict__ wsw, const in_t* __restrict__ wsb,
    const in_t* __restrict__ wlw, const in_t* __restrict__ wlb,
    float* __restrict__ hSC, float* __restrict__ f0, unsigned short* __restrict__ f0T)
{
  __shared__ float sw[KC*65], lw[KC*65];
  __shared__ float sb[KC], lb[KC];
  __shared__ float xs[16*65];
  int tid = threadIdx.x;
  for (int idx = tid; idx < KC*Tn; idx += 256) {
    int k = idx >> 6, t = idx & 63;
    sw[k*65+t] = wsw[idx];
    lw[k*65+t] = 0.5f * wlw[k*32 + (t>>1)];
  }
  if (tid < KC) { sb[tid] = wsb[tid]; lb[tid] = wlb[tid]; }
  int ng0 = blockIdx.x * 16;
  for (int idx = tid; idx < 16*Tn; idx += 256) {
    int t = idx >> 4, nl = idx & 15;
    int ng = ng0 + nl;
    int b = ng / Mn, m = ng - b*Mn;
    xs[nl*65 + t] = x[(size_t)b*Tn*Mn + (size_t)t*Mn + m];
  }
  __syncthreads();
  int nl = tid >> 4, k = tid & 15;
  int ng = ng0 + nl;
  int b = ng / Mn, m = ng - b*Mn;
  float s = 0.f, l = 0.f;
  #pragma unroll
  for (int t = 0; t < Tn; ++t) {
    float xv = xs[nl*65+t];
    s += xv * sw[k*65+t];
    l += xv * lw[k*65+t];
  }
  float vs = fmaxf(s + sb[k], 0.f);
  float vl = fmaxf(l + lb[k], 0.f);
  size_t base = (size_t)b*Mn + m;
  hSC[base*32 + k]      = vs; hSC[base*32 + KC + k] = vl;
  f0[base*DF + k]       = vs; f0[base*DF + KC + k]  = vl;
  f0T[((size_t)b*DF + k)*Mn + m]      = f2h(vs);
  f0T[((size_t)b*DF + KC + k)*Mn + m] = f2h(vl);
}

// ---------------------------------------------------------------------------
// K2: Q/K projections; thread = (gid, a), 4 gids x 64 outputs per block, 1000 blocks
__global__ __launch_bounds__(256) void k_qk(
    const float* __restrict__ hSC, const in_t* __restrict__ WQw, const in_t* __restrict__ WQb,
    const in_t* __restrict__ WKw, const in_t* __restrict__ WKb,
    float* __restrict__ Q, float* __restrict__ Kt)
{
  __shared__ float wq[HA*33], wk[HA*33];
  __shared__ float hs[4][32];
  __shared__ float bq[HA], bk[HA];
  int tid = threadIdx.x;
  for (int idx = tid; idx < HA*32; idx += 256) {
    int a = idx >> 5, c = idx & 31;
    wq[a*33+c] = WQw[idx];
    wk[a*33+c] = WKw[idx];
  }
  if (tid < HA) { bq[tid] = WQb[tid]; bk[tid] = WKb[tid]; }
  int gid0 = blockIdx.x * 4;
  for (int idx = tid; idx < 128; idx += 256)
    hs[idx>>5][idx&31] = hSC[(size_t)gid0*32 + idx];
  __syncthreads();
  int g = tid >> 6, a = tid & 63;
  int gid = gid0 + g;
  float aq = bq[a], ak = bk[a];
  #pragma unroll
  for (int c = 0; c < 32; ++c) {
    float hv = hs[g][c];
    aq += hv * wq[a*33+c];
    ak += hv * wk[a*33+c];
  }
  Q[(size_t)gid*HA + a]  = aq;
  Kt[(size_t)gid*HA + a] = ak;
}

// ---------------------------------------------------------------------------
// K3: split-K partial Gram
__global__ __launch_bounds__(256) void k_gram(
    const float* __restrict__ Kt, float* __restrict__ Gpart, float* __restrict__ Kpart)
{
  int split = blockIdx.x, b = blockIdx.y;
  int tid = threadIdx.x;
  __shared__ float L[64][HA];
  int m0 = split*63;
  int mend = min(m0 + 63, Mn);
  int p = tid & 63;
  int q0 = (tid >> 6) * 16;
  float acc[16];
  #pragma unroll
  for (int e = 0; e < 16; ++e) acc[e] = 0.f;
  for (int idx = tid; idx < 64*HA; idx += 256) {
    int r = idx >> 6, c = idx & 63;
    int m = m0 + r;
    L[r][c] = (m < mend) ? Kt[((size_t)b*Mn + m)*HA + c] : 0.f;
  }
  __syncthreads();
  float ks = 0.f;
  #pragma unroll 4
  for (int r = 0; r < 63; ++r) {
    float lp = L[r][p];
    if (tid < 64) ks += lp;
    #pragma unroll
    for (int e = 0; e < 16; ++e) acc[e] += lp * L[r][q0+e];
  }
  float* gp = Gpart + ((size_t)split*Bz + b)*HA*HA;
  #pragma unroll
  for (int e = 0; e < 16; ++e) gp[p*HA + q0 + e] = acc[e];
  if (tid < 64) Kpart[((size_t)split*Bz + b)*HA + tid] = ks;
}

// K3b: sum the GSPLIT partials once per batch
__global__ __launch_bounds__(256) void k_gfin(
    const float* __restrict__ Gpart, const float* __restrict__ Kpart,
    float* __restrict__ Gfull, float* __restrict__ Kfull)
{
  int b = blockIdx.x;
  int tid = threadIdx.x;
  for (int i = tid; i < HA*HA; i += 256) {
    float s = 0.f;
    #pragma unroll
    for (int sp = 0; sp < GSPLIT; ++sp) s += Gpart[((size_t)sp*Bz + b)*HA*HA + i];
    Gfull[(size_t)b*HA*HA + i] = s;
  }
  if (tid < HA) {
    float s = 0.f;
    #pragma unroll
    for (int sp = 0; sp < GSPLIT; ++sp) s += Kpart[((size_t)sp*Bz + b)*HA + tid];
    Kfull[b*HA + tid] = s;
  }
}

// ---------------------------------------------------------------------------
// K4: s-glob + h_L; wave-per-m (4 m per block, same batch since 500%4==0), 1000 blocks
__global__ __launch_bounds__(256) void k_sglob(
    const float* __restrict__ Q, const float* __restrict__ Gfull, const float* __restrict__ Kfull,
    const in_t* __restrict__ degree, const in_t* __restrict__ tencw, const in_t* __restrict__ tencb,
    const in_t* __restrict__ sencw, const in_t* __restrict__ sencb,
    float* __restrict__ f0, unsigned short* __restrict__ f0T)
{
  __shared__ float Gs[HA*65];
  __shared__ float qs[4][HA];
  __shared__ float Ks[HA], tw[HR], tb[HR], sw2[HR], sb2[HR];
  int tid = threadIdx.x;
  int gid0 = blockIdx.x*4;
  int b = gid0 / Mn;
  for (int idx = tid; idx < HA*HA; idx += 256) {
    int p = idx >> 6, c = idx & 63;
    Gs[p*65+c] = Gfull[(size_t)b*HA*HA + idx];
  }
  for (int idx = tid; idx < 4*HA; idx += 256)
    qs[idx>>6][idx&63] = Q[(size_t)gid0*HA + idx];
  if (tid < HA) {
    Ks[tid] = Kfull[b*HA + tid];
    tw[tid] = tencw[tid]; tb[tid] = tencb[tid];
    sw2[tid] = sencw[tid]; sb2[tid] = sencb[tid];
  }
  __syncthreads();
  int w = tid >> 6, p = tid & 63;
  int gid = gid0 + w;
  int m = gid - b*Mn;
  float t = 0.f;
  #pragma unroll
  for (int c = 0; c < HA; ++c) t += Gs[p*65+c] * qs[w][c];
  float qpv = qs[w][p];
  float qq = qpv * t;
  float rs = qpv * Ks[p];
  #pragma unroll
  for (int off = 32; off; off >>= 1) {
    qq += __shfl_xor(qq, off, 64);
    rs += __shfl_xor(rs, off, 64);
  }
  float nrm = fmaxf(sqrtf(fmaxf(qq, 0.f)), 1e-12f);
  float s = rs / nrm;
  float dg = degree[m];
  float v1 = s*tw[p] + tb[p];
  float v2 = dg*sw2[p] + sb2[p];
  float* fp = f0 + (size_t)gid*DF;
  fp[32+p] = v1;
  fp[96+p] = v2;
  f0T[((size_t)b*DF + 32 + p)*Mn + m] = f2h(v1);
  f0T[((size_t)b*DF + 96 + p)*Mn + m] = f2h(v2);
}

// ---------------------------------------------------------------------------
// K5: GRU — fdot2 with packed-fp16 h pairs in LDS (round-9 version, kept)
__global__ __launch_bounds__(256) void k_gru(
    const in_t* __restrict__ x, const in_t* __restrict__ Wih, const in_t* __restrict__ Whh,
    const in_t* __restrict__ bih, const in_t* __restrict__ bhh, float* __restrict__ lh)
{
  __shared__ unsigned int h2[8][20];
  int tid = threadIdx.x;
  int hid = tid & 31;
  int ls  = tid >> 5;
  int seq = blockIdx.x*8 + ls;
  int b = seq / Mn, m = seq - b*Mn;
  unsigned int wr2[16], wz2[16], wn2[16];
  #pragma unroll
  for (int p = 0; p < 16; ++p) {
    wr2[p] = pack2h(Whh[(size_t)hid*32 + 2*p],      Whh[(size_t)hid*32 + 2*p + 1]);
    wz2[p] = pack2h(Whh[(size_t)(32+hid)*32 + 2*p], Whh[(size_t)(32+hid)*32 + 2*p + 1]);
    wn2[p] = pack2h(Whh[(size_t)(64+hid)*32 + 2*p], Whh[(size_t)(64+hid)*32 + 2*p + 1]);
  }
  float wir = Wih[hid], wiz = Wih[32+hid], win = Wih[64+hid];
  float brc  = bih[hid]    + bhh[hid];
  float bzc  = bih[32+hid] + bhh[32+hid];
  float binc = bih[64+hid];
  float bhnc = bhh[64+hid];
  if (!(hid & 1)) h2[ls][hid>>1] = 0u;
  float h = 0.f;
  const in_t* xp = x + (size_t)b*Tn*Mn + m;
  float xcur = xp[0];
  for (int t = 0; t < Tn; ++t) {
    float xnext = (t < Tn-1) ? xp[(size_t)(t+1)*Mn] : 0.f;
    float rg = 0.f, zg = 0.f, ng = 0.f;
    #pragma unroll
    for (int p = 0; p < 16; ++p) {
      h2v hp = __builtin_bit_cast(h2v, h2[ls][p]);
      rg = __builtin_amdgcn_fdot2(__builtin_bit_cast(h2v, wr2[p]), hp, rg, false);
      zg = __builtin_amdgcn_fdot2(__builtin_bit_cast(h2v, wz2[p]), hp, zg, false);
      ng = __builtin_amdgcn_fdot2(__builtin_bit_cast(h2v, wn2[p]), hp, ng, false);
    }
    float r = sigm(xcur*wir + brc + rg);
    float z = sigm(xcur*wiz + bzc + zg);
    float n = tanhfast(xcur*win + binc + r*(ng + bhnc));
    h = (1.f - z)*n + z*h;
    float hpart = __shfl_xor(h, 1, 64);
    unsigned int pk = (hid & 1) ? pack2h(hpart, h) : pack2h(h, hpart);
    if (!(hid & 1)) h2[ls][hid>>1] = pk;
    xcur = xnext;
  }
  lh[(size_t)seq*NHID + hid] = h;
}

// ---------------------------------------------------------------------------
// K6: A1/A2
__global__ __launch_bounds__(256) void k_a1a2(
    const float* __restrict__ lh, const in_t* __restrict__ W1, const in_t* __restrict__ W2,
    float* __restrict__ A1, float* __restrict__ A2)
{
  __shared__ float w1[32*32], w2[32*32];
  int tid = threadIdx.x;
  for (int i = tid; i < 1024; i += 256) { w1[i] = W1[i]; w2[i] = W2[i]; }
  __syncthreads();
  int gid = blockIdx.x*256 + tid;
  if (gid >= Bz*Mn) return;
  float h[32];
  #pragma unroll
  for (int c = 0; c < 32; ++c) h[c] = lh[(size_t)gid*32 + c];
  float* a1 = A1 + (size_t)gid*32;
  float* a2 = A2 + (size_t)gid*32;
  for (int a = 0; a < 32; ++a) {
    float s1 = 0.f, s2 = 0.f;
    #pragma unroll
    for (int c = 0; c < 32; ++c) { s1 += h[c]*w1[a*32+c]; s2 += h[c]*w2[a*32+c]; }
    a1[a] = s1; a2[a] = s2;
  }
}

// ---------------------------------------------------------------------------
// K7: dmat
__global__ __launch_bounds__(256) void k_dmat(
    const in_t* __restrict__ dgate, const in_t* __restrict__ degree, float* __restrict__ dmat)
{
  int idx = blockIdx.x*256 + threadIdx.x;
  if (idx >= Mn*Mn) return;
  int i = idx / Mn, j = idx - i*Mn;
  dmat[idx] = sigm(dgate[idx] * degree[i] * degree[j]);
}

// ---------------------------------------------------------------------------
// K8: a[b,i,j] = V . elu(A1_i + A2_j + b1) + bv   (f32 — sign feeds binarize)
__global__ __launch_bounds__(256) void k_pair(
    const float* __restrict__ A1, const float* __restrict__ A2, const in_t* __restrict__ Vv,
    const in_t* __restrict__ b1, const in_t* __restrict__ bv, float* __restrict__ aB)
{
  __shared__ float a1s[16][33], a2s[16][33], vs[32], b1s[32];
  int b = blockIdx.z;
  int i0 = blockIdx.y*16, j0 = blockIdx.x*16;
  int tid = threadIdx.x;
  if (tid < 32) { vs[tid] = Vv[tid]; b1s[tid] = b1[tid]; }
  {
    int r = tid >> 5, c = tid & 31;
    for (int rr = r; rr < 16; rr += 8) {
      int i = i0 + rr, j = j0 + rr;
      a1s[rr][c] = (i < Mn) ? A1[((size_t)b*Mn + i)*32 + c] : 0.f;
      a2s[rr][c] = (j < Mn) ? A2[((size_t)b*Mn + j)*32 + c] : 0.f;
    }
  }
  __syncthreads();
  int ti = tid >> 4, tj = tid & 15;
  int i = i0 + ti, j = j0 + tj;
  if (i >= Mn || j >= Mn) return;
  float acc = 0.f;
  #pragma unroll
  for (int c = 0; c < 32; ++c) {
    float u = a1s[ti][c] + a2s[tj][c] + b1s[c];
    acc += eluf(u) * vs[c];
  }
  aB[((size_t)b*Mn + i)*Mn + j] = acc + bv[0];
}

// ---------------------------------------------------------------------------
// K9a: partial column sum-squares over row chunks; grid (4 jblk, 8 isplit, Bz)
__global__ __launch_bounds__(128) void k_cnorm(const float* __restrict__ aB, float* __restrict__ ssp)
{
  int jb = blockIdx.x, isp = blockIdx.y, b = blockIdx.z;
  int j = jb*128 + threadIdx.x;
  if (j >= Mn) return;
  int i0 = isp*63, iend = min(i0 + 63, Mn);
  const float* ap = aB + (size_t)b*Mn*Mn + j;
  float ss = 0.f;
  for (int i = i0; i < iend; ++i) { float v = ap[(size_t)i*Mn]; ss += v*v; }
  ssp[((size_t)isp*Bz + b)*Mn + j] = ss;
}

// K9b: finalize cinv
__global__ __launch_bounds__(256) void k_cfin(const float* __restrict__ ssp, float* __restrict__ cinv)
{
  int idx = blockIdx.x*256 + threadIdx.x;
  if (idx >= Bz*Mn) return;
  int b = idx / Mn, j = idx - b*Mn;
  float ss = 0.f;
  #pragma unroll
  for (int sp = 0; sp < 8; ++sp) ss += ssp[((size_t)sp*Bz + b)*Mn + j];
  cinv[idx] = 1.f / fmaxf(sqrtf(ss), 1e-12f);
}

// ---------------------------------------------------------------------------
// K10: c_gate GEMM fp16 MFMA, 512 threads (8 waves, 2x4 wave grid)
__global__ __launch_bounds__(512) void k_cgemm(
    const float* __restrict__ aB, const float* __restrict__ cinv, const in_t* __restrict__ Wb,
    const in_t* __restrict__ wb, const in_t* __restrict__ adj_geo, const float* __restrict__ dmat,
    float* __restrict__ adjb)
{
  __shared__ unsigned short As[64*72], Bs[64*72];
  int b = blockIdx.z, i0 = blockIdx.y*64, j0 = blockIdx.x*64;
  int tid = threadIdx.x;
  const float* aRow = aB + (size_t)b*Mn*Mn;
  const float* civ = cinv + b*Mn;
  int w = tid >> 6, lane = tid & 63, ln = lane & 15, lg = lane >> 4;
  int wm = (w >> 2)*32, wn = (w & 3)*16;
  f32x4 acc[2];
  acc[0] = (f32x4)(0.f); acc[1] = (f32x4)(0.f);

  for (int k0 = 0; k0 < 512; k0 += 64) {
    for (int idx = tid; idx < 2048; idx += 512) {
      int r = idx >> 5, cp = idx & 31;
      int i = i0 + r, k = k0 + 2*cp;
      unsigned int v = 0;
      if (i < Mn && k < Mn)
        v = pack2h(aRow[(size_t)i*Mn + k]*civ[k], aRow[(size_t)i*Mn + k + 1]*civ[k+1]);
      *reinterpret_cast<unsigned int*>(&As[r*72 + 2*cp]) = v;
    }
    for (int idx = tid; idx < 2048; idx += 512) {
      int c = idx & 63, rp = idx >> 6;
      int j = j0 + c, k = k0 + 2*rp;
      unsigned int v = 0;
      if (j < Mn && k < Mn)
        v = pack2h(Wb[(size_t)k*Mn + j], Wb[(size_t)(k+1)*Mn + j]);
      *reinterpret_cast<unsigned int*>(&Bs[c*72 + 2*rp]) = v;
    }
    __syncthreads();
    #pragma unroll
    for (int kk = 0; kk < 2; ++kk) {
      half8 a0 = *reinterpret_cast<const half8*>(&As[(wm + 0  + ln)*72 + kk*32 + lg*8]);
      half8 a1 = *reinterpret_cast<const half8*>(&As[(wm + 16 + ln)*72 + kk*32 + lg*8]);
      half8 b0 = *reinterpret_cast<const half8*>(&Bs[(wn + ln)*72 + kk*32 + lg*8]);
      acc[0] = MFMAH(a0, b0, acc[0], 0, 0, 0);
      acc[1] = MFMAH(a1, b0, acc[1], 0, 0, 0);
    }
    __syncthreads();
  }
  float wbv = wb[0];
  #pragma unroll
  for (int mt = 0; mt < 2; ++mt)
    #pragma unroll
    for (int r = 0; r < 4; ++r) {
      int i = i0 + wm + mt*16 + lg*4 + r;
      int j = j0 + wn + ln;
      if (i < Mn && j < Mn) {
        float cg = sigm(acc[mt][r] + wbv);
        float av = aRow[(size_t)i*Mn + j]*civ[j];
        float ag = adj_geo[(size_t)i*Mn + j];
        float adjf = ag*cg + av*(1.f - cg) + dmat[(size_t)i*Mn + j]*ag;
        adjb[((size_t)b*Mn + i)*Mn + j] = (adjf > 0.f) ? 1.f : adjf;
      }
    }
}

// ---------------------------------------------------------------------------
// K11: laplace row-normalize -> fp16 lapB
__global__ __launch_bounds__(256) void k_lap(const float* __restrict__ adjb, unsigned short* __restrict__ lapB)
{
  int b = blockIdx.y, i = blockIdx.x;
  const float* row = adjb + ((size_t)b*Mn + i)*Mn;
  int tid = threadIdx.x;
  float s = 0.f;
  for (int j = tid; j < Mn; j += 256) s += row[j];
  __shared__ float red[8];
  int lane = tid & 63, wv = tid >> 6;
  #pragma unroll
  for (int off = 32; off; off >>= 1) s += __shfl_down(s, off);
  if (lane == 0) red[wv] = s;
  __syncthreads();
  if (tid == 0) {
    float d = red[0] + red[1] + red[2] + red[3];
    red[4] = (d > 0.f) ? 1.f/d : 0.f;
  }
  __syncthreads();
  float inv = red[4];
  unsigned short* lrow = lapB + ((size_t)b*Mn + i)*Mn;
  for (int j = tid; j < Mn; j += 256) lrow[j] = f2h(row[j]*inv);
}

// ---------------------------------------------------------------------------
// K12: spmm via fp16 MFMA, 32x32 tiles: grid (5, 16, Bz)
__global__ __launch_bounds__(256) void k_spmm(
    const unsigned short* __restrict__ lapB, const unsigned short* __restrict__ fT,
    unsigned short* __restrict__ tmpB)
{
  __shared__ unsigned short As[32*72], Bs[32*72];
  int b = blockIdx.z, i0 = blockIdx.y*32, j0 = blockIdx.x*32;
  int tid = threadIdx.x;
  int w = tid >> 6, lane = tid & 63, ln = lane & 15, lg = lane >> 4;
  int wm = (w >> 1)*16, wn = (w & 1)*16;
  f32x4 acc = (f32x4)(0.f);

  for (int k0 = 0; k0 < 512; k0 += 64) {
    for (int idx = tid; idx < 1024; idx += 256) {
      int r = idx >> 5, cp = idx & 31;
      int i = i0 + r, k = k0 + 2*cp;
      unsigned int v = 0;
      if (i < Mn && k < Mn)
        v = *reinterpret_cast<const unsigned int*>(&lapB[((size_t)b*Mn + i)*Mn + k]);
      *reinterpret_cast<unsigned int*>(&As[r*72 + 2*cp]) = v;
    }
    for (int idx = tid; idx < 1024; idx += 256) {
      int r = idx >> 5, cp = idx & 31;
      int d = j0 + r, k = k0 + 2*cp;
      unsigned int v = 0;
      if (k < Mn)
        v = *reinterpret_cast<const unsigned int*>(&fT[((size_t)b*DF + d)*Mn + k]);
      *reinterpret_cast<unsigned int*>(&Bs[r*72 + 2*cp]) = v;
    }
    __syncthreads();
    #pragma unroll
    for (int kk = 0; kk < 2; ++kk) {
      half8 a0 = *reinterpret_cast<const half8*>(&As[(wm + ln)*72 + kk*32 + lg*8]);
      half8 b0 = *reinterpret_cast<const half8*>(&Bs[(wn + ln)*72 + kk*32 + lg*8]);
      acc = MFMAH(a0, b0, acc, 0, 0, 0);
    }
    __syncthreads();
  }
  #pragma unroll
  for (int r = 0; r < 4; ++r) {
    int i = i0 + wm + lg*4 + r;
    int j = j0 + wn + ln;
    if (i < Mn)
      tmpB[((size_t)b*Mn + i)*DF + j] = f2h(acc[r]);
  }
}

// ---------------------------------------------------------------------------
// K13: dense 32x32 tiles: grid (5, 125)
__global__ __launch_bounds__(256) void k_dense(
    const unsigned short* __restrict__ tmpB, const in_t* __restrict__ W, const in_t* __restrict__ bias,
    float* __restrict__ fout, unsigned short* __restrict__ foutT)
{
  __shared__ unsigned short As[32*72], Bs[32*72];
  __shared__ float bs[32];
  int i0 = blockIdx.y*32, j0 = blockIdx.x*32;
  int tid = threadIdx.x;
  if (tid < 32) bs[tid] = bias[j0 + tid];
  int w = tid >> 6, lane = tid & 63, ln = lane & 15, lg = lane >> 4;
  int wm = (w >> 1)*16, wn = (w & 1)*16;
  f32x4 acc = (f32x4)(0.f);

  for (int k0 = 0; k0 < 192; k0 += 64) {
    for (int idx = tid; idx < 1024; idx += 256) {
      int r = idx >> 5, cp = idx & 31;
      int i = i0 + r, k = k0 + 2*cp;
      unsigned int v = 0;
      if (k < DF)
        v = *reinterpret_cast<const unsigned int*>(&tmpB[(size_t)i*DF + k]);
      *reinterpret_cast<unsigned int*>(&As[r*72 + 2*cp]) = v;
    }
    for (int idx = tid; idx < 1024; idx += 256) {
      int c = idx & 31, rp = idx >> 5;
      int j = j0 + c, k = k0 + 2*rp;
      unsigned int v = 0;
      if (k < DF)
        v = pack2h(W[(size_t)k*DF + j], W[(size_t)(k+1)*DF + j]);
      *reinterpret_cast<unsigned int*>(&Bs[c*72 + 2*rp]) = v;
    }
    __syncthreads();
    #pragma unroll
    for (int kk = 0; kk < 2; ++kk) {
      half8 a0 = *reinterpret_cast<const half8*>(&As[(wm + ln)*72 + kk*32 + lg*8]);
      half8 b0 = *reinterpret_cast<const half8*>(&Bs[(wn + ln)*72 + kk*32 + lg*8]);
      acc = MFMAH(a0, b0, acc, 0, 0, 0);
    }
    __syncthreads();
  }
  #pragma unroll
  for (int r = 0; r < 4; ++r) {
    int i = i0 + wm + lg*4 + r;
    int jl = wn + ln;
    int j = j0 + jl;
    float val = eluf(acc[r] + bs[jl]);
    fout[(size_t)i*DF + j] = val;
    if (foutT) {
      int bb = i / Mn, mm = i - bb*Mn;
      foutT[((size_t)bb*DF + j)*Mn + mm] = f2h(val);
    }
  }
}

// ---------------------------------------------------------------------------
// K14: output projection — one wave per output row, lanes over channels
__global__ __launch_bounds__(256) void k_out(
    const float* __restrict__ f0, const float* __restrict__ f1, const float* __restrict__ f2,
    const float* __restrict__ lh, const in_t* __restrict__ ow, const in_t* __restrict__ ob,
    float* __restrict__ outp)
{
  __shared__ float w[FINALC];
  int tid = threadIdx.x;
  for (int i = tid; i < FINALC; i += 256) w[i] = ow[i];
  __syncthreads();
  int lane = tid & 63;
  int gid = blockIdx.x*4 + (tid >> 6);
  const float* p0 = f0 + (size_t)gid*DF;
  const float* p1 = f1 + (size_t)gid*DF;
  const float* p2 = f2 + (size_t)gid*DF;
  const float* pl = lh + (size_t)gid*NHID;
  float s = 0.f;
  #pragma unroll
  for (int ch = 0; ch < 8; ++ch) {
    int ci = ch*64 + lane;
    float v;
    if (ci < DF)          v = p0[ci];
    else if (ci < 2*DF)   v = p1[ci - DF];
    else if (ci < 3*DF)   v = p2[ci - 2*DF];
    else                  v = pl[ci - 3*DF];
    s += v * w[ci];
  }
  #pragma unroll
  for (int off = 32; off; off >>= 1) s += __shfl_down(s, off, 64);
  if (lane == 0) outp[gid] = s + ob[0];
}

// ---------------------------------------------------------------------------
extern "C" void kernel_launch(void* const* d_in, const int* in_sizes, int n_in,
                              void* d_out, int out_size, void* d_ws, size_t ws_size,
                              hipStream_t stream)
{
  const in_t* x       = (const in_t*)d_in[0];
  const in_t* adj_geo = (const in_t*)d_in[1];
  const in_t* degree  = (const in_t*)d_in[2];
  const in_t* conv_s_w= (const in_t*)d_in[3];
  const in_t* conv_s_b= (const in_t*)d_in[4];
  const in_t* conv_l_w= (const in_t*)d_in[5];
  const in_t* conv_l_b= (const in_t*)d_in[6];
  const in_t* WQ_w    = (const in_t*)d_in[7];
  const in_t* WQ_b    = (const in_t*)d_in[8];
  const in_t* WK_w    = (const in_t*)d_in[9];
  const in_t* WK_b    = (const in_t*)d_in[10];
  const in_t* tenc_w  = (const in_t*)d_in[11];
  const in_t* tenc_b  = (const in_t*)d_in[12];
  const in_t* senc_w  = (const in_t*)d_in[13];
  const in_t* senc_b  = (const in_t*)d_in[14];
  const in_t* gru_Wih = (const in_t*)d_in[15];
  const in_t* gru_Whh = (const in_t*)d_in[16];
  const in_t* gru_bih = (const in_t*)d_in[17];
  const in_t* gru_bhh = (const in_t*)d_in[18];
  const in_t* Vv      = (const in_t*)d_in[19];
  const in_t* W1      = (const in_t*)d_in[20];
  const in_t* W2      = (const in_t*)d_in[21];
  const in_t* Wb      = (const in_t*)d_in[22];
  const in_t* bv      = (const in_t*)d_in[23];
  const in_t* b1      = (const in_t*)d_in[24];
  const in_t* wb      = (const in_t*)d_in[25];
  const in_t* d_gate  = (const in_t*)d_in[26];
  const in_t* gnn_w   = (const in_t*)d_in[27];
  const in_t* gnn_b   = (const in_t*)d_in[28];
  const in_t* out_w   = (const in_t*)d_in[29];
  const in_t* out_b   = (const in_t*)d_in[30];
  float* out = (float*)d_out;

  // workspace carve-up (float offsets)
  float* ws   = (float*)d_ws;
  float* hSC  = ws;                    // 128000
  float* Qb   = ws + 128000;           // 256000
  float* Ktb  = ws + 384000;           // 256000
  float* lh   = ws + 673280;           // 128000
  float* A1   = ws + 801280;           // 128000
  float* A2   = ws + 929280;           // 128000
  float* aB   = ws + 1057280;          // 2000000 (dead after k_cgemm; lapB overlays)
  float* cinv = ws + 3057280;          // 4000
  float* adjb = ws + 3061280;          // 2000000
  float* dmat = ws + 5061280;          // 250000
  float* f0   = ws + 5311280;          // 640000
  float* f1   = ws + 5951280;          // 640000
  float* f2   = ws + 6591280;          // 640000
  unsigned short* f0T  = (unsigned short*)(ws + 7231280);  // 640000 fp16
  unsigned short* tmpB = (unsigned short*)(ws + 7551280);  // 640000 fp16
  unsigned short* f1T  = (unsigned short*)(ws + 7871280);  // 640000 fp16
  unsigned short* lapB = (unsigned short*)aB;              // fp16 overlay (aB dead after cgemm)
  // transient partials in adjb region (adjb written only later by k_cgemm):
  float* Gpart = adjb;                 // 8*8*4096 = 262144
  float* Kpart = adjb + 262144;        // 8*8*64   = 4096
  float* ssp   = adjb + 266240;        // 8*8*500  = 32000
  float* Gfull = adjb + 298240;        // 8*4096   = 32768
  float* Kfull = adjb + 331008;        // 8*64     = 512

  k_conv<<<dim3(250), 256, 0, stream>>>(x, conv_s_w, conv_s_b, conv_l_w, conv_l_b, hSC, f0, f0T);
  k_qk<<<dim3(1000), 256, 0, stream>>>(hSC, WQ_w, WQ_b, WK_w, WK_b, Qb, Ktb);
  k_gram<<<dim3(GSPLIT, Bz), 256, 0, stream>>>(Ktb, Gpart, Kpart);
  k_gfin<<<dim3(Bz), 256, 0, stream>>>(Gpart, Kpart, Gfull, Kfull);
  k_sglob<<<dim3(1000), 256, 0, stream>>>(Qb, Gfull, Kfull, degree, tenc_w, tenc_b, senc_w, senc_b, f0, f0T);
  k_gru<<<dim3(500), 256, 0, stream>>>(x, gru_Wih, gru_Whh, gru_bih, gru_bhh, lh);
  k_a1a2<<<dim3(16), 256, 0, stream>>>(lh, W1, W2, A1, A2);
  k_dmat<<<dim3((Mn*Mn + 255)/256), 256, 0, stream>>>(d_gate, degree, dmat);
  k_pair<<<dim3(32, 32, Bz), 256, 0, stream>>>(A1, A2, Vv, b1, bv, aB);
  k_cnorm<<<dim3(4, 8, Bz), 128, 0, stream>>>(aB, ssp);
  k_cfin<<<dim3(16), 256, 0, stream>>>(ssp, cinv);
  k_cgemm<<<dim3(8, 8, Bz), 512, 0, stream>>>(aB, cinv, Wb, wb, adj_geo, dmat, adjb);
  k_lap<<<dim3(Mn, Bz), 256, 0, stream>>>(adjb, lapB);
  // GNN layer 0
  k_spmm<<<dim3(5, 16, Bz), 256, 0, stream>>>(lapB, f0T, tmpB);
  k_dense<<<dim3(5, 125), 256, 0, stream>>>(tmpB, gnn_w, gnn_b, f1, f1T);
  // GNN layer 1
  k_spmm<<<dim3(5, 16, Bz), 256, 0, stream>>>(lapB, f1T, tmpB);
  k_dense<<<dim3(5, 125), 256, 0, stream>>>(tmpB, gnn_w + DF*DF, gnn_b + DF, f2, (unsigned short*)nullptr);
  k_out<<<dim3(1000), 256, 0, stream>>>(f0, f1, f2, lh, out_w, out_b, out);
}

// Round 12
// 237.117 us; speedup vs baseline: 1.9568x; 1.0725x over previous
//
#include <hip/hip_runtime.h>
#include <hip/hip_bf16.h>

// Problem constants
#define Bz 8
#define Tn 64
#define Mn 500
#define KC 16
#define HA 64
#define HR 64
#define NHID 32
#define DF 160
#define FINALC 512
#define GSPLIT 8

typedef float in_t;   // reference dtypes are all float32
typedef __attribute__((ext_vector_type(8))) _Float16 half8;
typedef __attribute__((ext_vector_type(2))) _Float16 h2v;
typedef __attribute__((ext_vector_type(4))) float f32x4;
#define MFMAH __builtin_amdgcn_mfma_f32_16x16x32_f16

__device__ __forceinline__ float sigm(float x){ return 1.0f/(1.0f+__expf(-x)); }
__device__ __forceinline__ float tanhfast(float x){ float e=__expf(2.0f*x); return 1.0f-2.0f/(e+1.0f); }
__device__ __forceinline__ float eluf(float x){ return x>0.0f? x : (__expf(x)-1.0f); }
__device__ __forceinline__ unsigned short f2h(float f){
  _Float16 h = (_Float16)f;
  return *reinterpret_cast<unsigned short*>(&h);
}
__device__ __forceinline__ unsigned int pack2h(float a, float b){
  return (unsigned int)f2h(a) | ((unsigned int)f2h(b) << 16);
}

// ---------------------------------------------------------------------------
// K1: convs; 16 nodes x 16 features per 256-block, 250 blocks
__global__ __launch_bounds__(256) void k_conv(
    const in_t* __restrict__ x, const in_t* __restrict__ wsw, const in_t* __restrict__ wsb,
    const in_t* __restrict__ wlw, const in_t* __restrict__ wlb,
    float* __restrict__ hSC, float* __restrict__ f0, unsigned short* __restrict__ f0T)
{
  __shared__ float sw[KC*65], lw[KC*65];
  __shared__ float sb[KC], lb[KC];
  __shared__ float xs[16*65];
  int tid = threadIdx.x;
  for (int idx = tid; idx < KC*Tn; idx += 256) {
    int k = idx >> 6, t = idx & 63;
    sw[k*65+t] = wsw[idx];
    lw[k*65+t] = 0.5f * wlw[k*32 + (t>>1)];
  }
  if (tid < KC) { sb[tid] = wsb[tid]; lb[tid] = wlb[tid]; }
  int ng0 = blockIdx.x * 16;
  for (int idx = tid; idx < 16*Tn; idx += 256) {
    int t = idx >> 4, nl = idx & 15;
    int ng = ng0 + nl;
    int b = ng / Mn, m = ng - b*Mn;
    xs[nl*65 + t] = x[(size_t)b*Tn*Mn + (size_t)t*Mn + m];
  }
  __syncthreads();
  int nl = tid >> 4, k = tid & 15;
  int ng = ng0 + nl;
  int b = ng / Mn, m = ng - b*Mn;
  float s = 0.f, l = 0.f;
  #pragma unroll
  for (int t = 0; t < Tn; ++t) {
    float xv = xs[nl*65+t];
    s += xv * sw[k*65+t];
    l += xv * lw[k*65+t];
  }
  float vs = fmaxf(s + sb[k], 0.f);
  float vl = fmaxf(l + lb[k], 0.f);
  size_t base = (size_t)b*Mn + m;
  hSC[base*32 + k]      = vs; hSC[base*32 + KC + k] = vl;
  f0[base*DF + k]       = vs; f0[base*DF + KC + k]  = vl;
  f0T[((size_t)b*DF + k)*Mn + m]      = f2h(vs);
  f0T[((size_t)b*DF + KC + k)*Mn + m] = f2h(vl);
}

// ---------------------------------------------------------------------------
// K2: Q/K projections; thread = (gid, a), 4 gids x 64 outputs per block, 1000 blocks
__global__ __launch_bounds__(256) void k_qk(
    const float* __restrict__ hSC, const in_t* __restrict__ WQw, const in_t* __restrict__ WQb,
    const in_t* __restrict__ WKw, const in_t* __restrict__ WKb,
    float* __restrict__ Q, float* __restrict__ Kt)
{
  __shared__ float wq[HA*33], wk[HA*33];
  __shared__ float hs[4][32];
  __shared__ float bq[HA], bk[HA];
  int tid = threadIdx.x;
  for (int idx = tid; idx < HA*32; idx += 256) {
    int a = idx >> 5, c = idx & 31;
    wq[a*33+c] = WQw[idx];
    wk[a*33+c] = WKw[idx];
  }
  if (tid < HA) { bq[tid] = WQb[tid]; bk[tid] = WKb[tid]; }
  int gid0 = blockIdx.x * 4;
  for (int idx = tid; idx < 128; idx += 256)
    hs[idx>>5][idx&31] = hSC[(size_t)gid0*32 + idx];
  __syncthreads();
  int g = tid >> 6, a = tid & 63;
  int gid = gid0 + g;
  float aq = bq[a], ak = bk[a];
  #pragma unroll
  for (int c = 0; c < 32; ++c) {
    float hv = hs[g][c];
    aq += hv * wq[a*33+c];
    ak += hv * wk[a*33+c];
  }
  Q[(size_t)gid*HA + a]  = aq;
  Kt[(size_t)gid*HA + a] = ak;
}

// ---------------------------------------------------------------------------
// K3: split-K partial Gram
__global__ __launch_bounds__(256) void k_gram(
    const float* __restrict__ Kt, float* __restrict__ Gpart, float* __restrict__ Kpart)
{
  int split = blockIdx.x, b = blockIdx.y;
  int tid = threadIdx.x;
  __shared__ float L[64][HA];
  int m0 = split*63;
  int mend = min(m0 + 63, Mn);
  int p = tid & 63;
  int q0 = (tid >> 6) * 16;
  float acc[16];
  #pragma unroll
  for (int e = 0; e < 16; ++e) acc[e] = 0.f;
  for (int idx = tid; idx < 64*HA; idx += 256) {
    int r = idx >> 6, c = idx & 63;
    int m = m0 + r;
    L[r][c] = (m < mend) ? Kt[((size_t)b*Mn + m)*HA + c] : 0.f;
  }
  __syncthreads();
  float ks = 0.f;
  #pragma unroll 4
  for (int r = 0; r < 63; ++r) {
    float lp = L[r][p];
    if (tid < 64) ks += lp;
    #pragma unroll
    for (int e = 0; e < 16; ++e) acc[e] += lp * L[r][q0+e];
  }
  float* gp = Gpart + ((size_t)split*Bz + b)*HA*HA;
  #pragma unroll
  for (int e = 0; e < 16; ++e) gp[p*HA + q0 + e] = acc[e];
  if (tid < 64) Kpart[((size_t)split*Bz + b)*HA + tid] = ks;
}

// K3b: sum the GSPLIT partials once per batch
__global__ __launch_bounds__(256) void k_gfin(
    const float* __restrict__ Gpart, const float* __restrict__ Kpart,
    float* __restrict__ Gfull, float* __restrict__ Kfull)
{
  int b = blockIdx.x;
  int tid = threadIdx.x;
  for (int i = tid; i < HA*HA; i += 256) {
    float s = 0.f;
    #pragma unroll
    for (int sp = 0; sp < GSPLIT; ++sp) s += Gpart[((size_t)sp*Bz + b)*HA*HA + i];
    Gfull[(size_t)b*HA*HA + i] = s;
  }
  if (tid < HA) {
    float s = 0.f;
    #pragma unroll
    for (int sp = 0; sp < GSPLIT; ++sp) s += Kpart[((size_t)sp*Bz + b)*HA + tid];
    Kfull[b*HA + tid] = s;
  }
}

// ---------------------------------------------------------------------------
// K4: s-glob + h_L; wave-per-m (4 m per block, same batch since 500%4==0), 1000 blocks
__global__ __launch_bounds__(256) void k_sglob(
    const float* __restrict__ Q, const float* __restrict__ Gfull, const float* __restrict__ Kfull,
    const in_t* __restrict__ degree, const in_t* __restrict__ tencw, const in_t* __restrict__ tencb,
    const in_t* __restrict__ sencw, const in_t* __restrict__ sencb,
    float* __restrict__ f0, unsigned short* __restrict__ f0T)
{
  __shared__ float Gs[HA*65];
  __shared__ float qs[4][HA];
  __shared__ float Ks[HA], tw[HR], tb[HR], sw2[HR], sb2[HR];
  int tid = threadIdx.x;
  int gid0 = blockIdx.x*4;
  int b = gid0 / Mn;
  for (int idx = tid; idx < HA*HA; idx += 256) {
    int p = idx >> 6, c = idx & 63;
    Gs[p*65+c] = Gfull[(size_t)b*HA*HA + idx];
  }
  for (int idx = tid; idx < 4*HA; idx += 256)
    qs[idx>>6][idx&63] = Q[(size_t)gid0*HA + idx];
  if (tid < HA) {
    Ks[tid] = Kfull[b*HA + tid];
    tw[tid] = tencw[tid]; tb[tid] = tencb[tid];
    sw2[tid] = sencw[tid]; sb2[tid] = sencb[tid];
  }
  __syncthreads();
  int w = tid >> 6, p = tid & 63;
  int gid = gid0 + w;
  int m = gid - b*Mn;
  float t = 0.f;
  #pragma unroll
  for (int c = 0; c < HA; ++c) t += Gs[p*65+c] * qs[w][c];
  float qpv = qs[w][p];
  float qq = qpv * t;
  float rs = qpv * Ks[p];
  #pragma unroll
  for (int off = 32; off; off >>= 1) {
    qq += __shfl_xor(qq, off, 64);
    rs += __shfl_xor(rs, off, 64);
  }
  float nrm = fmaxf(sqrtf(fmaxf(qq, 0.f)), 1e-12f);
  float s = rs / nrm;
  float dg = degree[m];
  float v1 = s*tw[p] + tb[p];
  float v2 = dg*sw2[p] + sb2[p];
  float* fp = f0 + (size_t)gid*DF;
  fp[32+p] = v1;
  fp[96+p] = v2;
  f0T[((size_t)b*DF + 32 + p)*Mn + m] = f2h(v1);
  f0T[((size_t)b*DF + 96 + p)*Mn + m] = f2h(v2);
}

// ---------------------------------------------------------------------------
// K5: GRU — fdot2 + pure-shuffle h broadcast (no LDS round trip).
// 32 lanes per seq, 8 seqs per 256-thr block, 500 blocks = 2000 waves.
__global__ __launch_bounds__(256) void k_gru(
    const in_t* __restrict__ x, const in_t* __restrict__ Wih, const in_t* __restrict__ Whh,
    const in_t* __restrict__ bih, const in_t* __restrict__ bhh, float* __restrict__ lh)
{
  int tid = threadIdx.x;
  int hid = tid & 31;
  int seq = blockIdx.x*8 + (tid >> 5);
  int b = seq / Mn, m = seq - b*Mn;
  unsigned int wr2[16], wz2[16], wn2[16];
  #pragma unroll
  for (int p = 0; p < 16; ++p) {
    wr2[p] = pack2h(Whh[(size_t)hid*32 + 2*p],      Whh[(size_t)hid*32 + 2*p + 1]);
    wz2[p] = pack2h(Whh[(size_t)(32+hid)*32 + 2*p], Whh[(size_t)(32+hid)*32 + 2*p + 1]);
    wn2[p] = pack2h(Whh[(size_t)(64+hid)*32 + 2*p], Whh[(size_t)(64+hid)*32 + 2*p + 1]);
  }
  float wir = Wih[hid], wiz = Wih[32+hid], win = Wih[64+hid];
  float brc  = bih[hid]    + bhh[hid];
  float bzc  = bih[32+hid] + bhh[32+hid];
  float binc = bih[64+hid];
  float bhnc = bhh[64+hid];
  float h = 0.f;
  unsigned int pk = 0u;     // packed (h[2k],h[2k+1]) valid in even lanes
  const in_t* xp = x + (size_t)b*Tn*Mn + m;
  float xcur = xp[0];
  for (int t = 0; t < Tn; ++t) {
    float xnext = (t < Tn-1) ? xp[(size_t)(t+1)*Mn] : 0.f;
    float rg = 0.f, zg = 0.f, ng = 0.f;
    #pragma unroll
    for (int p = 0; p < 16; ++p) {
      unsigned int pv = (unsigned int)__shfl((int)pk, 2*p, 32);
      h2v hp = __builtin_bit_cast(h2v, pv);
      rg = __builtin_amdgcn_fdot2(__builtin_bit_cast(h2v, wr2[p]), hp, rg, false);
      zg = __builtin_amdgcn_fdot2(__builtin_bit_cast(h2v, wz2[p]), hp, zg, false);
      ng = __builtin_amdgcn_fdot2(__builtin_bit_cast(h2v, wn2[p]), hp, ng, false);
    }
    float r = sigm(xcur*wir + brc + rg);
    float z = sigm(xcur*wiz + bzc + zg);
    float n = tanhfast(xcur*win + binc + r*(ng + bhnc));
    h = (1.f - z)*n + z*h;
    float hpart = __shfl_xor(h, 1, 64);
    pk = (hid & 1) ? pack2h(hpart, h) : pack2h(h, hpart);
    xcur = xnext;
  }
  lh[(size_t)seq*NHID + hid] = h;
}

// ---------------------------------------------------------------------------
// K6: A1/A2; thread = (gid, a) for both A1 and A2; 8 gids x 32 a per block, 500 blocks
__global__ __launch_bounds__(256) void k_a1a2(
    const float* __restrict__ lh, const in_t* __restrict__ W1, const in_t* __restrict__ W2,
    float* __restrict__ A1, float* __restrict__ A2)
{
  __shared__ float w1[32*33], w2[32*33];
  __shared__ float hs[8][33];
  int tid = threadIdx.x;
  for (int idx = tid; idx < 1024; idx += 256) {
    int a = idx >> 5, c = idx & 31;
    w1[a*33+c] = W1[idx];
    w2[a*33+c] = W2[idx];
  }
  int gid0 = blockIdx.x * 8;
  for (int idx = tid; idx < 256; idx += 256)
    hs[idx>>5][idx&31] = lh[(size_t)gid0*32 + idx];
  __syncthreads();
  int g = tid >> 5, a = tid & 31;
  int gid = gid0 + g;
  float s1 = 0.f, s2 = 0.f;
  #pragma unroll
  for (int c = 0; c < 32; ++c) {
    float hv = hs[g][c];
    s1 += hv * w1[a*33+c];
    s2 += hv * w2[a*33+c];
  }
  A1[(size_t)gid*32 + a] = s1;
  A2[(size_t)gid*32 + a] = s2;
}

// ---------------------------------------------------------------------------
// K7: dmat
__global__ __launch_bounds__(256) void k_dmat(
    const in_t* __restrict__ dgate, const in_t* __restrict__ degree, float* __restrict__ dmat)
{
  int idx = blockIdx.x*256 + threadIdx.x;
  if (idx >= Mn*Mn) return;
  int i = idx / Mn, j = idx - i*Mn;
  dmat[idx] = sigm(dgate[idx] * degree[i] * degree[j]);
}

// ---------------------------------------------------------------------------
// K8: a[b,i,j] = V . elu(A1_i + A2_j + b1) + bv   (f32 — sign feeds binarize)
__global__ __launch_bounds__(256) void k_pair(
    const float* __restrict__ A1, const float* __restrict__ A2, const in_t* __restrict__ Vv,
    const in_t* __restrict__ b1, const in_t* __restrict__ bv, float* __restrict__ aB)
{
  __shared__ float a1s[16][33], a2s[16][33], vs[32], b1s[32];
  int b = blockIdx.z;
  int i0 = blockIdx.y*16, j0 = blockIdx.x*16;
  int tid = threadIdx.x;
  if (tid < 32) { vs[tid] = Vv[tid]; b1s[tid] = b1[tid]; }
  {
    int r = tid >> 5, c = tid & 31;
    for (int rr = r; rr < 16; rr += 8) {
      int i = i0 + rr, j = j0 + rr;
      a1s[rr][c] = (i < Mn) ? A1[((size_t)b*Mn + i)*32 + c] : 0.f;
      a2s[rr][c] = (j < Mn) ? A2[((size_t)b*Mn + j)*32 + c] : 0.f;
    }
  }
  __syncthreads();
  int ti = tid >> 4, tj = tid & 15;
  int i = i0 + ti, j = j0 + tj;
  if (i >= Mn || j >= Mn) return;
  float acc = 0.f;
  #pragma unroll
  for (int c = 0; c < 32; ++c) {
    float u = a1s[ti][c] + a2s[tj][c] + b1s[c];
    acc += eluf(u) * vs[c];
  }
  aB[((size_t)b*Mn + i)*Mn + j] = acc + bv[0];
}

// ---------------------------------------------------------------------------
// K9a: partial column sum-squares over row chunks; grid (4 jblk, 8 isplit, Bz)
__global__ __launch_bounds__(128) void k_cnorm(const float* __restrict__ aB, float* __restrict__ ssp)
{
  int jb = blockIdx.x, isp = blockIdx.y, b = blockIdx.z;
  int j = jb*128 + threadIdx.x;
  if (j >= Mn) return;
  int i0 = isp*63, iend = min(i0 + 63, Mn);
  const float* ap = aB + (size_t)b*Mn*Mn + j;
  float ss = 0.f;
  for (int i = i0; i < iend; ++i) { float v = ap[(size_t)i*Mn]; ss += v*v; }
  ssp[((size_t)isp*Bz + b)*Mn + j] = ss;
}

// K9b: finalize cinv
__global__ __launch_bounds__(256) void k_cfin(const float* __restrict__ ssp, float* __restrict__ cinv)
{
  int idx = blockIdx.x*256 + threadIdx.x;
  if (idx >= Bz*Mn) return;
  int b = idx / Mn, j = idx - b*Mn;
  float ss = 0.f;
  #pragma unroll
  for (int sp = 0; sp < 8; ++sp) ss += ssp[((size_t)sp*Bz + b)*Mn + j];
  cinv[idx] = 1.f / fmaxf(sqrtf(ss), 1e-12f);
}

// ---------------------------------------------------------------------------
// K10: c_gate GEMM fp16 MFMA, 512 threads (8 waves, 2x4 wave grid)
__global__ __launch_bounds__(512) void k_cgemm(
    const float* __restrict__ aB, const float* __restrict__ cinv, const in_t* __restrict__ Wb,
    const in_t* __restrict__ wb, const in_t* __restrict__ adj_geo, const float* __restrict__ dmat,
    float* __restrict__ adjb)
{
  __shared__ unsigned short As[64*72], Bs[64*72];
  int b = blockIdx.z, i0 = blockIdx.y*64, j0 = blockIdx.x*64;
  int tid = threadIdx.x;
  const float* aRow = aB + (size_t)b*Mn*Mn;
  const float* civ = cinv + b*Mn;
  int w = tid >> 6, lane = tid & 63, ln = lane & 15, lg = lane >> 4;
  int wm = (w >> 2)*32, wn = (w & 3)*16;
  f32x4 acc[2];
  acc[0] = (f32x4)(0.f); acc[1] = (f32x4)(0.f);

  for (int k0 = 0; k0 < 512; k0 += 64) {
    for (int idx = tid; idx < 2048; idx += 512) {
      int r = idx >> 5, cp = idx & 31;
      int i = i0 + r, k = k0 + 2*cp;
      unsigned int v = 0;
      if (i < Mn && k < Mn)
        v = pack2h(aRow[(size_t)i*Mn + k]*civ[k], aRow[(size_t)i*Mn + k + 1]*civ[k+1]);
      *reinterpret_cast<unsigned int*>(&As[r*72 + 2*cp]) = v;
    }
    for (int idx = tid; idx < 2048; idx += 512) {
      int c = idx & 63, rp = idx >> 6;
      int j = j0 + c, k = k0 + 2*rp;
      unsigned int v = 0;
      if (j < Mn && k < Mn)
        v = pack2h(Wb[(size_t)k*Mn + j], Wb[(size_t)(k+1)*Mn + j]);
      *reinterpret_cast<unsigned int*>(&Bs[c*72 + 2*rp]) = v;
    }
    __syncthreads();
    #pragma unroll
    for (int kk = 0; kk < 2; ++kk) {
      half8 a0 = *reinterpret_cast<const half8*>(&As[(wm + 0  + ln)*72 + kk*32 + lg*8]);
      half8 a1 = *reinterpret_cast<const half8*>(&As[(wm + 16 + ln)*72 + kk*32 + lg*8]);
      half8 b0 = *reinterpret_cast<const half8*>(&Bs[(wn + ln)*72 + kk*32 + lg*8]);
      acc[0] = MFMAH(a0, b0, acc[0], 0, 0, 0);
      acc[1] = MFMAH(a1, b0, acc[1], 0, 0, 0);
    }
    __syncthreads();
  }
  float wbv = wb[0];
  #pragma unroll
  for (int mt = 0; mt < 2; ++mt)
    #pragma unroll
    for (int r = 0; r < 4; ++r) {
      int i = i0 + wm + mt*16 + lg*4 + r;
      int j = j0 + wn + ln;
      if (i < Mn && j < Mn) {
        float cg = sigm(acc[mt][r] + wbv);
        float av = aRow[(size_t)i*Mn + j]*civ[j];
        float ag = adj_geo[(size_t)i*Mn + j];
        float adjf = ag*cg + av*(1.f - cg) + dmat[(size_t)i*Mn + j]*ag;
        adjb[((size_t)b*Mn + i)*Mn + j] = (adjf > 0.f) ? 1.f : adjf;
      }
    }
}

// ---------------------------------------------------------------------------
// K11: laplace row-normalize -> fp16 lapB
__global__ __launch_bounds__(256) void k_lap(const float* __restrict__ adjb, unsigned short* __restrict__ lapB)
{
  int b = blockIdx.y, i = blockIdx.x;
  const float* row = adjb + ((size_t)b*Mn + i)*Mn;
  int tid = threadIdx.x;
  float s = 0.f;
  for (int j = tid; j < Mn; j += 256) s += row[j];
  __shared__ float red[8];
  int lane = tid & 63, wv = tid >> 6;
  #pragma unroll
  for (int off = 32; off; off >>= 1) s += __shfl_down(s, off);
  if (lane == 0) red[wv] = s;
  __syncthreads();
  if (tid == 0) {
    float d = red[0] + red[1] + red[2] + red[3];
    red[4] = (d > 0.f) ? 1.f/d : 0.f;
  }
  __syncthreads();
  float inv = red[4];
  unsigned short* lrow = lapB + ((size_t)b*Mn + i)*Mn;
  for (int j = tid; j < Mn; j += 256) lrow[j] = f2h(row[j]*inv);
}

// ---------------------------------------------------------------------------
// K12: spmm via fp16 MFMA, 32x32 tiles: grid (5, 16, Bz)
__global__ __launch_bounds__(256) void k_spmm(
    const unsigned short* __restrict__ lapB, const unsigned short* __restrict__ fT,
    unsigned short* __restrict__ tmpB)
{
  __shared__ unsigned short As[32*72], Bs[32*72];
  int b = blockIdx.z, i0 = blockIdx.y*32, j0 = blockIdx.x*32;
  int tid = threadIdx.x;
  int w = tid >> 6, lane = tid & 63, ln = lane & 15, lg = lane >> 4;
  int wm = (w >> 1)*16, wn = (w & 1)*16;
  f32x4 acc = (f32x4)(0.f);

  for (int k0 = 0; k0 < 512; k0 += 64) {
    for (int idx = tid; idx < 1024; idx += 256) {
      int r = idx >> 5, cp = idx & 31;
      int i = i0 + r, k = k0 + 2*cp;
      unsigned int v = 0;
      if (i < Mn && k < Mn)
        v = *reinterpret_cast<const unsigned int*>(&lapB[((size_t)b*Mn + i)*Mn + k]);
      *reinterpret_cast<unsigned int*>(&As[r*72 + 2*cp]) = v;
    }
    for (int idx = tid; idx < 1024; idx += 256) {
      int r = idx >> 5, cp = idx & 31;
      int d = j0 + r, k = k0 + 2*cp;
      unsigned int v = 0;
      if (k < Mn)
        v = *reinterpret_cast<const unsigned int*>(&fT[((size_t)b*DF + d)*Mn + k]);
      *reinterpret_cast<unsigned int*>(&Bs[r*72 + 2*cp]) = v;
    }
    __syncthreads();
    #pragma unroll
    for (int kk = 0; kk < 2; ++kk) {
      half8 a0 = *reinterpret_cast<const half8*>(&As[(wm + ln)*72 + kk*32 + lg*8]);
      half8 b0 = *reinterpret_cast<const half8*>(&Bs[(wn + ln)*72 + kk*32 + lg*8]);
      acc = MFMAH(a0, b0, acc, 0, 0, 0);
    }
    __syncthreads();
  }
  #pragma unroll
  for (int r = 0; r < 4; ++r) {
    int i = i0 + wm + lg*4 + r;
    int j = j0 + wn + ln;
    if (i < Mn)
      tmpB[((size_t)b*Mn + i)*DF + j] = f2h(acc[r]);
  }
}

// ---------------------------------------------------------------------------
// K13: dense 32x32 tiles: grid (5, 125)
__global__ __launch_bounds__(256) void k_dense(
    const unsigned short* __restrict__ tmpB, const in_t* __restrict__ W, const in_t* __restrict__ bias,
    float* __restrict__ fout, unsigned short* __restrict__ foutT)
{
  __shared__ unsigned short As[32*72], Bs[32*72];
  __shared__ float bs[32];
  int i0 = blockIdx.y*32, j0 = blockIdx.x*32;
  int tid = threadIdx.x;
  if (tid < 32) bs[tid] = bias[j0 + tid];
  int w = tid >> 6, lane = tid & 63, ln = lane & 15, lg = lane >> 4;
  int wm = (w >> 1)*16, wn = (w & 1)*16;
  f32x4 acc = (f32x4)(0.f);

  for (int k0 = 0; k0 < 192; k0 += 64) {
    for (int idx = tid; idx < 1024; idx += 256) {
      int r = idx >> 5, cp = idx & 31;
      int i = i0 + r, k = k0 + 2*cp;
      unsigned int v = 0;
      if (k < DF)
        v = *reinterpret_cast<const unsigned int*>(&tmpB[(size_t)i*DF + k]);
      *reinterpret_cast<unsigned int*>(&As[r*72 + 2*cp]) = v;
    }
    for (int idx = tid; idx < 1024; idx += 256) {
      int c = idx & 31, rp = idx >> 5;
      int j = j0 + c, k = k0 + 2*rp;
      unsigned int v = 0;
      if (k < DF)
        v = pack2h(W[(size_t)k*DF + j], W[(size_t)(k+1)*DF + j]);
      *reinterpret_cast<unsigned int*>(&Bs[c*72 + 2*rp]) = v;
    }
    __syncthreads();
    #pragma unroll
    for (int kk = 0; kk < 2; ++kk) {
      half8 a0 = *reinterpret_cast<const half8*>(&As[(wm + ln)*72 + kk*32 + lg*8]);
      half8 b0 = *reinterpret_cast<const half8*>(&Bs[(wn + ln)*72 + kk*32 + lg*8]);
      acc = MFMAH(a0, b0, acc, 0, 0, 0);
    }
    __syncthreads();
  }
  #pragma unroll
  for (int r = 0; r < 4; ++r) {
    int i = i0 + wm + lg*4 + r;
    int jl = wn + ln;
    int j = j0 + jl;
    float val = eluf(acc[r] + bs[jl]);
    fout[(size_t)i*DF + j] = val;
    if (foutT) {
      int bb = i / Mn, mm = i - bb*Mn;
      foutT[((size_t)bb*DF + j)*Mn + mm] = f2h(val);
    }
  }
}

// ---------------------------------------------------------------------------
// K14: output projection — one wave per output row, lanes over channels
__global__ __launch_bounds__(256) void k_out(
    const float* __restrict__ f0, const float* __restrict__ f1, const float* __restrict__ f2,
    const float* __restrict__ lh, const in_t* __restrict__ ow, const in_t* __restrict__ ob,
    float* __restrict__ outp)
{
  __shared__ float w[FINALC];
  int tid = threadIdx.x;
  for (int i = tid; i < FINALC; i += 256) w[i] = ow[i];
  __syncthreads();
  int lane = tid & 63;
  int gid = blockIdx.x*4 + (tid >> 6);
  const float* p0 = f0 + (size_t)gid*DF;
  const float* p1 = f1 + (size_t)gid*DF;
  const float* p2 = f2 + (size_t)gid*DF;
  const float* pl = lh + (size_t)gid*NHID;
  float s = 0.f;
  #pragma unroll
  for (int ch = 0; ch < 8; ++ch) {
    int ci = ch*64 + lane;
    float v;
    if (ci < DF)          v = p0[ci];
    else if (ci < 2*DF)   v = p1[ci - DF];
    else if (ci < 3*DF)   v = p2[ci - 2*DF];
    else                  v = pl[ci - 3*DF];
    s += v * w[ci];
  }
  #pragma unroll
  for (int off = 32; off; off >>= 1) s += __shfl_down(s, off, 64);
  if (lane == 0) outp[gid] = s + ob[0];
}

// ---------------------------------------------------------------------------
extern "C" void kernel_launch(void* const* d_in, const int* in_sizes, int n_in,
                              void* d_out, int out_size, void* d_ws, size_t ws_size,
                              hipStream_t stream)
{
  const in_t* x       = (const in_t*)d_in[0];
  const in_t* adj_geo = (const in_t*)d_in[1];
  const in_t* degree  = (const in_t*)d_in[2];
  const in_t* conv_s_w= (const in_t*)d_in[3];
  const in_t* conv_s_b= (const in_t*)d_in[4];
  const in_t* conv_l_w= (const in_t*)d_in[5];
  const in_t* conv_l_b= (const in_t*)d_in[6];
  const in_t* WQ_w    = (const in_t*)d_in[7];
  const in_t* WQ_b    = (const in_t*)d_in[8];
  const in_t* WK_w    = (const in_t*)d_in[9];
  const in_t* WK_b    = (const in_t*)d_in[10];
  const in_t* tenc_w  = (const in_t*)d_in[11];
  const in_t* tenc_b  = (const in_t*)d_in[12];
  const in_t* senc_w  = (const in_t*)d_in[13];
  const in_t* senc_b  = (const in_t*)d_in[14];
  const in_t* gru_Wih = (const in_t*)d_in[15];
  const in_t* gru_Whh = (const in_t*)d_in[16];
  const in_t* gru_bih = (const in_t*)d_in[17];
  const in_t* gru_bhh = (const in_t*)d_in[18];
  const in_t* Vv      = (const in_t*)d_in[19];
  const in_t* W1      = (const in_t*)d_in[20];
  const in_t* W2      = (const in_t*)d_in[21];
  const in_t* Wb      = (const in_t*)d_in[22];
  const in_t* bv      = (const in_t*)d_in[23];
  const in_t* b1      = (const in_t*)d_in[24];
  const in_t* wb      = (const in_t*)d_in[25];
  const in_t* d_gate  = (const in_t*)d_in[26];
  const in_t* gnn_w   = (const in_t*)d_in[27];
  const in_t* gnn_b   = (const in_t*)d_in[28];
  const in_t* out_w   = (const in_t*)d_in[29];
  const in_t* out_b   = (const in_t*)d_in[30];
  float* out = (float*)d_out;

  // workspace carve-up (float offsets)
  float* ws   = (float*)d_ws;
  float* hSC  = ws;                    // 128000
  float* Qb   = ws + 128000;           // 256000
  float* Ktb  = ws + 384000;           // 256000
  float* lh   = ws + 673280;           // 128000
  float* A1   = ws + 801280;           // 128000
  float* A2   = ws + 929280;           // 128000
  float* aB   = ws + 1057280;          // 2000000 (dead after k_cgemm; lapB overlays)
  float* cinv = ws + 3057280;          // 4000
  float* adjb = ws + 3061280;          // 2000000
  float* dmat = ws + 5061280;          // 250000
  float* f0   = ws + 5311280;          // 640000
  float* f1   = ws + 5951280;          // 640000
  float* f2   = ws + 6591280;          // 640000
  unsigned short* f0T  = (unsigned short*)(ws + 7231280);  // 640000 fp16
  unsigned short* tmpB = (unsigned short*)(ws + 7551280);  // 640000 fp16
  unsigned short* f1T  = (unsigned short*)(ws + 7871280);  // 640000 fp16
  unsigned short* lapB = (unsigned short*)aB;              // fp16 overlay (aB dead after cgemm)
  // transient partials in adjb region (adjb written only later by k_cgemm):
  float* Gpart = adjb;                 // 8*8*4096 = 262144
  float* Kpart = adjb + 262144;        // 8*8*64   = 4096
  float* ssp   = adjb + 266240;        // 8*8*500  = 32000
  float* Gfull = adjb + 298240;        // 8*4096   = 32768
  float* Kfull = adjb + 331008;        // 8*64     = 512

  k_conv<<<dim3(250), 256, 0, stream>>>(x, conv_s_w, conv_s_b, conv_l_w, conv_l_b, hSC, f0, f0T);
  k_qk<<<dim3(1000), 256, 0, stream>>>(hSC, WQ_w, WQ_b, WK_w, WK_b, Qb, Ktb);
  k_gram<<<dim3(GSPLIT, Bz), 256, 0, stream>>>(Ktb, Gpart, Kpart);
  k_gfin<<<dim3(Bz), 256, 0, stream>>>(Gpart, Kpart, Gfull, Kfull);
  k_sglob<<<dim3(1000), 256, 0, stream>>>(Qb, Gfull, Kfull, degree, tenc_w, tenc_b, senc_w, senc_b, f0, f0T);
  k_gru<<<dim3(500), 256, 0, stream>>>(x, gru_Wih, gru_Whh, gru_bih, gru_bhh, lh);
  k_a1a2<<<dim3(500), 256, 0, stream>>>(lh, W1, W2, A1, A2);
  k_dmat<<<dim3((Mn*Mn + 255)/256), 256, 0, stream>>>(d_gate, degree, dmat);
  k_pair<<<dim3(32, 32, Bz), 256, 0, stream>>>(A1, A2, Vv, b1, bv, aB);
  k_cnorm<<<dim3(4, 8, Bz), 128, 0, stream>>>(aB, ssp);
  k_cfin<<<dim3(16), 256, 0, stream>>>(ssp, cinv);
  k_cgemm<<<dim3(8, 8, Bz), 512, 0, stream>>>(aB, cinv, Wb, wb, adj_geo, dmat, adjb);
  k_lap<<<dim3(Mn, Bz), 256, 0, stream>>>(adjb, lapB);
  // GNN layer 0
  k_spmm<<<dim3(5, 16, Bz), 256, 0, stream>>>(lapB, f0T, tmpB);
  k_dense<<<dim3(5, 125), 256, 0, stream>>>(tmpB, gnn_w, gnn_b, f1, f1T);
  // GNN layer 1
  k_spmm<<<dim3(5, 16, Bz), 256, 0, stream>>>(lapB, f1T, tmpB);
  k_dense<<<dim3(5, 125), 256, 0, stream>>>(tmpB, gnn_w + DF*DF, gnn_b + DF, f2, (unsigned short*)nullptr);
  k_out<<<dim3(1000), 256, 0, stream>>>(f0, f1, f2, lh, out_w, out_b, out);
}

// Round 13
// 230.963 us; speedup vs baseline: 2.0089x; 1.0266x over previous
//
#include <hip/hip_runtime.h>
#include <hip/hip_bf16.h>

// Problem constants
#define Bz 8
#define Tn 64
#define Mn 500
#define KC 16
#define HA 64
#define HR 64
#define NHID 32
#define DF 160
#define FINALC 512
#define GSPLIT 8

typedef float in_t;   // reference dtypes are all float32
typedef __attribute__((ext_vector_type(8))) _Float16 half8;
typedef __attribute__((ext_vector_type(2))) _Float16 h2v;
typedef __attribute__((ext_vector_type(4))) float f32x4;
#define MFMAH __builtin_amdgcn_mfma_f32_16x16x32_f16

__device__ __forceinline__ float sigm(float x){ return 1.0f/(1.0f+__expf(-x)); }
__device__ __forceinline__ float tanhfast(float x){ float e=__expf(2.0f*x); return 1.0f-2.0f/(e+1.0f); }
__device__ __forceinline__ float eluf(float x){ return x>0.0f? x : (__expf(x)-1.0f); }
__device__ __forceinline__ unsigned short f2h(float f){
  _Float16 h = (_Float16)f;
  return *reinterpret_cast<unsigned short*>(&h);
}
__device__ __forceinline__ unsigned int pack2h(float a, float b){
  return (unsigned int)f2h(a) | ((unsigned int)f2h(b) << 16);
}

// ---------------------------------------------------------------------------
// K1: convs; 16 nodes x 16 features per 256-block, 250 blocks
__global__ __launch_bounds__(256) void k_conv(
    const in_t* __restrict__ x, const in_t* __restrict__ wsw, const in_t* __restrict__ wsb,
    const in_t* __restrict__ wlw, const in_t* __restrict__ wlb,
    float* __restrict__ hSC, float* __restrict__ f0, unsigned short* __restrict__ f0T)
{
  __shared__ float sw[KC*65], lw[KC*65];
  __shared__ float sb[KC], lb[KC];
  __shared__ float xs[16*65];
  int tid = threadIdx.x;
  for (int idx = tid; idx < KC*Tn; idx += 256) {
    int k = idx >> 6, t = idx & 63;
    sw[k*65+t] = wsw[idx];
    lw[k*65+t] = 0.5f * wlw[k*32 + (t>>1)];
  }
  if (tid < KC) { sb[tid] = wsb[tid]; lb[tid] = wlb[tid]; }
  int ng0 = blockIdx.x * 16;
  for (int idx = tid; idx < 16*Tn; idx += 256) {
    int t = idx >> 4, nl = idx & 15;
    int ng = ng0 + nl;
    int b = ng / Mn, m = ng - b*Mn;
    xs[nl*65 + t] = x[(size_t)b*Tn*Mn + (size_t)t*Mn + m];
  }
  __syncthreads();
  int nl = tid >> 4, k = tid & 15;
  int ng = ng0 + nl;
  int b = ng / Mn, m = ng - b*Mn;
  float s = 0.f, l = 0.f;
  #pragma unroll
  for (int t = 0; t < Tn; ++t) {
    float xv = xs[nl*65+t];
    s += xv * sw[k*65+t];
    l += xv * lw[k*65+t];
  }
  float vs = fmaxf(s + sb[k], 0.f);
  float vl = fmaxf(l + lb[k], 0.f);
  size_t base = (size_t)b*Mn + m;
  hSC[base*32 + k]      = vs; hSC[base*32 + KC + k] = vl;
  f0[base*DF + k]       = vs; f0[base*DF + KC + k]  = vl;
  f0T[((size_t)b*DF + k)*Mn + m]      = f2h(vs);
  f0T[((size_t)b*DF + KC + k)*Mn + m] = f2h(vl);
}

// ---------------------------------------------------------------------------
// K2: Q/K projections; thread = (gid, a), 4 gids x 64 outputs per block, 1000 blocks
__global__ __launch_bounds__(256) void k_qk(
    const float* __restrict__ hSC, const in_t* __restrict__ WQw, const in_t* __restrict__ WQb,
    const in_t* __restrict__ WKw, const in_t* __restrict__ WKb,
    float* __restrict__ Q, float* __restrict__ Kt)
{
  __shared__ float wq[HA*33], wk[HA*33];
  __shared__ float hs[4][32];
  __shared__ float bq[HA], bk[HA];
  int tid = threadIdx.x;
  for (int idx = tid; idx < HA*32; idx += 256) {
    int a = idx >> 5, c = idx & 31;
    wq[a*33+c] = WQw[idx];
    wk[a*33+c] = WKw[idx];
  }
  if (tid < HA) { bq[tid] = WQb[tid]; bk[tid] = WKb[tid]; }
  int gid0 = blockIdx.x * 4;
  for (int idx = tid; idx < 128; idx += 256)
    hs[idx>>5][idx&31] = hSC[(size_t)gid0*32 + idx];
  __syncthreads();
  int g = tid >> 6, a = tid & 63;
  int gid = gid0 + g;
  float aq = bq[a], ak = bk[a];
  #pragma unroll
  for (int c = 0; c < 32; ++c) {
    float hv = hs[g][c];
    aq += hv * wq[a*33+c];
    ak += hv * wk[a*33+c];
  }
  Q[(size_t)gid*HA + a]  = aq;
  Kt[(size_t)gid*HA + a] = ak;
}

// ---------------------------------------------------------------------------
// K3: split-K partial Gram
__global__ __launch_bounds__(256) void k_gram(
    const float* __restrict__ Kt, float* __restrict__ Gpart, float* __restrict__ Kpart)
{
  int split = blockIdx.x, b = blockIdx.y;
  int tid = threadIdx.x;
  __shared__ float L[64][HA];
  int m0 = split*63;
  int mend = min(m0 + 63, Mn);
  int p = tid & 63;
  int q0 = (tid >> 6) * 16;
  float acc[16];
  #pragma unroll
  for (int e = 0; e < 16; ++e) acc[e] = 0.f;
  for (int idx = tid; idx < 64*HA; idx += 256) {
    int r = idx >> 6, c = idx & 63;
    int m = m0 + r;
    L[r][c] = (m < mend) ? Kt[((size_t)b*Mn + m)*HA + c] : 0.f;
  }
  __syncthreads();
  float ks = 0.f;
  #pragma unroll 4
  for (int r = 0; r < 63; ++r) {
    float lp = L[r][p];
    if (tid < 64) ks += lp;
    #pragma unroll
    for (int e = 0; e < 16; ++e) acc[e] += lp * L[r][q0+e];
  }
  float* gp = Gpart + ((size_t)split*Bz + b)*HA*HA;
  #pragma unroll
  for (int e = 0; e < 16; ++e) gp[p*HA + q0 + e] = acc[e];
  if (tid < 64) Kpart[((size_t)split*Bz + b)*HA + tid] = ks;
}

// K3b: sum the GSPLIT partials once per batch
__global__ __launch_bounds__(256) void k_gfin(
    const float* __restrict__ Gpart, const float* __restrict__ Kpart,
    float* __restrict__ Gfull, float* __restrict__ Kfull)
{
  int b = blockIdx.x;
  int tid = threadIdx.x;
  for (int i = tid; i < HA*HA; i += 256) {
    float s = 0.f;
    #pragma unroll
    for (int sp = 0; sp < GSPLIT; ++sp) s += Gpart[((size_t)sp*Bz + b)*HA*HA + i];
    Gfull[(size_t)b*HA*HA + i] = s;
  }
  if (tid < HA) {
    float s = 0.f;
    #pragma unroll
    for (int sp = 0; sp < GSPLIT; ++sp) s += Kpart[((size_t)sp*Bz + b)*HA + tid];
    Kfull[b*HA + tid] = s;
  }
}

// ---------------------------------------------------------------------------
// K4: s-glob + h_L; wave-per-m (4 m per block), 1000 blocks
__global__ __launch_bounds__(256) void k_sglob(
    const float* __restrict__ Q, const float* __restrict__ Gfull, const float* __restrict__ Kfull,
    const in_t* __restrict__ degree, const in_t* __restrict__ tencw, const in_t* __restrict__ tencb,
    const in_t* __restrict__ sencw, const in_t* __restrict__ sencb,
    float* __restrict__ f0, unsigned short* __restrict__ f0T)
{
  __shared__ float Gs[HA*65];
  __shared__ float qs[4][HA];
  __shared__ float Ks[HA], tw[HR], tb[HR], sw2[HR], sb2[HR];
  int tid = threadIdx.x;
  int gid0 = blockIdx.x*4;
  int b = gid0 / Mn;
  for (int idx = tid; idx < HA*HA; idx += 256) {
    int p = idx >> 6, c = idx & 63;
    Gs[p*65+c] = Gfull[(size_t)b*HA*HA + idx];
  }
  for (int idx = tid; idx < 4*HA; idx += 256)
    qs[idx>>6][idx&63] = Q[(size_t)gid0*HA + idx];
  if (tid < HA) {
    Ks[tid] = Kfull[b*HA + tid];
    tw[tid] = tencw[tid]; tb[tid] = tencb[tid];
    sw2[tid] = sencw[tid]; sb2[tid] = sencb[tid];
  }
  __syncthreads();
  int w = tid >> 6, p = tid & 63;
  int gid = gid0 + w;
  int m = gid - b*Mn;
  float t = 0.f;
  #pragma unroll
  for (int c = 0; c < HA; ++c) t += Gs[p*65+c] * qs[w][c];
  float qpv = qs[w][p];
  float qq = qpv * t;
  float rs = qpv * Ks[p];
  #pragma unroll
  for (int off = 32; off; off >>= 1) {
    qq += __shfl_xor(qq, off, 64);
    rs += __shfl_xor(rs, off, 64);
  }
  float nrm = fmaxf(sqrtf(fmaxf(qq, 0.f)), 1e-12f);
  float s = rs / nrm;
  float dg = degree[m];
  float v1 = s*tw[p] + tb[p];
  float v2 = dg*sw2[p] + sb2[p];
  float* fp = f0 + (size_t)gid*DF;
  fp[32+p] = v1;
  fp[96+p] = v2;
  f0T[((size_t)b*DF + 32 + p)*Mn + m] = f2h(v1);
  f0T[((size_t)b*DF + 96 + p)*Mn + m] = f2h(v2);
}

// ---------------------------------------------------------------------------
// K5: GRU — fdot2 + LDS h exchange (round-11) + x tile staged in LDS.
// 32 lanes per seq, 8 seqs per 256-thr block, 500 blocks = 2000 waves.
__global__ __launch_bounds__(256) void k_gru(
    const in_t* __restrict__ x, const in_t* __restrict__ Wih, const in_t* __restrict__ Whh,
    const in_t* __restrict__ bih, const in_t* __restrict__ bhh, float* __restrict__ lh)
{
  __shared__ unsigned int h2[8][20];
  __shared__ float xs[Tn*8];           // [t][s]
  int tid = threadIdx.x;
  int hid = tid & 31;
  int ls  = tid >> 5;
  int seq = blockIdx.x*8 + ls;
  int b = seq / Mn, m = seq - b*Mn;
  // stage x: 512 elements, coalesced (8 consecutive m per t)
  for (int idx = tid; idx < Tn*8; idx += 256) {
    int t = idx >> 3, s = idx & 7;
    int gs = blockIdx.x*8 + s;
    int bb = gs / Mn, mm = gs - bb*Mn;
    xs[idx] = x[(size_t)bb*Tn*Mn + (size_t)t*Mn + mm];
  }
  unsigned int wr2[16], wz2[16], wn2[16];
  #pragma unroll
  for (int p = 0; p < 16; ++p) {
    wr2[p] = pack2h(Whh[(size_t)hid*32 + 2*p],      Whh[(size_t)hid*32 + 2*p + 1]);
    wz2[p] = pack2h(Whh[(size_t)(32+hid)*32 + 2*p], Whh[(size_t)(32+hid)*32 + 2*p + 1]);
    wn2[p] = pack2h(Whh[(size_t)(64+hid)*32 + 2*p], Whh[(size_t)(64+hid)*32 + 2*p + 1]);
  }
  float wir = Wih[hid], wiz = Wih[32+hid], win = Wih[64+hid];
  float brc  = bih[hid]    + bhh[hid];
  float bzc  = bih[32+hid] + bhh[32+hid];
  float binc = bih[64+hid];
  float bhnc = bhh[64+hid];
  if (!(hid & 1)) h2[ls][hid>>1] = 0u;
  __syncthreads();
  float h = 0.f;
  for (int t = 0; t < Tn; ++t) {
    float xcur = xs[t*8 + ls];
    float rg = 0.f, zg = 0.f, ng = 0.f;
    #pragma unroll
    for (int p = 0; p < 16; ++p) {
      h2v hp = __builtin_bit_cast(h2v, h2[ls][p]);
      rg = __builtin_amdgcn_fdot2(__builtin_bit_cast(h2v, wr2[p]), hp, rg, false);
      zg = __builtin_amdgcn_fdot2(__builtin_bit_cast(h2v, wz2[p]), hp, zg, false);
      ng = __builtin_amdgcn_fdot2(__builtin_bit_cast(h2v, wn2[p]), hp, ng, false);
    }
    float r = sigm(xcur*wir + brc + rg);
    float z = sigm(xcur*wiz + bzc + zg);
    float n = tanhfast(xcur*win + binc + r*(ng + bhnc));
    h = (1.f - z)*n + z*h;
    float hpart = __shfl_xor(h, 1, 64);
    unsigned int pk = (hid & 1) ? pack2h(hpart, h) : pack2h(h, hpart);
    if (!(hid & 1)) h2[ls][hid>>1] = pk;
  }
  lh[(size_t)seq*NHID + hid] = h;
}

// ---------------------------------------------------------------------------
// K6: A1/A2; thread = (gid, a); 8 gids x 32 a per block, 500 blocks
__global__ __launch_bounds__(256) void k_a1a2(
    const float* __restrict__ lh, const in_t* __restrict__ W1, const in_t* __restrict__ W2,
    float* __restrict__ A1, float* __restrict__ A2)
{
  __shared__ float w1[32*33], w2[32*33];
  __shared__ float hs[8][33];
  int tid = threadIdx.x;
  for (int idx = tid; idx < 1024; idx += 256) {
    int a = idx >> 5, c = idx & 31;
    w1[a*33+c] = W1[idx];
    w2[a*33+c] = W2[idx];
  }
  int gid0 = blockIdx.x * 8;
  for (int idx = tid; idx < 256; idx += 256)
    hs[idx>>5][idx&31] = lh[(size_t)gid0*32 + idx];
  __syncthreads();
  int g = tid >> 5, a = tid & 31;
  int gid = gid0 + g;
  float s1 = 0.f, s2 = 0.f;
  #pragma unroll
  for (int c = 0; c < 32; ++c) {
    float hv = hs[g][c];
    s1 += hv * w1[a*33+c];
    s2 += hv * w2[a*33+c];
  }
  A1[(size_t)gid*32 + a] = s1;
  A2[(size_t)gid*32 + a] = s2;
}

// ---------------------------------------------------------------------------
// K7: dmat
__global__ __launch_bounds__(256) void k_dmat(
    const in_t* __restrict__ dgate, const in_t* __restrict__ degree, float* __restrict__ dmat)
{
  int idx = blockIdx.x*256 + threadIdx.x;
  if (idx >= Mn*Mn) return;
  int i = idx / Mn, j = idx - i*Mn;
  dmat[idx] = sigm(dgate[idx] * degree[i] * degree[j]);
}

// ---------------------------------------------------------------------------
// K8: a[b,i,j] = V . elu(A1_i + A2_j + b1) + bv   (f32 — sign feeds binarize)
__global__ __launch_bounds__(256) void k_pair(
    const float* __restrict__ A1, const float* __restrict__ A2, const in_t* __restrict__ Vv,
    const in_t* __restrict__ b1, const in_t* __restrict__ bv, float* __restrict__ aB)
{
  __shared__ float a1s[16][33], a2s[16][33], vs[32], b1s[32];
  int b = blockIdx.z;
  int i0 = blockIdx.y*16, j0 = blockIdx.x*16;
  int tid = threadIdx.x;
  if (tid < 32) { vs[tid] = Vv[tid]; b1s[tid] = b1[tid]; }
  {
    int r = tid >> 5, c = tid & 31;
    for (int rr = r; rr < 16; rr += 8) {
      int i = i0 + rr, j = j0 + rr;
      a1s[rr][c] = (i < Mn) ? A1[((size_t)b*Mn + i)*32 + c] : 0.f;
      a2s[rr][c] = (j < Mn) ? A2[((size_t)b*Mn + j)*32 + c] : 0.f;
    }
  }
  __syncthreads();
  int ti = tid >> 4, tj = tid & 15;
  int i = i0 + ti, j = j0 + tj;
  if (i >= Mn || j >= Mn) return;
  float acc = 0.f;
  #pragma unroll
  for (int c = 0; c < 32; ++c) {
    float u = a1s[ti][c] + a2s[tj][c] + b1s[c];
    acc += eluf(u) * vs[c];
  }
  aB[((size_t)b*Mn + i)*Mn + j] = acc + bv[0];
}

// ---------------------------------------------------------------------------
// K9a: partial column sum-squares over row chunks; grid (4 jblk, 8 isplit, Bz)
__global__ __launch_bounds__(128) void k_cnorm(const float* __restrict__ aB, float* __restrict__ ssp)
{
  int jb = blockIdx.x, isp = blockIdx.y, b = blockIdx.z;
  int j = jb*128 + threadIdx.x;
  if (j >= Mn) return;
  int i0 = isp*63, iend = min(i0 + 63, Mn);
  const float* ap = aB + (size_t)b*Mn*Mn + j;
  float ss = 0.f;
  for (int i = i0; i < iend; ++i) { float v = ap[(size_t)i*Mn]; ss += v*v; }
  ssp[((size_t)isp*Bz + b)*Mn + j] = ss;
}

// K9b: finalize cinv
__global__ __launch_bounds__(256) void k_cfin(const float* __restrict__ ssp, float* __restrict__ cinv)
{
  int idx = blockIdx.x*256 + threadIdx.x;
  if (idx >= Bz*Mn) return;
  int b = idx / Mn, j = idx - b*Mn;
  float ss = 0.f;
  #pragma unroll
  for (int sp = 0; sp < 8; ++sp) ss += ssp[((size_t)sp*Bz + b)*Mn + j];
  cinv[idx] = 1.f / fmaxf(sqrtf(ss), 1e-12f);
}

// ---------------------------------------------------------------------------
// K10: c_gate GEMM fp16 MFMA, 512 threads (8 waves, 2x4 wave grid)
__global__ __launch_bounds__(512) void k_cgemm(
    const float* __restrict__ aB, const float* __restrict__ cinv, const in_t* __restrict__ Wb,
    const in_t* __restrict__ wb, const in_t* __restrict__ adj_geo, const float* __restrict__ dmat,
    float* __restrict__ adjb)
{
  __shared__ unsigned short As[64*72], Bs[64*72];
  int b = blockIdx.z, i0 = blockIdx.y*64, j0 = blockIdx.x*64;
  int tid = threadIdx.x;
  const float* aRow = aB + (size_t)b*Mn*Mn;
  const float* civ = cinv + b*Mn;
  int w = tid >> 6, lane = tid & 63, ln = lane & 15, lg = lane >> 4;
  int wm = (w >> 2)*32, wn = (w & 3)*16;
  f32x4 acc[2];
  acc[0] = (f32x4)(0.f); acc[1] = (f32x4)(0.f);

  for (int k0 = 0; k0 < 512; k0 += 64) {
    for (int idx = tid; idx < 2048; idx += 512) {
      int r = idx >> 5, cp = idx & 31;
      int i = i0 + r, k = k0 + 2*cp;
      unsigned int v = 0;
      if (i < Mn && k < Mn)
        v = pack2h(aRow[(size_t)i*Mn + k]*civ[k], aRow[(size_t)i*Mn + k + 1]*civ[k+1]);
      *reinterpret_cast<unsigned int*>(&As[r*72 + 2*cp]) = v;
    }
    for (int idx = tid; idx < 2048; idx += 512) {
      int c = idx & 63, rp = idx >> 6;
      int j = j0 + c, k = k0 + 2*rp;
      unsigned int v = 0;
      if (j < Mn && k < Mn)
        v = pack2h(Wb[(size_t)k*Mn + j], Wb[(size_t)(k+1)*Mn + j]);
      *reinterpret_cast<unsigned int*>(&Bs[c*72 + 2*rp]) = v;
    }
    __syncthreads();
    #pragma unroll
    for (int kk = 0; kk < 2; ++kk) {
      half8 a0 = *reinterpret_cast<const half8*>(&As[(wm + 0  + ln)*72 + kk*32 + lg*8]);
      half8 a1 = *reinterpret_cast<const half8*>(&As[(wm + 16 + ln)*72 + kk*32 + lg*8]);
      half8 b0 = *reinterpret_cast<const half8*>(&Bs[(wn + ln)*72 + kk*32 + lg*8]);
      acc[0] = MFMAH(a0, b0, acc[0], 0, 0, 0);
      acc[1] = MFMAH(a1, b0, acc[1], 0, 0, 0);
    }
    __syncthreads();
  }
  float wbv = wb[0];
  #pragma unroll
  for (int mt = 0; mt < 2; ++mt)
    #pragma unroll
    for (int r = 0; r < 4; ++r) {
      int i = i0 + wm + mt*16 + lg*4 + r;
      int j = j0 + wn + ln;
      if (i < Mn && j < Mn) {
        float cg = sigm(acc[mt][r] + wbv);
        float av = aRow[(size_t)i*Mn + j]*civ[j];
        float ag = adj_geo[(size_t)i*Mn + j];
        float adjf = ag*cg + av*(1.f - cg) + dmat[(size_t)i*Mn + j]*ag;
        adjb[((size_t)b*Mn + i)*Mn + j] = (adjf > 0.f) ? 1.f : adjf;
      }
    }
}

// ---------------------------------------------------------------------------
// K11: laplace row-normalize -> fp16 lapB
__global__ __launch_bounds__(256) void k_lap(const float* __restrict__ adjb, unsigned short* __restrict__ lapB)
{
  int b = blockIdx.y, i = blockIdx.x;
  const float* row = adjb + ((size_t)b*Mn + i)*Mn;
  int tid = threadIdx.x;
  float s = 0.f;
  for (int j = tid; j < Mn; j += 256) s += row[j];
  __shared__ float red[8];
  int lane = tid & 63, wv = tid >> 6;
  #pragma unroll
  for (int off = 32; off; off >>= 1) s += __shfl_down(s, off);
  if (lane == 0) red[wv] = s;
  __syncthreads();
  if (tid == 0) {
    float d = red[0] + red[1] + red[2] + red[3];
    red[4] = (d > 0.f) ? 1.f/d : 0.f;
  }
  __syncthreads();
  float inv = red[4];
  unsigned short* lrow = lapB + ((size_t)b*Mn + i)*Mn;
  for (int j = tid; j < Mn; j += 256) lrow[j] = f2h(row[j]*inv);
}

// ---------------------------------------------------------------------------
// K12: spmm via fp16 MFMA, 32x32 tiles: grid (5, 16, Bz)
__global__ __launch_bounds__(256) void k_spmm(
    const unsigned short* __restrict__ lapB, const unsigned short* __restrict__ fT,
    unsigned short* __restrict__ tmpB)
{
  __shared__ unsigned short As[32*72], Bs[32*72];
  int b = blockIdx.z, i0 = blockIdx.y*32, j0 = blockIdx.x*32;
  int tid = threadIdx.x;
  int w = tid >> 6, lane = tid & 63, ln = lane & 15, lg = lane >> 4;
  int wm = (w >> 1)*16, wn = (w & 1)*16;
  f32x4 acc = (f32x4)(0.f);

  for (int k0 = 0; k0 < 512; k0 += 64) {
    for (int idx = tid; idx < 1024; idx += 256) {
      int r = idx >> 5, cp = idx & 31;
      int i = i0 + r, k = k0 + 2*cp;
      unsigned int v = 0;
      if (i < Mn && k < Mn)
        v = *reinterpret_cast<const unsigned int*>(&lapB[((size_t)b*Mn + i)*Mn + k]);
      *reinterpret_cast<unsigned int*>(&As[r*72 + 2*cp]) = v;
    }
    for (int idx = tid; idx < 1024; idx += 256) {
      int r = idx >> 5, cp = idx & 31;
      int d = j0 + r, k = k0 + 2*cp;
      unsigned int v = 0;
      if (k < Mn)
        v = *reinterpret_cast<const unsigned int*>(&fT[((size_t)b*DF + d)*Mn + k]);
      *reinterpret_cast<unsigned int*>(&Bs[r*72 + 2*cp]) = v;
    }
    __syncthreads();
    #pragma unroll
    for (int kk = 0; kk < 2; ++kk) {
      half8 a0 = *reinterpret_cast<const half8*>(&As[(wm + ln)*72 + kk*32 + lg*8]);
      half8 b0 = *reinterpret_cast<const half8*>(&Bs[(wn + ln)*72 + kk*32 + lg*8]);
      acc = MFMAH(a0, b0, acc, 0, 0, 0);
    }
    __syncthreads();
  }
  #pragma unroll
  for (int r = 0; r < 4; ++r) {
    int i = i0 + wm + lg*4 + r;
    int j = j0 + wn + ln;
    if (i < Mn)
      tmpB[((size_t)b*Mn + i)*DF + j] = f2h(acc[r]);
  }
}

// ---------------------------------------------------------------------------
// K13: dense 32x32 tiles: grid (5, 125)
__global__ __launch_bounds__(256) void k_dense(
    const unsigned short* __restrict__ tmpB, const in_t* __restrict__ W, const in_t* __restrict__ bias,
    float* __restrict__ fout, unsigned short* __restrict__ foutT)
{
  __shared__ unsigned short As[32*72], Bs[32*72];
  __shared__ float bs[32];
  int i0 = blockIdx.y*32, j0 = blockIdx.x*32;
  int tid = threadIdx.x;
  if (tid < 32) bs[tid] = bias[j0 + tid];
  int w = tid >> 6, lane = tid & 63, ln = lane & 15, lg = lane >> 4;
  int wm = (w >> 1)*16, wn = (w & 1)*16;
  f32x4 acc = (f32x4)(0.f);

  for (int k0 = 0; k0 < 192; k0 += 64) {
    for (int idx = tid; idx < 1024; idx += 256) {
      int r = idx >> 5, cp = idx & 31;
      int i = i0 + r, k = k0 + 2*cp;
      unsigned int v = 0;
      if (k < DF)
        v = *reinterpret_cast<const unsigned int*>(&tmpB[(size_t)i*DF + k]);
      *reinterpret_cast<unsigned int*>(&As[r*72 + 2*cp]) = v;
    }
    for (int idx = tid; idx < 1024; idx += 256) {
      int c = idx & 31, rp = idx >> 5;
      int j = j0 + c, k = k0 + 2*rp;
      unsigned int v = 0;
      if (k < DF)
        v = pack2h(W[(size_t)k*DF + j], W[(size_t)(k+1)*DF + j]);
      *reinterpret_cast<unsigned int*>(&Bs[c*72 + 2*rp]) = v;
    }
    __syncthreads();
    #pragma unroll
    for (int kk = 0; kk < 2; ++kk) {
      half8 a0 = *reinterpret_cast<const half8*>(&As[(wm + ln)*72 + kk*32 + lg*8]);
      half8 b0 = *reinterpret_cast<const half8*>(&Bs[(wn + ln)*72 + kk*32 + lg*8]);
      acc = MFMAH(a0, b0, acc, 0, 0, 0);
    }
    __syncthreads();
  }
  #pragma unroll
  for (int r = 0; r < 4; ++r) {
    int i = i0 + wm + lg*4 + r;
    int jl = wn + ln;
    int j = j0 + jl;
    float val = eluf(acc[r] + bs[jl]);
    fout[(size_t)i*DF + j] = val;
    if (foutT) {
      int bb = i / Mn, mm = i - bb*Mn;
      foutT[((size_t)bb*DF + j)*Mn + mm] = f2h(val);
    }
  }
}

// ---------------------------------------------------------------------------
// K14: output projection — one wave per output row, lanes over channels
__global__ __launch_bounds__(256) void k_out(
    const float* __restrict__ f0, const float* __restrict__ f1, const float* __restrict__ f2,
    const float* __restrict__ lh, const in_t* __restrict__ ow, const in_t* __restrict__ ob,
    float* __restrict__ outp)
{
  __shared__ float w[FINALC];
  int tid = threadIdx.x;
  for (int i = tid; i < FINALC; i += 256) w[i] = ow[i];
  __syncthreads();
  int lane = tid & 63;
  int gid = blockIdx.x*4 + (tid >> 6);
  const float* p0 = f0 + (size_t)gid*DF;
  const float* p1 = f1 + (size_t)gid*DF;
  const float* p2 = f2 + (size_t)gid*DF;
  const float* pl = lh + (size_t)gid*NHID;
  float s = 0.f;
  #pragma unroll
  for (int ch = 0; ch < 8; ++ch) {
    int ci = ch*64 + lane;
    float v;
    if (ci < DF)          v = p0[ci];
    else if (ci < 2*DF)   v = p1[ci - DF];
    else if (ci < 3*DF)   v = p2[ci - 2*DF];
    else                  v = pl[ci - 3*DF];
    s += v * w[ci];
  }
  #pragma unroll
  for (int off = 32; off; off >>= 1) s += __shfl_down(s, off, 64);
  if (lane == 0) outp[gid] = s + ob[0];
}

// ---------------------------------------------------------------------------
extern "C" void kernel_launch(void* const* d_in, const int* in_sizes, int n_in,
                              void* d_out, int out_size, void* d_ws, size_t ws_size,
                              hipStream_t stream)
{
  const in_t* x       = (const in_t*)d_in[0];
  const in_t* adj_geo = (const in_t*)d_in[1];
  const in_t* degree  = (const in_t*)d_in[2];
  const in_t* conv_s_w= (const in_t*)d_in[3];
  const in_t* conv_s_b= (const in_t*)d_in[4];
  const in_t* conv_l_w= (const in_t*)d_in[5];
  const in_t* conv_l_b= (const in_t*)d_in[6];
  const in_t* WQ_w    = (const in_t*)d_in[7];
  const in_t* WQ_b    = (const in_t*)d_in[8];
  const in_t* WK_w    = (const in_t*)d_in[9];
  const in_t* WK_b    = (const in_t*)d_in[10];
  const in_t* tenc_w  = (const in_t*)d_in[11];
  const in_t* tenc_b  = (const in_t*)d_in[12];
  const in_t* senc_w  = (const in_t*)d_in[13];
  const in_t* senc_b  = (const in_t*)d_in[14];
  const in_t* gru_Wih = (const in_t*)d_in[15];
  const in_t* gru_Whh = (const in_t*)d_in[16];
  const in_t* gru_bih = (const in_t*)d_in[17];
  const in_t* gru_bhh = (const in_t*)d_in[18];
  const in_t* Vv      = (const in_t*)d_in[19];
  const in_t* W1      = (const in_t*)d_in[20];
  const in_t* W2      = (const in_t*)d_in[21];
  const in_t* Wb      = (const in_t*)d_in[22];
  const in_t* bv      = (const in_t*)d_in[23];
  const in_t* b1      = (const in_t*)d_in[24];
  const in_t* wb      = (const in_t*)d_in[25];
  const in_t* d_gate  = (const in_t*)d_in[26];
  const in_t* gnn_w   = (const in_t*)d_in[27];
  const in_t* gnn_b   = (const in_t*)d_in[28];
  const in_t* out_w   = (const in_t*)d_in[29];
  const in_t* out_b   = (const in_t*)d_in[30];
  float* out = (float*)d_out;

  // workspace carve-up (float offsets)
  float* ws   = (float*)d_ws;
  float* hSC  = ws;                    // 128000
  float* Qb   = ws + 128000;           // 256000
  float* Ktb  = ws + 384000;           // 256000
  float* lh   = ws + 673280;           // 128000
  float* A1   = ws + 801280;           // 128000
  float* A2   = ws + 929280;           // 128000
  float* aB   = ws + 1057280;          // 2000000 (dead after k_cgemm; lapB overlays)
  float* cinv = ws + 3057280;          // 4000
  float* adjb = ws + 3061280;          // 2000000
  float* dmat = ws + 5061280;          // 250000
  float* f0   = ws + 5311280;          // 640000
  float* f1   = ws + 5951280;          // 640000
  float* f2   = ws + 6591280;          // 640000
  unsigned short* f0T  = (unsigned short*)(ws + 7231280);  // 640000 fp16
  unsigned short* tmpB = (unsigned short*)(ws + 7551280);  // 640000 fp16
  unsigned short* f1T  = (unsigned short*)(ws + 7871280);  // 640000 fp16
  unsigned short* lapB = (unsigned short*)aB;              // fp16 overlay (aB dead after cgemm)
  // transient partials in adjb region (adjb written only later by k_cgemm):
  float* Gpart = adjb;                 // 8*8*4096 = 262144
  float* Kpart = adjb + 262144;        // 8*8*64   = 4096
  float* ssp   = adjb + 266240;        // 8*8*500  = 32000
  float* Gfull = adjb + 298240;        // 8*4096   = 32768
  float* Kfull = adjb + 331008;        // 8*64     = 512

  k_conv<<<dim3(250), 256, 0, stream>>>(x, conv_s_w, conv_s_b, conv_l_w, conv_l_b, hSC, f0, f0T);
  k_qk<<<dim3(1000), 256, 0, stream>>>(hSC, WQ_w, WQ_b, WK_w, WK_b, Qb, Ktb);
  k_gram<<<dim3(GSPLIT, Bz), 256, 0, stream>>>(Ktb, Gpart, Kpart);
  k_gfin<<<dim3(Bz), 256, 0, stream>>>(Gpart, Kpart, Gfull, Kfull);
  k_sglob<<<dim3(1000), 256, 0, stream>>>(Qb, Gfull, Kfull, degree, tenc_w, tenc_b, senc_w, senc_b, f0, f0T);
  k_gru<<<dim3(500), 256, 0, stream>>>(x, gru_Wih, gru_Whh, gru_bih, gru_bhh, lh);
  k_a1a2<<<dim3(500), 256, 0, stream>>>(lh, W1, W2, A1, A2);
  k_dmat<<<dim3((Mn*Mn + 255)/256), 256, 0, stream>>>(d_gate, degree, dmat);
  k_pair<<<dim3(32, 32, Bz), 256, 0, stream>>>(A1, A2, Vv, b1, bv, aB);
  k_cnorm<<<dim3(4, 8, Bz), 128, 0, stream>>>(aB, ssp);
  k_cfin<<<dim3(16), 256, 0, stream>>>(ssp, cinv);
  k_cgemm<<<dim3(8, 8, Bz), 512, 0, stream>>>(aB, cinv, Wb, wb, adj_geo, dmat, adjb);
  k_lap<<<dim3(Mn, Bz), 256, 0, stream>>>(adjb, lapB);
  // GNN layer 0
  k_spmm<<<dim3(5, 16, Bz), 256, 0, stream>>>(lapB, f0T, tmpB);
  k_dense<<<dim3(5, 125), 256, 0, stream>>>(tmpB, gnn_w, gnn_b, f1, f1T);
  // GNN layer 1
  k_spmm<<<dim3(5, 16, Bz), 256, 0, stream>>>(lapB, f1T, tmpB);
  k_dense<<<dim3(5, 125), 256, 0, stream>>>(tmpB, gnn_w + DF*DF, gnn_b + DF, f2, (unsigned short*)nullptr);
  k_out<<<dim3(1000), 256, 0, stream>>>(f0, f1, f2, lh, out_w, out_b, out);
}